// Round 3
// baseline (3698.284 us; speedup 1.0000x reference)
//
#include <hip/hip_runtime.h>
#include <hip/hip_bf16.h>

#define TT 2048
#define BB 4
#define HH 4
#define DD 1024

using bf16x8 = __attribute__((ext_vector_type(8))) short;
using f32x4  = __attribute__((ext_vector_type(4))) float;

__device__ __forceinline__ float wave_sum(float x) {
#pragma unroll
  for (int off = 32; off >= 1; off >>= 1) x += __shfl_xor(x, off);
  return x;
}

__device__ __forceinline__ float siluf(float x) {
  return x / (1.f + expf(-x));
}

__device__ __forceinline__ unsigned short f2bf(float f) {
  unsigned u = __float_as_uint(f);
  u = (u + 0x7fffu + ((u >> 16) & 1u)) >> 16;
  return (unsigned short)u;
}
__device__ __forceinline__ float bf2f(unsigned short b) {
  return __uint_as_float(((unsigned)b) << 16);
}

// ---------------- bf16 MFMA GEMM: C[M,N] = A[M,K] @ B[K,N], Bt is [N][K] ----
__global__ __launch_bounds__(256) void gemm_bt(const unsigned short* __restrict__ A,
                                               const unsigned short* __restrict__ Bt,
                                               float* __restrict__ C,
                                               int M, int N, int K) {
  __shared__ unsigned short As[128 * 64];
  __shared__ unsigned short Bs[128 * 64];
  const int tid = threadIdx.x;
  const int l = tid & 63;
  const int w = tid >> 6;
  const int wm = w >> 1, wn = w & 1;
  const int m0 = blockIdx.y * 128, n0 = blockIdx.x * 128;

  f32x4 acc[4][4];
#pragma unroll
  for (int i = 0; i < 4; ++i)
#pragma unroll
    for (int j = 0; j < 4; ++j) acc[i][j] = (f32x4){0.f, 0.f, 0.f, 0.f};

  int c_row[4], c_slot[4], c_dst[4];
#pragma unroll
  for (int it = 0; it < 4; ++it) {
    int chunk = it * 256 + tid;
    int row = chunk >> 3, s = chunk & 7;
    c_row[it] = row;
    c_slot[it] = s;
    c_dst[it] = row * 128 + ((s ^ (row & 7)) << 4);
  }
  int ra_off[2][4], rb_off[2][4];
#pragma unroll
  for (int kh = 0; kh < 2; ++kh)
#pragma unroll
    for (int f = 0; f < 4; ++f) {
      int rowA = wm * 64 + f * 16 + (l & 15);
      ra_off[kh][f] = rowA * 128 + (((kh * 4 + (l >> 4)) ^ (rowA & 7)) << 4);
      int rowB = wn * 64 + f * 16 + (l & 15);
      rb_off[kh][f] = rowB * 128 + (((kh * 4 + (l >> 4)) ^ (rowB & 7)) << 4);
    }

  for (int k0 = 0; k0 < K; k0 += 64) {
    uint4 ra[4], rb[4];
#pragma unroll
    for (int it = 0; it < 4; ++it) {
      ra[it] = *(const uint4*)(A + (size_t)(m0 + c_row[it]) * K + k0 + c_slot[it] * 8);
      rb[it] = *(const uint4*)(Bt + (size_t)(n0 + c_row[it]) * K + k0 + c_slot[it] * 8);
    }
    __syncthreads();
#pragma unroll
    for (int it = 0; it < 4; ++it) {
      *(uint4*)((char*)As + c_dst[it]) = ra[it];
      *(uint4*)((char*)Bs + c_dst[it]) = rb[it];
    }
    __syncthreads();
#pragma unroll
    for (int kh = 0; kh < 2; ++kh) {
      bf16x8 af[4], bfv[4];
#pragma unroll
      for (int f = 0; f < 4; ++f) {
        af[f] = *(const bf16x8*)((const char*)As + ra_off[kh][f]);
        bfv[f] = *(const bf16x8*)((const char*)Bs + rb_off[kh][f]);
      }
#pragma unroll
      for (int i = 0; i < 4; ++i)
#pragma unroll
        for (int j = 0; j < 4; ++j)
          acc[i][j] = __builtin_amdgcn_mfma_f32_16x16x32_bf16(af[i], bfv[j],
                                                              acc[i][j], 0, 0, 0);
    }
  }
  const int cn = n0 + wn * 64 + (l & 15);
  const int rbase = m0 + wm * 64 + ((l >> 4) << 2);
#pragma unroll
  for (int i = 0; i < 4; ++i)
#pragma unroll
    for (int j = 0; j < 4; ++j)
#pragma unroll
      for (int r = 0; r < 4; ++r)
        C[(size_t)(rbase + i * 16 + r) * N + cn + j * 16] = acc[i][j][r];
}

// ------------- split-bf16 3-term GEMM (fp32-accurate): C = Ah@Bh+Al@Bh+Ah@Bl
__global__ __launch_bounds__(256) void gemm_bt3(const unsigned short* __restrict__ Ah,
                                                const unsigned short* __restrict__ Al,
                                                const unsigned short* __restrict__ Bh,
                                                const unsigned short* __restrict__ Bl,
                                                float* __restrict__ C,
                                                int M, int N, int K) {
  __shared__ unsigned short Ash[128 * 64];
  __shared__ unsigned short Asl[128 * 64];
  __shared__ unsigned short Bsh[128 * 64];
  __shared__ unsigned short Bsl[128 * 64];
  const int tid = threadIdx.x;
  const int l = tid & 63;
  const int w = tid >> 6;
  const int wm = w >> 1, wn = w & 1;
  const int m0 = blockIdx.y * 128, n0 = blockIdx.x * 128;

  f32x4 acc[4][4];
#pragma unroll
  for (int i = 0; i < 4; ++i)
#pragma unroll
    for (int j = 0; j < 4; ++j) acc[i][j] = (f32x4){0.f, 0.f, 0.f, 0.f};

  int c_row[4], c_slot[4], c_dst[4];
#pragma unroll
  for (int it = 0; it < 4; ++it) {
    int chunk = it * 256 + tid;
    int row = chunk >> 3, s = chunk & 7;
    c_row[it] = row;
    c_slot[it] = s;
    c_dst[it] = row * 128 + ((s ^ (row & 7)) << 4);
  }
  int ra_off[2][4], rb_off[2][4];
#pragma unroll
  for (int kh = 0; kh < 2; ++kh)
#pragma unroll
    for (int f = 0; f < 4; ++f) {
      int rowA = wm * 64 + f * 16 + (l & 15);
      ra_off[kh][f] = rowA * 128 + (((kh * 4 + (l >> 4)) ^ (rowA & 7)) << 4);
      int rowB = wn * 64 + f * 16 + (l & 15);
      rb_off[kh][f] = rowB * 128 + (((kh * 4 + (l >> 4)) ^ (rowB & 7)) << 4);
    }

  for (int k0 = 0; k0 < K; k0 += 64) {
    uint4 rah[4], ral[4], rbh[4], rbl[4];
#pragma unroll
    for (int it = 0; it < 4; ++it) {
      size_t aoff = (size_t)(m0 + c_row[it]) * K + k0 + c_slot[it] * 8;
      size_t boff = (size_t)(n0 + c_row[it]) * K + k0 + c_slot[it] * 8;
      rah[it] = *(const uint4*)(Ah + aoff);
      ral[it] = *(const uint4*)(Al + aoff);
      rbh[it] = *(const uint4*)(Bh + boff);
      rbl[it] = *(const uint4*)(Bl + boff);
    }
    __syncthreads();
#pragma unroll
    for (int it = 0; it < 4; ++it) {
      *(uint4*)((char*)Ash + c_dst[it]) = rah[it];
      *(uint4*)((char*)Asl + c_dst[it]) = ral[it];
      *(uint4*)((char*)Bsh + c_dst[it]) = rbh[it];
      *(uint4*)((char*)Bsl + c_dst[it]) = rbl[it];
    }
    __syncthreads();
#pragma unroll
    for (int kh = 0; kh < 2; ++kh) {
      bf16x8 afh[4], bfh[4], tmp[4];
#pragma unroll
      for (int f = 0; f < 4; ++f) {
        afh[f] = *(const bf16x8*)((const char*)Ash + ra_off[kh][f]);
        bfh[f] = *(const bf16x8*)((const char*)Bsh + rb_off[kh][f]);
      }
#pragma unroll
      for (int i = 0; i < 4; ++i)
#pragma unroll
        for (int j = 0; j < 4; ++j)
          acc[i][j] = __builtin_amdgcn_mfma_f32_16x16x32_bf16(afh[i], bfh[j],
                                                              acc[i][j], 0, 0, 0);
#pragma unroll
      for (int f = 0; f < 4; ++f)
        tmp[f] = *(const bf16x8*)((const char*)Asl + ra_off[kh][f]);
#pragma unroll
      for (int i = 0; i < 4; ++i)
#pragma unroll
        for (int j = 0; j < 4; ++j)
          acc[i][j] = __builtin_amdgcn_mfma_f32_16x16x32_bf16(tmp[i], bfh[j],
                                                              acc[i][j], 0, 0, 0);
#pragma unroll
      for (int f = 0; f < 4; ++f)
        tmp[f] = *(const bf16x8*)((const char*)Bsl + rb_off[kh][f]);
#pragma unroll
      for (int i = 0; i < 4; ++i)
#pragma unroll
        for (int j = 0; j < 4; ++j)
          acc[i][j] = __builtin_amdgcn_mfma_f32_16x16x32_bf16(afh[i], tmp[j],
                                                              acc[i][j], 0, 0, 0);
    }
  }
  const int cn = n0 + wn * 64 + (l & 15);
  const int rbase = m0 + wm * 64 + ((l >> 4) << 2);
#pragma unroll
  for (int i = 0; i < 4; ++i)
#pragma unroll
    for (int j = 0; j < 4; ++j)
#pragma unroll
      for (int r = 0; r < 4; ++r)
        C[(size_t)(rbase + i * 16 + r) * N + cn + j * 16] = acc[i][j][r];
}

// ---------------- casts ----------------
__global__ __launch_bounds__(256) void cast_bf16_kernel(const float* __restrict__ in,
                                                        unsigned short* __restrict__ out) {
  const size_t i = ((size_t)blockIdx.x * 256 + threadIdx.x) * 4;
  float4 x = *(const float4*)(in + i);
  ushort4 o4;
  o4.x = f2bf(x.x);
  o4.y = f2bf(x.y);
  o4.z = f2bf(x.z);
  o4.w = f2bf(x.w);
  *(ushort4*)(out + i) = o4;
}

__global__ __launch_bounds__(256) void cast2_bf16_kernel(const float* __restrict__ in,
                                                         unsigned short* __restrict__ hi,
                                                         unsigned short* __restrict__ lo) {
  const size_t i = ((size_t)blockIdx.x * 256 + threadIdx.x) * 4;
  float4 x = *(const float4*)(in + i);
  ushort4 h4, l4;
  h4.x = f2bf(x.x); l4.x = f2bf(x.x - bf2f(h4.x));
  h4.y = f2bf(x.y); l4.y = f2bf(x.y - bf2f(h4.y));
  h4.z = f2bf(x.z); l4.z = f2bf(x.z - bf2f(h4.z));
  h4.w = f2bf(x.w); l4.w = f2bf(x.w - bf2f(h4.w));
  *(ushort4*)(hi + i) = h4;
  *(ushort4*)(lo + i) = l4;
}

// W [R][C] f32 row-major -> WT [C][R] bf16 (transpose + cast)
__global__ __launch_bounds__(256) void tcast_kernel(const float* __restrict__ W,
                                                    unsigned short* __restrict__ WT,
                                                    int R, int C) {
  __shared__ float tile[32][33];
  const int tx = threadIdx.x, ty = threadIdx.y;
  const int c0 = blockIdx.x * 32, r0 = blockIdx.y * 32;
#pragma unroll
  for (int i = 0; i < 4; ++i)
    tile[ty + 8 * i][tx] = W[(size_t)(r0 + ty + 8 * i) * C + c0 + tx];
  __syncthreads();
#pragma unroll
  for (int i = 0; i < 4; ++i)
    WT[(size_t)(c0 + ty + 8 * i) * R + r0 + tx] = f2bf(tile[tx][ty + 8 * i]);
}

__global__ __launch_bounds__(256) void tcast2_kernel(const float* __restrict__ W,
                                                     unsigned short* __restrict__ WTh,
                                                     unsigned short* __restrict__ WTl,
                                                     int R, int C) {
  __shared__ float tile[32][33];
  const int tx = threadIdx.x, ty = threadIdx.y;
  const int c0 = blockIdx.x * 32, r0 = blockIdx.y * 32;
#pragma unroll
  for (int i = 0; i < 4; ++i)
    tile[ty + 8 * i][tx] = W[(size_t)(r0 + ty + 8 * i) * C + c0 + tx];
  __syncthreads();
#pragma unroll
  for (int i = 0; i < 4; ++i) {
    float x = tile[tx][ty + 8 * i];
    unsigned short h = f2bf(x);
    WTh[(size_t)(c0 + ty + 8 * i) * R + r0 + tx] = h;
    WTl[(size_t)(c0 + ty + 8 * i) * R + r0 + tx] = f2bf(x - bf2f(h));
  }
}

// ---------------- routing: a/beta dots, top-4, silu+norms, dense decay ----
__global__ __launch_bounds__(256) void routing_kernel(
    const float* __restrict__ hidden, const float* __restrict__ Wa,
    const float* __restrict__ Wb, const float* __restrict__ dt,
    const float* __restrict__ rproj, float* __restrict__ qk,
    float* __restrict__ kk_, float* __restrict__ vv, float* __restrict__ decT,
    float* __restrict__ betaT) {
  const int row = blockIdx.x;  // b*T + t
  const int b = row >> 11;
  const int t = row & (TT - 1);
  const int h = threadIdx.x >> 6;
  const int l = threadIdx.x & 63;
  const size_t base = (size_t)row * DD + h * 256;

  const float* hrow = hidden + (size_t)row * DD;
  float aa = 0.f, bb = 0.f;
#pragma unroll
  for (int i = 0; i < 16; ++i) {
    float hv = hrow[l + 64 * i];
    aa = fmaf(hv, Wa[(l + 64 * i) * HH + h], aa);
    bb = fmaf(hv, Wb[(l + 64 * i) * HH + h], bb);
  }
  aa = wave_sum(aa);
  bb = wave_sum(bb);
  float sp = (aa > 20.f) ? aa : log1pf(expf(aa));
  float a_ = -sp * expf(dt[h]);
  float beta = 1.f / (1.f + expf(-bb));
  const int bh = b * HH + h;
  if (l == 0) betaT[(size_t)bh * TT + t] = beta;

  float4 rt4 = *(const float4*)(rproj + base + l * 4);
  float rv[4] = {rt4.x, rt4.y, rt4.z, rt4.w};
  int used = 0;
  int widx[4];
  float wsig[4], wdec[4], wkfac[4];
#pragma unroll
  for (int it = 0; it < 4; ++it) {
    float bv = -3.4e38f;
    int bi = 0x7fffffff;
#pragma unroll
    for (int c = 0; c < 4; ++c) {
      bool ok = !(used & (1 << c));
      float v = rv[c];
      if (ok && (v > bv)) {
        bv = v;
        bi = l * 4 + c;
      }
    }
#pragma unroll
    for (int off = 32; off >= 1; off >>= 1) {
      float ov = __shfl_xor(bv, off);
      int oi = __shfl_xor(bi, off);
      if (ov > bv || (ov == bv && oi < bi)) {
        bv = ov;
        bi = oi;
      }
    }
    widx[it] = bi;
    wsig[it] = 1.f / (1.f + expf(-bv));
    if ((bi >> 2) == l) used |= 1 << (bi & 3);
  }
  float wsum = wsig[0] + wsig[1] + wsig[2] + wsig[3] + 1e-6f;
#pragma unroll
  for (int it = 0; it < 4; ++it) {
    float g = a_ * (wsig[it] / wsum);
    wdec[it] = expf(g);
    wkfac[it] = 1.f - wdec[it];
  }

  float4 kv4 = *(const float4*)(kk_ + base + l * 4);
  float kvv[4] = {kv4.x, kv4.y, kv4.z, kv4.w};
  float kmask[4], ddv[4];
#pragma unroll
  for (int c = 0; c < 4; ++c) {
    int slot = l * 4 + c;
    float f = 0.f, d = 1.f;
#pragma unroll
    for (int it = 0; it < 4; ++it) {
      bool hit = (slot == widx[it]);
      f = hit ? wkfac[it] : f;
      d = hit ? wdec[it] : d;
    }
    kmask[c] = siluf(kvv[c]) * f;
    ddv[c] = d;
  }
  float ss = kmask[0] * kmask[0] + kmask[1] * kmask[1] + kmask[2] * kmask[2] +
             kmask[3] * kmask[3];
  ss = wave_sum(ss);
  float kn = rsqrtf(ss + 1e-6f);
  *(float4*)(kk_ + base + l * 4) =
      make_float4(kmask[0] * kn, kmask[1] * kn, kmask[2] * kn, kmask[3] * kn);
  *(float4*)(decT + base + l * 4) = make_float4(ddv[0], ddv[1], ddv[2], ddv[3]);

  float4 qv4 = *(const float4*)(qk + base + l * 4);
  float qs[4] = {siluf(qv4.x), siluf(qv4.y), siluf(qv4.z), siluf(qv4.w)};
  float qss = qs[0] * qs[0] + qs[1] * qs[1] + qs[2] * qs[2] + qs[3] * qs[3];
  qss = wave_sum(qss);
  float qn = rsqrtf(qss + 1e-6f) * 0.0625f;
  *(float4*)(qk + base + l * 4) =
      make_float4(qs[0] * qn, qs[1] * qn, qs[2] * qn, qs[3] * qn);

  float4 vv4 = *(const float4*)(vv + base + l * 4);
  *(float4*)(vv + base + l * 4) =
      make_float4(siluf(vv4.x), siluf(vv4.y), siluf(vv4.z), siluf(vv4.w));
}

// ---------------- gated delta-rule scan, lookahead form ----------------
// Exact reassociation: with S_{t-1} = D_{t-1} S_{t-2} + k_{t-1} be_{t-1}^T,
//   ep_t = k_t^T D_t S_{t-1} = a_t + c_t * be_{t-1}
//   a_t  = sum_k (k_t d_t)_k (d_{t-1} S_{t-2})_kj   (off serial chain)
//   c_t  = sum_k (k_t d_t)_k k_{t-1,k}              (off serial chain)
// so the serial chain per step is only:  be_t = beta(v - a - c*be_prev).
// 512 blocks x 256 threads; block=(bh, cg); wave w: cols cg*8+w*2+{0,1}.
// lane=(kg in [0,32), jl in [0,2)); 8 state rows per lane.
struct F8 { float v[8]; };
__device__ __forceinline__ F8 load8(const float* p) {
  float4 a = *(const float4*)p, b = *(const float4*)(p + 4);
  F8 r;
  r.v[0] = a.x; r.v[1] = a.y; r.v[2] = a.z; r.v[3] = a.w;
  r.v[4] = b.x; r.v[5] = b.y; r.v[6] = b.z; r.v[7] = b.w;
  return r;
}

__global__ __launch_bounds__(256) void scan_kernel(
    const float* __restrict__ q, const float* __restrict__ k,
    const float* __restrict__ dec, const float* __restrict__ v,
    const float* __restrict__ betaT, float* __restrict__ o) {
  const int bid = blockIdx.x;
  const int bh = (bid & 7) + ((bid >> 8) << 3);  // same-bh blocks -> same XCD
  const int cg = (bid >> 3) & 31;
  const int b = bh >> 2, h = bh & 3;
  const int lane = threadIdx.x & 63;
  const int w = threadIdx.x >> 6;
  const int kg = lane >> 1;
  const int jl = lane & 1;
  const int col = cg * 8 + w * 2 + jl;

  float S[8], dprev[8], kprev[8];
#pragma unroll
  for (int r = 0; r < 8; ++r) {
    S[r] = 0.f;
    dprev[r] = 1.f;
    kprev[r] = 0.f;
  }
  float be_prev = 0.f;

  const size_t base0 = (size_t)(b * TT) * DD + h * 256;
  const float* qp = q + base0 + kg * 8;
  const float* kp = k + base0 + kg * 8;
  const float* dp = dec + base0 + kg * 8;
  const float* vp = v + base0 + col;
  const float* bp = betaT + (size_t)bh * TT;
  float* op = o + base0 + col;

  F8 kA, dA, qA, kB, dB, qB;
  float vA, bA, vB, bB;

#define LOADS(Kx, Dx, Qx, Vx, Bx, t)                       \
  {                                                        \
    int tc = (t) < TT ? (t) : (TT - 1);                    \
    size_t off_ = (size_t)tc * DD;                         \
    Kx = load8(kp + off_);                                 \
    Dx = load8(dp + off_);                                 \
    Qx = load8(qp + off_);                                 \
    Vx = vp[off_];                                         \
    Bx = bp[tc];                                           \
  }

#define COMPS(Kx, Dx, Qx, Vx, Bx, t)                       \
  {                                                        \
    float u_[8];                                           \
    float a = 0.f, p = 0.f, c = 0.f, pc = 0.f, eq = 0.f;   \
    _Pragma("unroll") for (int r = 0; r < 8; ++r) {        \
      float kd = Kx.v[r] * Dx.v[r];                        \
      float qd = Qx.v[r] * Dx.v[r];                        \
      float uu = dprev[r] * S[r];                          \
      u_[r] = uu;                                          \
      a = fmaf(kd, uu, a);                                 \
      p = fmaf(qd, uu, p);                                 \
      c = fmaf(kd, kprev[r], c);                           \
      pc = fmaf(qd, kprev[r], pc);                         \
      eq = fmaf(Qx.v[r], Kx.v[r], eq);                     \
    }                                                      \
    _Pragma("unroll") for (int off = 2; off <= 32; off <<= 1) { \
      a += __shfl_xor(a, off);                             \
      p += __shfl_xor(p, off);                             \
      c += __shfl_xor(c, off);                             \
      pc += __shfl_xor(pc, off);                           \
      eq += __shfl_xor(eq, off);                           \
    }                                                      \
    float be = Bx * (Vx - a - c * be_prev);                \
    float oo = fmaf(eq, be, fmaf(pc, be_prev, p));         \
    if (kg == 0) op[(size_t)(t) * DD] = oo;                \
    _Pragma("unroll") for (int r = 0; r < 8; ++r) {        \
      S[r] = fmaf(kprev[r], be_prev, u_[r]);               \
      dprev[r] = Dx.v[r];                                  \
      kprev[r] = Kx.v[r];                                  \
    }                                                      \
    be_prev = be;                                          \
  }

  LOADS(kA, dA, qA, vA, bA, 0);
  LOADS(kB, dB, qB, vB, bB, 1);
  for (int t = 0; t < TT; t += 2) {
    COMPS(kA, dA, qA, vA, bA, t);
    LOADS(kA, dA, qA, vA, bA, t + 2);
    COMPS(kB, dB, qB, vB, bB, t + 1);
    LOADS(kB, dB, qB, vB, bB, t + 3);
  }
#undef LOADS
#undef COMPS
}

// ---------------- per-head RMSNorm ----------------
__global__ __launch_bounds__(256) void rmsnorm_kernel(
    const float* __restrict__ o, const float* __restrict__ w,
    float* __restrict__ out) {
  const int row = blockIdx.x;
  const int l = threadIdx.x & 63;
  const size_t base = (size_t)row * DD + (threadIdx.x >> 6) * 256 + l * 4;
  float4 x = *(const float4*)(o + base);
  float ss = x.x * x.x + x.y * x.y + x.z * x.z + x.w * x.w;
  ss = wave_sum(ss);
  float sc = rsqrtf(ss * (1.f / 256.f) + 1e-5f);
  float4 wv = *(const float4*)(w + l * 4);
  *(float4*)(out + base) = make_float4(x.x * sc * wv.x, x.y * sc * wv.y,
                                       x.z * sc * wv.z, x.w * sc * wv.w);
}

extern "C" void kernel_launch(void* const* d_in, const int* in_sizes, int n_in,
                              void* d_out, int out_size, void* d_ws,
                              size_t ws_size, hipStream_t stream) {
  const float* hidden = (const float*)d_in[0];
  const float* Wq = (const float*)d_in[1];
  const float* Wk = (const float*)d_in[2];
  const float* Wv = (const float*)d_in[3];
  const float* Wa = (const float*)d_in[4];
  const float* Wr = (const float*)d_in[5];
  const float* Wb = (const float*)d_in[6];
  const float* dt = (const float*)d_in[7];
  const float* norm_w = (const float*)d_in[8];
  const float* Wo = (const float*)d_in[9];
  float* out = (float*)d_out;

  const size_t NP = (size_t)BB * TT * DD;  // 8388608
  float* ws = (float*)d_ws;
  float* qproj = ws;
  float* kproj = ws + NP;
  float* vproj = ws + 2 * NP;
  float* decT = ws + 3 * NP;
  unsigned short* hbf = (unsigned short*)(ws + 4 * NP);          // NP bf16
  unsigned short* wT = (unsigned short*)(ws + 4 * NP + NP / 2);  // 6 x 1M bf16
  unsigned short* WT0 = wT;                // Wq^T hi
  unsigned short* WT1 = wT + 1048576;      // Wk^T
  unsigned short* WT2 = wT + 2 * 1048576;  // Wv^T
  unsigned short* WT3 = wT + 3 * 1048576;  // Wo^T
  unsigned short* WT4 = wT + 4 * 1048576;  // Wr^T hi
  unsigned short* WT5 = wT + 5 * 1048576;  // Wr^T lo
  float* betaT = ws + 4 * NP + NP / 2 + 3 * 1024 * 1024;  // 16*2048 floats
  unsigned short* hlo = (unsigned short*)qproj;  // alias: dead before qproj GEMM
  float* rproj = out;
  float* normed = qproj;

  dim3 bt(256);
  // casts / transposes
  cast2_bf16_kernel<<<8192, 256, 0, stream>>>(hidden, hbf, hlo);
  dim3 tg(32, 32), tb(32, 8);
  tcast2_kernel<<<tg, tb, 0, stream>>>(Wr, WT4, WT5, 1024, 1024);
  tcast_kernel<<<tg, tb, 0, stream>>>(Wq, WT0, 1024, 1024);
  tcast_kernel<<<tg, tb, 0, stream>>>(Wk, WT1, 1024, 1024);
  tcast_kernel<<<tg, tb, 0, stream>>>(Wv, WT2, 1024, 1024);
  tcast_kernel<<<tg, tb, 0, stream>>>(Wo, WT3, 1024, 1024);

  dim3 gmm(1024 / 128, 8192 / 128);
  // rproj: split-bf16 (fp32-accurate ordering for top-k)
  gemm_bt3<<<gmm, bt, 0, stream>>>(hbf, hlo, WT4, WT5, rproj, 8192, 1024, 1024);
  // q/k/v projections (plain bf16) -- qproj write kills hlo alias (ordered)
  gemm_bt<<<gmm, bt, 0, stream>>>(hbf, WT0, qproj, 8192, 1024, 1024);
  gemm_bt<<<gmm, bt, 0, stream>>>(hbf, WT1, kproj, 8192, 1024, 1024);
  gemm_bt<<<gmm, bt, 0, stream>>>(hbf, WT2, vproj, 8192, 1024, 1024);

  routing_kernel<<<8192, 256, 0, stream>>>(hidden, Wa, Wb, dt, rproj, qproj,
                                           kproj, vproj, decT, betaT);
  scan_kernel<<<512, 256, 0, stream>>>(qproj, kproj, decT, vproj, betaT, out);
  rmsnorm_kernel<<<8192, 256, 0, stream>>>(out, norm_w, normed);
  cast_bf16_kernel<<<8192, 256, 0, stream>>>(normed, hbf);
  gemm_bt<<<gmm, bt, 0, stream>>>(hbf, WT3, out, 8192, 1024, 1024);
}

// Round 4
// 1638.616 us; speedup vs baseline: 2.2570x; 2.2570x over previous
//
#include <hip/hip_runtime.h>
#include <hip/hip_bf16.h>

#define TT 2048
#define BB 4
#define HH 4
#define DD 1024

using bf16x8 = __attribute__((ext_vector_type(8))) short;
using f32x4  = __attribute__((ext_vector_type(4))) float;

__device__ __forceinline__ float wave_sum(float x) {
#pragma unroll
  for (int off = 32; off >= 1; off >>= 1) x += __shfl_xor(x, off);
  return x;
}

__device__ __forceinline__ float siluf(float x) {
  return x / (1.f + expf(-x));
}

__device__ __forceinline__ unsigned short f2bf(float f) {
  unsigned u = __float_as_uint(f);
  u = (u + 0x7fffu + ((u >> 16) & 1u)) >> 16;
  return (unsigned short)u;
}
__device__ __forceinline__ float bf2f(unsigned short b) {
  return __uint_as_float(((unsigned)b) << 16);
}
__device__ __forceinline__ unsigned pack2(float a, float b) {
  return ((unsigned)f2bf(a)) | (((unsigned)f2bf(b)) << 16);
}

// ---------------- bf16 MFMA GEMM: C[M,N] = A[M,K] @ B[K,N], Bt is [N][K] ----
__global__ __launch_bounds__(256) void gemm_bt(const unsigned short* __restrict__ A,
                                               const unsigned short* __restrict__ Bt,
                                               float* __restrict__ C,
                                               int M, int N, int K) {
  __shared__ unsigned short As[128 * 64];
  __shared__ unsigned short Bs[128 * 64];
  const int tid = threadIdx.x;
  const int l = tid & 63;
  const int w = tid >> 6;
  const int wm = w >> 1, wn = w & 1;
  const int m0 = blockIdx.y * 128, n0 = blockIdx.x * 128;

  f32x4 acc[4][4];
#pragma unroll
  for (int i = 0; i < 4; ++i)
#pragma unroll
    for (int j = 0; j < 4; ++j) acc[i][j] = (f32x4){0.f, 0.f, 0.f, 0.f};

  int c_row[4], c_slot[4], c_dst[4];
#pragma unroll
  for (int it = 0; it < 4; ++it) {
    int chunk = it * 256 + tid;
    int row = chunk >> 3, s = chunk & 7;
    c_row[it] = row;
    c_slot[it] = s;
    c_dst[it] = row * 128 + ((s ^ (row & 7)) << 4);
  }
  int ra_off[2][4], rb_off[2][4];
#pragma unroll
  for (int kh = 0; kh < 2; ++kh)
#pragma unroll
    for (int f = 0; f < 4; ++f) {
      int rowA = wm * 64 + f * 16 + (l & 15);
      ra_off[kh][f] = rowA * 128 + (((kh * 4 + (l >> 4)) ^ (rowA & 7)) << 4);
      int rowB = wn * 64 + f * 16 + (l & 15);
      rb_off[kh][f] = rowB * 128 + (((kh * 4 + (l >> 4)) ^ (rowB & 7)) << 4);
    }

  for (int k0 = 0; k0 < K; k0 += 64) {
    uint4 ra[4], rb[4];
#pragma unroll
    for (int it = 0; it < 4; ++it) {
      ra[it] = *(const uint4*)(A + (size_t)(m0 + c_row[it]) * K + k0 + c_slot[it] * 8);
      rb[it] = *(const uint4*)(Bt + (size_t)(n0 + c_row[it]) * K + k0 + c_slot[it] * 8);
    }
    __syncthreads();
#pragma unroll
    for (int it = 0; it < 4; ++it) {
      *(uint4*)((char*)As + c_dst[it]) = ra[it];
      *(uint4*)((char*)Bs + c_dst[it]) = rb[it];
    }
    __syncthreads();
#pragma unroll
    for (int kh = 0; kh < 2; ++kh) {
      bf16x8 af[4], bfv[4];
#pragma unroll
      for (int f = 0; f < 4; ++f) {
        af[f] = *(const bf16x8*)((const char*)As + ra_off[kh][f]);
        bfv[f] = *(const bf16x8*)((const char*)Bs + rb_off[kh][f]);
      }
#pragma unroll
      for (int i = 0; i < 4; ++i)
#pragma unroll
        for (int j = 0; j < 4; ++j)
          acc[i][j] = __builtin_amdgcn_mfma_f32_16x16x32_bf16(af[i], bfv[j],
                                                              acc[i][j], 0, 0, 0);
    }
  }
  const int cn = n0 + wn * 64 + (l & 15);
  const int rbase = m0 + wm * 64 + ((l >> 4) << 2);
#pragma unroll
  for (int i = 0; i < 4; ++i)
#pragma unroll
    for (int j = 0; j < 4; ++j)
#pragma unroll
      for (int r = 0; r < 4; ++r)
        C[(size_t)(rbase + i * 16 + r) * N + cn + j * 16] = acc[i][j][r];
}

// ------------- split-bf16 3-term GEMM (fp32-accurate): C = Ah@Bh+Al@Bh+Ah@Bl
__global__ __launch_bounds__(256) void gemm_bt3(const unsigned short* __restrict__ Ah,
                                                const unsigned short* __restrict__ Al,
                                                const unsigned short* __restrict__ Bh,
                                                const unsigned short* __restrict__ Bl,
                                                float* __restrict__ C,
                                                int M, int N, int K) {
  __shared__ unsigned short Ash[128 * 64];
  __shared__ unsigned short Asl[128 * 64];
  __shared__ unsigned short Bsh[128 * 64];
  __shared__ unsigned short Bsl[128 * 64];
  const int tid = threadIdx.x;
  const int l = tid & 63;
  const int w = tid >> 6;
  const int wm = w >> 1, wn = w & 1;
  const int m0 = blockIdx.y * 128, n0 = blockIdx.x * 128;

  f32x4 acc[4][4];
#pragma unroll
  for (int i = 0; i < 4; ++i)
#pragma unroll
    for (int j = 0; j < 4; ++j) acc[i][j] = (f32x4){0.f, 0.f, 0.f, 0.f};

  int c_row[4], c_slot[4], c_dst[4];
#pragma unroll
  for (int it = 0; it < 4; ++it) {
    int chunk = it * 256 + tid;
    int row = chunk >> 3, s = chunk & 7;
    c_row[it] = row;
    c_slot[it] = s;
    c_dst[it] = row * 128 + ((s ^ (row & 7)) << 4);
  }
  int ra_off[2][4], rb_off[2][4];
#pragma unroll
  for (int kh = 0; kh < 2; ++kh)
#pragma unroll
    for (int f = 0; f < 4; ++f) {
      int rowA = wm * 64 + f * 16 + (l & 15);
      ra_off[kh][f] = rowA * 128 + (((kh * 4 + (l >> 4)) ^ (rowA & 7)) << 4);
      int rowB = wn * 64 + f * 16 + (l & 15);
      rb_off[kh][f] = rowB * 128 + (((kh * 4 + (l >> 4)) ^ (rowB & 7)) << 4);
    }

  for (int k0 = 0; k0 < K; k0 += 64) {
    uint4 rah[4], ral[4], rbh[4], rbl[4];
#pragma unroll
    for (int it = 0; it < 4; ++it) {
      size_t aoff = (size_t)(m0 + c_row[it]) * K + k0 + c_slot[it] * 8;
      size_t boff = (size_t)(n0 + c_row[it]) * K + k0 + c_slot[it] * 8;
      rah[it] = *(const uint4*)(Ah + aoff);
      ral[it] = *(const uint4*)(Al + aoff);
      rbh[it] = *(const uint4*)(Bh + boff);
      rbl[it] = *(const uint4*)(Bl + boff);
    }
    __syncthreads();
#pragma unroll
    for (int it = 0; it < 4; ++it) {
      *(uint4*)((char*)Ash + c_dst[it]) = rah[it];
      *(uint4*)((char*)Asl + c_dst[it]) = ral[it];
      *(uint4*)((char*)Bsh + c_dst[it]) = rbh[it];
      *(uint4*)((char*)Bsl + c_dst[it]) = rbl[it];
    }
    __syncthreads();
#pragma unroll
    for (int kh = 0; kh < 2; ++kh) {
      bf16x8 afh[4], bfh[4], tmp[4];
#pragma unroll
      for (int f = 0; f < 4; ++f) {
        afh[f] = *(const bf16x8*)((const char*)Ash + ra_off[kh][f]);
        bfh[f] = *(const bf16x8*)((const char*)Bsh + rb_off[kh][f]);
      }
#pragma unroll
      for (int i = 0; i < 4; ++i)
#pragma unroll
        for (int j = 0; j < 4; ++j)
          acc[i][j] = __builtin_amdgcn_mfma_f32_16x16x32_bf16(afh[i], bfh[j],
                                                              acc[i][j], 0, 0, 0);
#pragma unroll
      for (int f = 0; f < 4; ++f)
        tmp[f] = *(const bf16x8*)((const char*)Asl + ra_off[kh][f]);
#pragma unroll
      for (int i = 0; i < 4; ++i)
#pragma unroll
        for (int j = 0; j < 4; ++j)
          acc[i][j] = __builtin_amdgcn_mfma_f32_16x16x32_bf16(tmp[i], bfh[j],
                                                              acc[i][j], 0, 0, 0);
#pragma unroll
      for (int f = 0; f < 4; ++f)
        tmp[f] = *(const bf16x8*)((const char*)Bsl + rb_off[kh][f]);
#pragma unroll
      for (int i = 0; i < 4; ++i)
#pragma unroll
        for (int j = 0; j < 4; ++j)
          acc[i][j] = __builtin_amdgcn_mfma_f32_16x16x32_bf16(afh[i], tmp[j],
                                                              acc[i][j], 0, 0, 0);
    }
  }
  const int cn = n0 + wn * 64 + (l & 15);
  const int rbase = m0 + wm * 64 + ((l >> 4) << 2);
#pragma unroll
  for (int i = 0; i < 4; ++i)
#pragma unroll
    for (int j = 0; j < 4; ++j)
#pragma unroll
      for (int r = 0; r < 4; ++r)
        C[(size_t)(rbase + i * 16 + r) * N + cn + j * 16] = acc[i][j][r];
}

// ---------------- casts ----------------
__global__ __launch_bounds__(256) void cast_bf16_kernel(const float* __restrict__ in,
                                                        unsigned short* __restrict__ out) {
  const size_t i = ((size_t)blockIdx.x * 256 + threadIdx.x) * 4;
  float4 x = *(const float4*)(in + i);
  ushort4 o4;
  o4.x = f2bf(x.x);
  o4.y = f2bf(x.y);
  o4.z = f2bf(x.z);
  o4.w = f2bf(x.w);
  *(ushort4*)(out + i) = o4;
}

__global__ __launch_bounds__(256) void cast2_bf16_kernel(const float* __restrict__ in,
                                                         unsigned short* __restrict__ hi,
                                                         unsigned short* __restrict__ lo) {
  const size_t i = ((size_t)blockIdx.x * 256 + threadIdx.x) * 4;
  float4 x = *(const float4*)(in + i);
  ushort4 h4, l4;
  h4.x = f2bf(x.x); l4.x = f2bf(x.x - bf2f(h4.x));
  h4.y = f2bf(x.y); l4.y = f2bf(x.y - bf2f(h4.y));
  h4.z = f2bf(x.z); l4.z = f2bf(x.z - bf2f(h4.z));
  h4.w = f2bf(x.w); l4.w = f2bf(x.w - bf2f(h4.w));
  *(ushort4*)(hi + i) = h4;
  *(ushort4*)(lo + i) = l4;
}

// W [R][C] f32 row-major -> WT [C][R] bf16 (transpose + cast)
__global__ __launch_bounds__(256) void tcast_kernel(const float* __restrict__ W,
                                                    unsigned short* __restrict__ WT,
                                                    int R, int C) {
  __shared__ float tile[32][33];
  const int tx = threadIdx.x, ty = threadIdx.y;
  const int c0 = blockIdx.x * 32, r0 = blockIdx.y * 32;
#pragma unroll
  for (int i = 0; i < 4; ++i)
    tile[ty + 8 * i][tx] = W[(size_t)(r0 + ty + 8 * i) * C + c0 + tx];
  __syncthreads();
#pragma unroll
  for (int i = 0; i < 4; ++i)
    WT[(size_t)(c0 + ty + 8 * i) * R + r0 + tx] = f2bf(tile[tx][ty + 8 * i]);
}

__global__ __launch_bounds__(256) void tcast2_kernel(const float* __restrict__ W,
                                                     unsigned short* __restrict__ WTh,
                                                     unsigned short* __restrict__ WTl,
                                                     int R, int C) {
  __shared__ float tile[32][33];
  const int tx = threadIdx.x, ty = threadIdx.y;
  const int c0 = blockIdx.x * 32, r0 = blockIdx.y * 32;
#pragma unroll
  for (int i = 0; i < 4; ++i)
    tile[ty + 8 * i][tx] = W[(size_t)(r0 + ty + 8 * i) * C + c0 + tx];
  __syncthreads();
#pragma unroll
  for (int i = 0; i < 4; ++i) {
    float x = tile[tx][ty + 8 * i];
    unsigned short h = f2bf(x);
    WTh[(size_t)(c0 + ty + 8 * i) * R + r0 + tx] = h;
    WTl[(size_t)(c0 + ty + 8 * i) * R + r0 + tx] = f2bf(x - bf2f(h));
  }
}

// ---------------- routing: a/beta dots, top-4, silu+norms, dense LOG-decay ----
__global__ __launch_bounds__(256) void routing_kernel(
    const float* __restrict__ hidden, const float* __restrict__ Wa,
    const float* __restrict__ Wb, const float* __restrict__ dt,
    const float* __restrict__ rproj, float* __restrict__ qk,
    float* __restrict__ kk_, float* __restrict__ vv, float* __restrict__ gbuf,
    float* __restrict__ betaT) {
  const int row = blockIdx.x;  // b*T + t
  const int b = row >> 11;
  const int t = row & (TT - 1);
  const int h = threadIdx.x >> 6;
  const int l = threadIdx.x & 63;
  const size_t base = (size_t)row * DD + h * 256;

  const float* hrow = hidden + (size_t)row * DD;
  float aa = 0.f, bb = 0.f;
#pragma unroll
  for (int i = 0; i < 16; ++i) {
    float hv = hrow[l + 64 * i];
    aa = fmaf(hv, Wa[(l + 64 * i) * HH + h], aa);
    bb = fmaf(hv, Wb[(l + 64 * i) * HH + h], bb);
  }
  aa = wave_sum(aa);
  bb = wave_sum(bb);
  float sp = (aa > 20.f) ? aa : log1pf(expf(aa));
  float a_ = -sp * expf(dt[h]);
  float beta = 1.f / (1.f + expf(-bb));
  const int bh = b * HH + h;
  if (l == 0) betaT[(size_t)bh * TT + t] = beta;

  float4 rt4 = *(const float4*)(rproj + base + l * 4);
  float rv[4] = {rt4.x, rt4.y, rt4.z, rt4.w};
  int used = 0;
  int widx[4];
  float wsig[4], wg[4], wkfac[4];
#pragma unroll
  for (int it = 0; it < 4; ++it) {
    float bv = -3.4e38f;
    int bi = 0x7fffffff;
#pragma unroll
    for (int c = 0; c < 4; ++c) {
      bool ok = !(used & (1 << c));
      float v = rv[c];
      if (ok && (v > bv)) {
        bv = v;
        bi = l * 4 + c;
      }
    }
#pragma unroll
    for (int off = 32; off >= 1; off >>= 1) {
      float ov = __shfl_xor(bv, off);
      int oi = __shfl_xor(bi, off);
      if (ov > bv || (ov == bv && oi < bi)) {
        bv = ov;
        bi = oi;
      }
    }
    widx[it] = bi;
    wsig[it] = 1.f / (1.f + expf(-bv));
    if ((bi >> 2) == l) used |= 1 << (bi & 3);
  }
  float wsum = wsig[0] + wsig[1] + wsig[2] + wsig[3] + 1e-6f;
#pragma unroll
  for (int it = 0; it < 4; ++it) {
    float g = a_ * (wsig[it] / wsum);
    wg[it] = g;
    wkfac[it] = 1.f - expf(g);
  }

  float4 kv4 = *(const float4*)(kk_ + base + l * 4);
  float kvv[4] = {kv4.x, kv4.y, kv4.z, kv4.w};
  float kmask[4], ddv[4];
#pragma unroll
  for (int c = 0; c < 4; ++c) {
    int slot = l * 4 + c;
    float f = 0.f, d = 0.f;
#pragma unroll
    for (int it = 0; it < 4; ++it) {
      bool hit = (slot == widx[it]);
      f = hit ? wkfac[it] : f;
      d = hit ? wg[it] : d;
    }
    kmask[c] = siluf(kvv[c]) * f;
    ddv[c] = d;  // log-decay (0 for unselected slots)
  }
  float ss = kmask[0] * kmask[0] + kmask[1] * kmask[1] + kmask[2] * kmask[2] +
             kmask[3] * kmask[3];
  ss = wave_sum(ss);
  float kn = rsqrtf(ss + 1e-6f);
  *(float4*)(kk_ + base + l * 4) =
      make_float4(kmask[0] * kn, kmask[1] * kn, kmask[2] * kn, kmask[3] * kn);
  // g to [bh][T][K] layout
  *(float4*)(gbuf + ((size_t)bh * TT + t) * 256 + l * 4) =
      make_float4(ddv[0], ddv[1], ddv[2], ddv[3]);

  float4 qv4 = *(const float4*)(qk + base + l * 4);
  float qs[4] = {siluf(qv4.x), siluf(qv4.y), siluf(qv4.z), siluf(qv4.w)};
  float qss = qs[0] * qs[0] + qs[1] * qs[1] + qs[2] * qs[2] + qs[3] * qs[3];
  qss = wave_sum(qss);
  float qn = rsqrtf(qss + 1e-6f) * 0.0625f;
  *(float4*)(qk + base + l * 4) =
      make_float4(qs[0] * qn, qs[1] * qn, qs[2] * qn, qs[3] * qn);

  float4 vv4 = *(const float4*)(vv + base + l * 4);
  *(float4*)(vv + base + l * 4) =
      make_float4(siluf(vv4.x), siluf(vv4.y), siluf(vv4.z), siluf(vv4.w));
}

// ---------------- phase A: per-(bh,chunk) cumsum/expc, A=QwX^T, M=WX^T, Tinv ----
// block = (bh,chunk): 512 blocks x 256 threads. LDS 144KB -> 1 block/CU.
__global__ __launch_bounds__(256) void phaseA_kernel(
    const float* __restrict__ kproj, const float* __restrict__ qproj,
    float* __restrict__ expcG,  // in: g, out: exp(cumsum g)  [bh][T][K]
    const float* __restrict__ betaT, float* __restrict__ TinvG,
    float* __restrict__ AG) {
  __shared__ float Xs[64 * 256];   // X = k*exp(-c), swizzled k^(i&31) in 32-blocks
  __shared__ float Ws[64 * 256];   // Qw then W
  __shared__ float buf1[64 * 64];  // partial/final M,A,Tinv; elem (i,s) at i*64+(s^(i&31))
  const int bid = blockIdx.x;
  const int bh = bid >> 5, c = bid & 31;
  const int b = bh >> 2, h = bh & 3;
  const int t0 = c * 64;
  const int tid = threadIdx.x;
  const int wv = tid >> 6, ln = tid & 63;

  // stage1: cumsum -> expc global; X and Qw into LDS
  {
    float cacc = 0.f;
    for (int i = 0; i < 64; ++i) {
      size_t ga = ((size_t)bh * TT + t0 + i) * 256 + tid;
      size_t pa = (((size_t)b * TT + t0 + i) * HH + h) * 256 + tid;
      cacc += expcG[ga];
      float e = expf(cacc);
      expcG[ga] = e;
      float kv = kproj[pa], qv = qproj[pa];
      int ks = (tid & ~31) | ((tid & 31) ^ (i & 31));
      Xs[i * 256 + ks] = kv * __builtin_amdgcn_rcpf(e);
      Ws[i * 256 + ks] = qv * e;  // Qw
    }
  }
  __syncthreads();

  float acc[64];
  // ---- A = Qw X^T (waves 0,1 over k halves; lane = row i) ----
  if (wv < 2) {
#pragma unroll
    for (int s = 0; s < 64; ++s) acc[s] = 0.f;
    for (int kk = wv * 128; kk < wv * 128 + 128; ++kk) {
      int khi = kk & ~31, klo = kk & 31;
      float wq = Ws[ln * 256 + (khi | (klo ^ (ln & 31)))];
#pragma unroll
      for (int s = 0; s < 64; ++s)
        acc[s] = fmaf(wq, Xs[s * 256 + (khi | (klo ^ (s & 31)))], acc[s]);
    }
    if (wv == 1) {
#pragma unroll
      for (int s = 0; s < 64; ++s) buf1[ln * 64 + (s ^ (ln & 31))] = acc[s];
    }
  }
  __syncthreads();
  if (wv == 0) {
#pragma unroll
    for (int s = 0; s < 64; ++s) {
      float v = acc[s] + buf1[ln * 64 + (s ^ (ln & 31))];
      buf1[ln * 64 + (s ^ (ln & 31))] = v;
    }
  }
  __syncthreads();
  // write A (mask s<=i) + restage Ws = W = k*expc
  {
    int i = tid >> 2;
    size_t gb = (((size_t)bh * 32 + c) << 12) + (size_t)tid * 16;
#pragma unroll
    for (int mq = 0; mq < 4; ++mq) {
      int sb = (tid & 3) * 16 + mq * 4;
      float4 v;
      v.x = (sb + 0 <= i) ? buf1[i * 64 + ((sb + 0) ^ (i & 31))] : 0.f;
      v.y = (sb + 1 <= i) ? buf1[i * 64 + ((sb + 1) ^ (i & 31))] : 0.f;
      v.z = (sb + 2 <= i) ? buf1[i * 64 + ((sb + 2) ^ (i & 31))] : 0.f;
      v.w = (sb + 3 <= i) ? buf1[i * 64 + ((sb + 3) ^ (i & 31))] : 0.f;
      *(float4*)(AG + gb + mq * 4) = v;
    }
    for (int ii = 0; ii < 64; ++ii) {
      size_t ga = ((size_t)bh * TT + t0 + ii) * 256 + tid;
      size_t pa = (((size_t)b * TT + t0 + ii) * HH + h) * 256 + tid;
      float e = expcG[ga];
      float kv = kproj[pa];
      Ws[ii * 256 + ((tid & ~31) | ((tid & 31) ^ (ii & 31)))] = kv * e;
    }
  }
  __syncthreads();
  // ---- M = W X^T ----
  if (wv < 2) {
#pragma unroll
    for (int s = 0; s < 64; ++s) acc[s] = 0.f;
    for (int kk = wv * 128; kk < wv * 128 + 128; ++kk) {
      int khi = kk & ~31, klo = kk & 31;
      float wq = Ws[ln * 256 + (khi | (klo ^ (ln & 31)))];
#pragma unroll
      for (int s = 0; s < 64; ++s)
        acc[s] = fmaf(wq, Xs[s * 256 + (khi | (klo ^ (s & 31)))], acc[s]);
    }
    if (wv == 1) {
#pragma unroll
      for (int s = 0; s < 64; ++s) buf1[ln * 64 + (s ^ (ln & 31))] = acc[s];
    }
  }
  __syncthreads();
  if (wv == 0) {
#pragma unroll
    for (int s = 0; s < 64; ++s) {
      float v = acc[s] + buf1[ln * 64 + (s ^ (ln & 31))];
      buf1[ln * 64 + (s ^ (ln & 31))] = v;
    }
  }
  __syncthreads();
  // ---- Tinv = (I + diag(beta) M)^{-1}: wave 0, column ln in registers ----
  if (wv == 0) {
    float tcol[64];
#pragma unroll
    for (int i = 0; i < 64; ++i) {
      float bi = betaT[(size_t)bh * TT + t0 + i];
      float a_ = (ln == i) ? 1.f : 0.f;
#pragma unroll
      for (int s = 0; s < i; ++s) {
        float m = buf1[i * 64 + (s ^ (i & 31))];  // uniform bcast
        a_ = fmaf(-bi * m, tcol[s], a_);
      }
      tcol[i] = a_;
    }
#pragma unroll
    for (int s = 0; s < 64; ++s)
      buf1[s * 64 + (ln ^ (s & 31))] = tcol[s];
  }
  __syncthreads();
  // write Tinv
  {
    int i = tid >> 2;
    size_t gb = (((size_t)bh * 32 + c) << 12) + (size_t)tid * 16;
#pragma unroll
    for (int mq = 0; mq < 4; ++mq) {
      int sb = (tid & 3) * 16 + mq * 4;
      float4 v;
      v.x = buf1[i * 64 + ((sb + 0) ^ (i & 31))];
      v.y = buf1[i * 64 + ((sb + 1) ^ (i & 31))];
      v.z = buf1[i * 64 + ((sb + 2) ^ (i & 31))];
      v.w = buf1[i * 64 + ((sb + 3) ^ (i & 31))];
      *(float4*)(TinvG + gb + mq * 4) = v;
    }
  }
}

// ---------------- phase B: sequential over 32 chunks; block=(bh,vslice16) ----
// 256 blocks x 256 threads, 1 block/CU (152KB LDS). S[256][16] in registers
// (thread tid owns k-row tid). Per chunk: RHS=W@S, U=Tinv@(beta(V-RHS)),
// O=Qw@S + A@U, S = expcL*(S + X^T U).
__global__ __launch_bounds__(256) void chunk_scan_kernel(
    const float* __restrict__ kproj, const float* __restrict__ qproj,
    const float* __restrict__ vproj, const float* __restrict__ expcG,
    const float* __restrict__ betaT, const float* __restrict__ TinvG,
    const float* __restrict__ AG, float* __restrict__ obuf) {
  __shared__ unsigned Wl[64 * 128];        // bf16x2: W=k*e  [row][kw ^ row&31]
  __shared__ unsigned Ql[64 * 128];        // bf16x2: Qw=q*e
  __shared__ unsigned short Xl[256 * 64];  // bf16: X^T-ish [k][t], tw^(k>>1 &31)
  __shared__ float Slds[256 * 16];
  __shared__ float R2l[64 * 20];
  __shared__ float Ul[64 * 20];
  __shared__ float Tl[64 * 64];  // (r,s) at r*64 + (s ^ ((r&7)<<3))
  __shared__ float Al[64 * 64];
  const int bid = blockIdx.x;
  const int bh = bid & 15, slice = bid >> 4;  // same-bh blocks -> same XCD (%8)
  const int b = bh >> 2, h = bh & 3;
  const int tid = threadIdx.x;
  const int tr = tid >> 2, jp = tid & 3, j0 = jp * 4;
  const int ih = tid >> 7, kw_s = tid & 127;

  float S[16];
#pragma unroll
  for (int j = 0; j < 16; ++j) S[j] = 0.f;

  for (int c = 0; c < 32; ++c) {
    const int t0 = c * 64;
    // ---- phase 0: S->LDS, stage W/Q/X, stage Tinv/A ----
#pragma unroll
    for (int jq = 0; jq < 4; ++jq)
      *(float4*)(&Slds[tid * 16 + jq * 4]) =
          make_float4(S[jq * 4 + 0], S[jq * 4 + 1], S[jq * 4 + 2], S[jq * 4 + 3]);
    for (int ii = ih; ii < 64; ii += 2) {
      size_t pr = (((size_t)b * TT + t0 + ii) * HH + h) * 256 + 2 * kw_s;
      size_t er = ((size_t)bh * TT + t0 + ii) * 256 + 2 * kw_s;
      float2 kv = *(const float2*)(kproj + pr);
      float2 qv = *(const float2*)(qproj + pr);
      float2 ev = *(const float2*)(expcG + er);
      int ks = (kw_s & ~31) | ((kw_s & 31) ^ (ii & 31));
      Wl[ii * 128 + ks] = pack2(kv.x * ev.x, kv.y * ev.y);
      Ql[ii * 128 + ks] = pack2(qv.x * ev.x, qv.y * ev.y);
      float r0 = __builtin_amdgcn_rcpf(ev.x), r1 = __builtin_amdgcn_rcpf(ev.y);
      int twsw = (ii >> 1) ^ (kw_s & 31);
      Xl[((2 * kw_s) * 32 + twsw) * 2 + (ii & 1)] = f2bf(kv.x * r0);
      Xl[((2 * kw_s + 1) * 32 + twsw) * 2 + (ii & 1)] = f2bf(kv.y * r1);
    }
    {
      size_t gb = (((size_t)bh * 32 + c) << 12) + (size_t)tid * 16;
#pragma unroll
      for (int mq = 0; mq < 4; ++mq) {
        float4 tv = *(const float4*)(TinvG + gb + mq * 4);
        float4 av = *(const float4*)(AG + gb + mq * 4);
        int sb = (tid & 3) * 16 + mq * 4;
        int sw = sb ^ ((tr & 7) << 3);
        *(float4*)(&Tl[tr * 64 + sw]) = tv;
        *(float4*)(&Al[tr * 64 + sw]) = av;
      }
    }
    __syncthreads();
    // ---- (a) RHS = W@Sin, Oq = Qw@Sin ----
    float rhs0 = 0, rhs1 = 0, rhs2 = 0, rhs3 = 0;
    float oq0 = 0, oq1 = 0, oq2 = 0, oq3 = 0;
    if (c > 0) {
#pragma unroll 4
      for (int kw = 0; kw < 128; ++kw) {
        int ks = (kw & ~31) | ((kw & 31) ^ (tr & 31));
        unsigned ww = Wl[tr * 128 + ks], qq = Ql[tr * 128 + ks];
        float w0 = __uint_as_float(ww << 16);
        float w1 = __uint_as_float(ww & 0xffff0000u);
        float q0 = __uint_as_float(qq << 16);
        float q1 = __uint_as_float(qq & 0xffff0000u);
        float4 s0 = *(const float4*)(&Slds[(2 * kw) * 16 + j0]);
        float4 s1 = *(const float4*)(&Slds[(2 * kw + 1) * 16 + j0]);
        rhs0 = fmaf(w0, s0.x, rhs0); rhs1 = fmaf(w0, s0.y, rhs1);
        rhs2 = fmaf(w0, s0.z, rhs2); rhs3 = fmaf(w0, s0.w, rhs3);
        rhs0 = fmaf(w1, s1.x, rhs0); rhs1 = fmaf(w1, s1.y, rhs1);
        rhs2 = fmaf(w1, s1.z, rhs2); rhs3 = fmaf(w1, s1.w, rhs3);
        oq0 = fmaf(q0, s0.x, oq0); oq1 = fmaf(q0, s0.y, oq1);
        oq2 = fmaf(q0, s0.z, oq2); oq3 = fmaf(q0, s0.w, oq3);
        oq0 = fmaf(q1, s1.x, oq0); oq1 = fmaf(q1, s1.y, oq1);
        oq2 = fmaf(q1, s1.z, oq2); oq3 = fmaf(q1, s1.w, oq3);
      }
    }
    // ---- R2 = beta*(V - RHS) ----
    {
      float beta_r = betaT[(size_t)bh * TT + t0 + tr];
      float4 vv = *(const float4*)(vproj + (((size_t)b * TT + t0 + tr) * HH + h) * 256 +
                                   slice * 16 + j0);
      *(float4*)(&R2l[tr * 20 + j0]) =
          make_float4(beta_r * (vv.x - rhs0), beta_r * (vv.y - rhs1),
                      beta_r * (vv.z - rhs2), beta_r * (vv.w - rhs3));
    }
    __syncthreads();
    // ---- (b) U = Tinv @ R2 ----
    {
      float u0 = 0, u1 = 0, u2 = 0, u3 = 0;
#pragma unroll 4
      for (int sq = 0; sq < 16; ++sq) {
        float4 t4 = *(const float4*)(&Tl[tr * 64 + ((sq * 4) ^ ((tr & 7) << 3))]);
        float4 r0 = *(const float4*)(&R2l[(sq * 4 + 0) * 20 + j0]);
        float4 r1 = *(const float4*)(&R2l[(sq * 4 + 1) * 20 + j0]);
        float4 r2 = *(const float4*)(&R2l[(sq * 4 + 2) * 20 + j0]);
        float4 r3 = *(const float4*)(&R2l[(sq * 4 + 3) * 20 + j0]);
        u0 = fmaf(t4.x, r0.x, u0); u1 = fmaf(t4.x, r0.y, u1);
        u2 = fmaf(t4.x, r0.z, u2); u3 = fmaf(t4.x, r0.w, u3);
        u0 = fmaf(t4.y, r1.x, u0); u1 = fmaf(t4.y, r1.y, u1);
        u2 = fmaf(t4.y, r1.z, u2); u3 = fmaf(t4.y, r1.w, u3);
        u0 = fmaf(t4.z, r2.x, u0); u1 = fmaf(t4.z, r2.y, u1);
        u2 = fmaf(t4.z, r2.z, u2); u3 = fmaf(t4.z, r2.w, u3);
        u0 = fmaf(t4.w, r3.x, u0); u1 = fmaf(t4.w, r3.y, u1);
        u2 = fmaf(t4.w, r3.z, u2); u3 = fmaf(t4.w, r3.w, u3);
      }
      *(float4*)(&Ul[tr * 20 + j0]) = make_float4(u0, u1, u2, u3);
    }
    __syncthreads();
    // ---- (c2) O = Oq + A@U -> global ----
    {
      float o0 = oq0, o1 = oq1, o2 = oq2, o3 = oq3;
#pragma unroll 4
      for (int sq = 0; sq < 16; ++sq) {
        float4 a4 = *(const float4*)(&Al[tr * 64 + ((sq * 4) ^ ((tr & 7) << 3))]);
        float4 r0 = *(const float4*)(&Ul[(sq * 4 + 0) * 20 + j0]);
        float4 r1 = *(const float4*)(&Ul[(sq * 4 + 1) * 20 + j0]);
        float4 r2 = *(const float4*)(&Ul[(sq * 4 + 2) * 20 + j0]);
        float4 r3 = *(const float4*)(&Ul[(sq * 4 + 3) * 20 + j0]);
        o0 = fmaf(a4.x, r0.x, o0); o1 = fmaf(a4.x, r0.y, o1);
        o2 = fmaf(a4.x, r0.z, o2); o3 = fmaf(a4.x, r0.w, o3);
        o0 = fmaf(a4.y, r1.x, o0); o1 = fmaf(a4.y, r1.y, o1);
        o2 = fmaf(a4.y, r1.z, o2); o3 = fmaf(a4.y, r1.w, o3);
        o0 = fmaf(a4.z, r2.x, o0); o1 = fmaf(a4.z, r2.y, o1);
        o2 = fmaf(a4.z, r2.z, o2); o3 = fmaf(a4.z, r2.w, o3);
        o0 = fmaf(a4.w, r3.x, o0); o1 = fmaf(a4.w, r3.y, o1);
        o2 = fmaf(a4.w, r3.z, o2); o3 = fmaf(a4.w, r3.w, o3);
      }
      *(float4*)(obuf + (((size_t)b * TT + t0 + tr) * HH + h) * 256 + slice * 16 + j0) =
          make_float4(o0, o1, o2, o3);
    }
    // ---- (d) S = expcL * (S + X^T U)  (thread tid = k-row) ----
    {
#pragma unroll 4
      for (int t = 0; t < 64; t += 2) {
        unsigned xw = ((const unsigned*)Xl)[(tid << 5) + ((t >> 1) ^ ((tid >> 1) & 31))];
        float x0 = __uint_as_float(xw << 16);
        float x1 = __uint_as_float(xw & 0xffff0000u);
        const float* u0p = &Ul[t * 20];
        const float* u1p = &Ul[(t + 1) * 20];
#pragma unroll
        for (int jq = 0; jq < 4; ++jq) {
          float4 a4 = *(const float4*)(u0p + jq * 4);
          float4 b4 = *(const float4*)(u1p + jq * 4);
          S[jq * 4 + 0] = fmaf(x0, a4.x, S[jq * 4 + 0]);
          S[jq * 4 + 1] = fmaf(x0, a4.y, S[jq * 4 + 1]);
          S[jq * 4 + 2] = fmaf(x0, a4.z, S[jq * 4 + 2]);
          S[jq * 4 + 3] = fmaf(x0, a4.w, S[jq * 4 + 3]);
          S[jq * 4 + 0] = fmaf(x1, b4.x, S[jq * 4 + 0]);
          S[jq * 4 + 1] = fmaf(x1, b4.y, S[jq * 4 + 1]);
          S[jq * 4 + 2] = fmaf(x1, b4.z, S[jq * 4 + 2]);
          S[jq * 4 + 3] = fmaf(x1, b4.w, S[jq * 4 + 3]);
        }
      }
      float eL = expcG[((size_t)bh * TT + t0 + 63) * 256 + tid];
#pragma unroll
      for (int j = 0; j < 16; ++j) S[j] *= eL;
    }
    __syncthreads();
  }
}

// ---------------- per-head RMSNorm ----------------
__global__ __launch_bounds__(256) void rmsnorm_kernel(
    const float* __restrict__ o, const float* __restrict__ w,
    float* __restrict__ out) {
  const int row = blockIdx.x;
  const int l = threadIdx.x & 63;
  const size_t base = (size_t)row * DD + (threadIdx.x >> 6) * 256 + l * 4;
  float4 x = *(const float4*)(o + base);
  float ss = x.x * x.x + x.y * x.y + x.z * x.z + x.w * x.w;
  ss = wave_sum(ss);
  float sc = rsqrtf(ss * (1.f / 256.f) + 1e-5f);
  float4 wv = *(const float4*)(w + l * 4);
  *(float4*)(out + base) = make_float4(x.x * sc * wv.x, x.y * sc * wv.y,
                                       x.z * sc * wv.z, x.w * sc * wv.w);
}

extern "C" void kernel_launch(void* const* d_in, const int* in_sizes, int n_in,
                              void* d_out, int out_size, void* d_ws,
                              size_t ws_size, hipStream_t stream) {
  const float* hidden = (const float*)d_in[0];
  const float* Wq = (const float*)d_in[1];
  const float* Wk = (const float*)d_in[2];
  const float* Wv = (const float*)d_in[3];
  const float* Wa = (const float*)d_in[4];
  const float* Wr = (const float*)d_in[5];
  const float* Wb = (const float*)d_in[6];
  const float* dt = (const float*)d_in[7];
  const float* norm_w = (const float*)d_in[8];
  const float* Wo = (const float*)d_in[9];
  float* out = (float*)d_out;

  const size_t NP = (size_t)BB * TT * DD;  // 8388608
  float* ws = (float*)d_ws;
  float* qproj = ws;
  float* kproj = ws + NP;
  float* vproj = ws + 2 * NP;
  float* gbuf = ws + 3 * NP;         // g -> expc [bh][T][K]
  float* TinvG = ws + 4 * NP;        // 16*32*4096
  float* AG = TinvG + (16 * 32 * 4096);
  float* betaT = AG + (16 * 32 * 4096);
  unsigned short* wT = (unsigned short*)(betaT + 16 * TT);
  unsigned short* WT0 = wT;
  unsigned short* WT1 = wT + 1048576;
  unsigned short* WT2 = wT + 2 * 1048576;
  unsigned short* WT3 = wT + 3 * 1048576;
  unsigned short* WT4 = wT + 4 * 1048576;
  unsigned short* WT5 = wT + 5 * 1048576;
  unsigned short* hbf = (unsigned short*)gbuf;   // alias: dead before routing
  unsigned short* hlo = (unsigned short*)qproj;  // alias: dead before q-GEMM
  float* rproj = out;
  float* normed = qproj;

  dim3 bt(256);
  cast2_bf16_kernel<<<8192, 256, 0, stream>>>(hidden, hbf, hlo);
  dim3 tg(32, 32), tb(32, 8);
  tcast2_kernel<<<tg, tb, 0, stream>>>(Wr, WT4, WT5, 1024, 1024);
  tcast_kernel<<<tg, tb, 0, stream>>>(Wq, WT0, 1024, 1024);
  tcast_kernel<<<tg, tb, 0, stream>>>(Wk, WT1, 1024, 1024);
  tcast_kernel<<<tg, tb, 0, stream>>>(Wv, WT2, 1024, 1024);
  tcast_kernel<<<tg, tb, 0, stream>>>(Wo, WT3, 1024, 1024);

  dim3 gmm(1024 / 128, 8192 / 128);
  gemm_bt3<<<gmm, bt, 0, stream>>>(hbf, hlo, WT4, WT5, rproj, 8192, 1024, 1024);
  gemm_bt<<<gmm, bt, 0, stream>>>(hbf, WT0, qproj, 8192, 1024, 1024);
  gemm_bt<<<gmm, bt, 0, stream>>>(hbf, WT1, kproj, 8192, 1024, 1024);
  gemm_bt<<<gmm, bt, 0, stream>>>(hbf, WT2, vproj, 8192, 1024, 1024);

  routing_kernel<<<8192, 256, 0, stream>>>(hidden, Wa, Wb, dt, rproj, qproj,
                                           kproj, vproj, gbuf, betaT);
  phaseA_kernel<<<512, 256, 0, stream>>>(kproj, qproj, gbuf, betaT, TinvG, AG);
  chunk_scan_kernel<<<256, 256, 0, stream>>>(kproj, qproj, vproj, gbuf, betaT,
                                             TinvG, AG, out);
  rmsnorm_kernel<<<8192, 256, 0, stream>>>(out, norm_w, normed);
  cast_bf16_kernel<<<8192, 256, 0, stream>>>(normed, hbf);
  gemm_bt<<<gmm, bt, 0, stream>>>(hbf, WT3, out, 8192, 1024, 1024);
}

// Round 5
// 1147.356 us; speedup vs baseline: 3.2233x; 1.4282x over previous
//
#include <hip/hip_runtime.h>
#include <hip/hip_bf16.h>

#define TT 2048
#define BB 4
#define HH 4
#define DD 1024

using bf16x8 = __attribute__((ext_vector_type(8))) short;
using f32x4  = __attribute__((ext_vector_type(4))) float;

__device__ __forceinline__ float wave_sum(float x) {
#pragma unroll
  for (int off = 32; off >= 1; off >>= 1) x += __shfl_xor(x, off);
  return x;
}

__device__ __forceinline__ float siluf(float x) {
  return x / (1.f + expf(-x));
}

__device__ __forceinline__ unsigned short f2bf(float f) {
  unsigned u = __float_as_uint(f);
  u = (u + 0x7fffu + ((u >> 16) & 1u)) >> 16;
  return (unsigned short)u;
}
__device__ __forceinline__ float bf2f(unsigned short b) {
  return __uint_as_float(((unsigned)b) << 16);
}
__device__ __forceinline__ unsigned pack2(float a, float b) {
  return ((unsigned)f2bf(a)) | (((unsigned)f2bf(b)) << 16);
}

// ---------------- bf16 MFMA GEMM: C[M,N] = A[M,K] @ B[K,N], Bt is [N][K] ----
__global__ __launch_bounds__(256) void gemm_bt(const unsigned short* __restrict__ A,
                                               const unsigned short* __restrict__ Bt,
                                               float* __restrict__ C,
                                               int M, int N, int K) {
  __shared__ unsigned short As[128 * 64];
  __shared__ unsigned short Bs[128 * 64];
  const int tid = threadIdx.x;
  const int l = tid & 63;
  const int w = tid >> 6;
  const int wm = w >> 1, wn = w & 1;
  const int m0 = blockIdx.y * 128, n0 = blockIdx.x * 128;

  f32x4 acc[4][4];
#pragma unroll
  for (int i = 0; i < 4; ++i)
#pragma unroll
    for (int j = 0; j < 4; ++j) acc[i][j] = (f32x4){0.f, 0.f, 0.f, 0.f};

  int c_row[4], c_slot[4], c_dst[4];
#pragma unroll
  for (int it = 0; it < 4; ++it) {
    int chunk = it * 256 + tid;
    int row = chunk >> 3, s = chunk & 7;
    c_row[it] = row;
    c_slot[it] = s;
    c_dst[it] = row * 128 + ((s ^ (row & 7)) << 4);
  }
  int ra_off[2][4], rb_off[2][4];
#pragma unroll
  for (int kh = 0; kh < 2; ++kh)
#pragma unroll
    for (int f = 0; f < 4; ++f) {
      int rowA = wm * 64 + f * 16 + (l & 15);
      ra_off[kh][f] = rowA * 128 + (((kh * 4 + (l >> 4)) ^ (rowA & 7)) << 4);
      int rowB = wn * 64 + f * 16 + (l & 15);
      rb_off[kh][f] = rowB * 128 + (((kh * 4 + (l >> 4)) ^ (rowB & 7)) << 4);
    }

  for (int k0 = 0; k0 < K; k0 += 64) {
    uint4 ra[4], rb[4];
#pragma unroll
    for (int it = 0; it < 4; ++it) {
      ra[it] = *(const uint4*)(A + (size_t)(m0 + c_row[it]) * K + k0 + c_slot[it] * 8);
      rb[it] = *(const uint4*)(Bt + (size_t)(n0 + c_row[it]) * K + k0 + c_slot[it] * 8);
    }
    __syncthreads();
#pragma unroll
    for (int it = 0; it < 4; ++it) {
      *(uint4*)((char*)As + c_dst[it]) = ra[it];
      *(uint4*)((char*)Bs + c_dst[it]) = rb[it];
    }
    __syncthreads();
#pragma unroll
    for (int kh = 0; kh < 2; ++kh) {
      bf16x8 af[4], bfv[4];
#pragma unroll
      for (int f = 0; f < 4; ++f) {
        af[f] = *(const bf16x8*)((const char*)As + ra_off[kh][f]);
        bfv[f] = *(const bf16x8*)((const char*)Bs + rb_off[kh][f]);
      }
#pragma unroll
      for (int i = 0; i < 4; ++i)
#pragma unroll
        for (int j = 0; j < 4; ++j)
          acc[i][j] = __builtin_amdgcn_mfma_f32_16x16x32_bf16(af[i], bfv[j],
                                                              acc[i][j], 0, 0, 0);
    }
  }
  const int cn = n0 + wn * 64 + (l & 15);
  const int rbase = m0 + wm * 64 + ((l >> 4) << 2);
#pragma unroll
  for (int i = 0; i < 4; ++i)
#pragma unroll
    for (int j = 0; j < 4; ++j)
#pragma unroll
      for (int r = 0; r < 4; ++r)
        C[(size_t)(rbase + i * 16 + r) * N + cn + j * 16] = acc[i][j][r];
}

// ------------- split-bf16 3-term GEMM (fp32-accurate): C = Ah@Bh+Al@Bh+Ah@Bl
__global__ __launch_bounds__(256) void gemm_bt3(const unsigned short* __restrict__ Ah,
                                                const unsigned short* __restrict__ Al,
                                                const unsigned short* __restrict__ Bh,
                                                const unsigned short* __restrict__ Bl,
                                                float* __restrict__ C,
                                                int M, int N, int K) {
  __shared__ unsigned short Ash[128 * 64];
  __shared__ unsigned short Asl[128 * 64];
  __shared__ unsigned short Bsh[128 * 64];
  __shared__ unsigned short Bsl[128 * 64];
  const int tid = threadIdx.x;
  const int l = tid & 63;
  const int w = tid >> 6;
  const int wm = w >> 1, wn = w & 1;
  const int m0 = blockIdx.y * 128, n0 = blockIdx.x * 128;

  f32x4 acc[4][4];
#pragma unroll
  for (int i = 0; i < 4; ++i)
#pragma unroll
    for (int j = 0; j < 4; ++j) acc[i][j] = (f32x4){0.f, 0.f, 0.f, 0.f};

  int c_row[4], c_slot[4], c_dst[4];
#pragma unroll
  for (int it = 0; it < 4; ++it) {
    int chunk = it * 256 + tid;
    int row = chunk >> 3, s = chunk & 7;
    c_row[it] = row;
    c_slot[it] = s;
    c_dst[it] = row * 128 + ((s ^ (row & 7)) << 4);
  }
  int ra_off[2][4], rb_off[2][4];
#pragma unroll
  for (int kh = 0; kh < 2; ++kh)
#pragma unroll
    for (int f = 0; f < 4; ++f) {
      int rowA = wm * 64 + f * 16 + (l & 15);
      ra_off[kh][f] = rowA * 128 + (((kh * 4 + (l >> 4)) ^ (rowA & 7)) << 4);
      int rowB = wn * 64 + f * 16 + (l & 15);
      rb_off[kh][f] = rowB * 128 + (((kh * 4 + (l >> 4)) ^ (rowB & 7)) << 4);
    }

  for (int k0 = 0; k0 < K; k0 += 64) {
    uint4 rah[4], ral[4], rbh[4], rbl[4];
#pragma unroll
    for (int it = 0; it < 4; ++it) {
      size_t aoff = (size_t)(m0 + c_row[it]) * K + k0 + c_slot[it] * 8;
      size_t boff = (size_t)(n0 + c_row[it]) * K + k0 + c_slot[it] * 8;
      rah[it] = *(const uint4*)(Ah + aoff);
      ral[it] = *(const uint4*)(Al + aoff);
      rbh[it] = *(const uint4*)(Bh + boff);
      rbl[it] = *(const uint4*)(Bl + boff);
    }
    __syncthreads();
#pragma unroll
    for (int it = 0; it < 4; ++it) {
      *(uint4*)((char*)Ash + c_dst[it]) = rah[it];
      *(uint4*)((char*)Asl + c_dst[it]) = ral[it];
      *(uint4*)((char*)Bsh + c_dst[it]) = rbh[it];
      *(uint4*)((char*)Bsl + c_dst[it]) = rbl[it];
    }
    __syncthreads();
#pragma unroll
    for (int kh = 0; kh < 2; ++kh) {
      bf16x8 afh[4], bfh[4], tmp[4];
#pragma unroll
      for (int f = 0; f < 4; ++f) {
        afh[f] = *(const bf16x8*)((const char*)Ash + ra_off[kh][f]);
        bfh[f] = *(const bf16x8*)((const char*)Bsh + rb_off[kh][f]);
      }
#pragma unroll
      for (int i = 0; i < 4; ++i)
#pragma unroll
        for (int j = 0; j < 4; ++j)
          acc[i][j] = __builtin_amdgcn_mfma_f32_16x16x32_bf16(afh[i], bfh[j],
                                                              acc[i][j], 0, 0, 0);
#pragma unroll
      for (int f = 0; f < 4; ++f)
        tmp[f] = *(const bf16x8*)((const char*)Asl + ra_off[kh][f]);
#pragma unroll
      for (int i = 0; i < 4; ++i)
#pragma unroll
        for (int j = 0; j < 4; ++j)
          acc[i][j] = __builtin_amdgcn_mfma_f32_16x16x32_bf16(tmp[i], bfh[j],
                                                              acc[i][j], 0, 0, 0);
#pragma unroll
      for (int f = 0; f < 4; ++f)
        tmp[f] = *(const bf16x8*)((const char*)Bsl + rb_off[kh][f]);
#pragma unroll
      for (int i = 0; i < 4; ++i)
#pragma unroll
        for (int j = 0; j < 4; ++j)
          acc[i][j] = __builtin_amdgcn_mfma_f32_16x16x32_bf16(afh[i], tmp[j],
                                                              acc[i][j], 0, 0, 0);
    }
  }
  const int cn = n0 + wn * 64 + (l & 15);
  const int rbase = m0 + wm * 64 + ((l >> 4) << 2);
#pragma unroll
  for (int i = 0; i < 4; ++i)
#pragma unroll
    for (int j = 0; j < 4; ++j)
#pragma unroll
      for (int r = 0; r < 4; ++r)
        C[(size_t)(rbase + i * 16 + r) * N + cn + j * 16] = acc[i][j][r];
}

// ---------------- casts ----------------
__global__ __launch_bounds__(256) void cast_bf16_kernel(const float* __restrict__ in,
                                                        unsigned short* __restrict__ out) {
  const size_t i = ((size_t)blockIdx.x * 256 + threadIdx.x) * 4;
  float4 x = *(const float4*)(in + i);
  ushort4 o4;
  o4.x = f2bf(x.x);
  o4.y = f2bf(x.y);
  o4.z = f2bf(x.z);
  o4.w = f2bf(x.w);
  *(ushort4*)(out + i) = o4;
}

__global__ __launch_bounds__(256) void cast2_bf16_kernel(const float* __restrict__ in,
                                                         unsigned short* __restrict__ hi,
                                                         unsigned short* __restrict__ lo) {
  const size_t i = ((size_t)blockIdx.x * 256 + threadIdx.x) * 4;
  float4 x = *(const float4*)(in + i);
  ushort4 h4, l4;
  h4.x = f2bf(x.x); l4.x = f2bf(x.x - bf2f(h4.x));
  h4.y = f2bf(x.y); l4.y = f2bf(x.y - bf2f(h4.y));
  h4.z = f2bf(x.z); l4.z = f2bf(x.z - bf2f(h4.z));
  h4.w = f2bf(x.w); l4.w = f2bf(x.w - bf2f(h4.w));
  *(ushort4*)(hi + i) = h4;
  *(ushort4*)(lo + i) = l4;
}

// W [R][C] f32 row-major -> WT [C][R] bf16 (transpose + cast)
__global__ __launch_bounds__(256) void tcast_kernel(const float* __restrict__ W,
                                                    unsigned short* __restrict__ WT,
                                                    int R, int C) {
  __shared__ float tile[32][33];
  const int tx = threadIdx.x, ty = threadIdx.y;
  const int c0 = blockIdx.x * 32, r0 = blockIdx.y * 32;
#pragma unroll
  for (int i = 0; i < 4; ++i)
    tile[ty + 8 * i][tx] = W[(size_t)(r0 + ty + 8 * i) * C + c0 + tx];
  __syncthreads();
#pragma unroll
  for (int i = 0; i < 4; ++i)
    WT[(size_t)(c0 + ty + 8 * i) * R + r0 + tx] = f2bf(tile[tx][ty + 8 * i]);
}

__global__ __launch_bounds__(256) void tcast2_kernel(const float* __restrict__ W,
                                                     unsigned short* __restrict__ WTh,
                                                     unsigned short* __restrict__ WTl,
                                                     int R, int C) {
  __shared__ float tile[32][33];
  const int tx = threadIdx.x, ty = threadIdx.y;
  const int c0 = blockIdx.x * 32, r0 = blockIdx.y * 32;
#pragma unroll
  for (int i = 0; i < 4; ++i)
    tile[ty + 8 * i][tx] = W[(size_t)(r0 + ty + 8 * i) * C + c0 + tx];
  __syncthreads();
#pragma unroll
  for (int i = 0; i < 4; ++i) {
    float x = tile[tx][ty + 8 * i];
    unsigned short h = f2bf(x);
    WTh[(size_t)(c0 + ty + 8 * i) * R + r0 + tx] = h;
    WTl[(size_t)(c0 + ty + 8 * i) * R + r0 + tx] = f2bf(x - bf2f(h));
  }
}

// ---------------- routing: a/beta dots, top-4, silu+norms, dense LOG-decay ----
__global__ __launch_bounds__(256) void routing_kernel(
    const float* __restrict__ hidden, const float* __restrict__ Wa,
    const float* __restrict__ Wb, const float* __restrict__ dt,
    const float* __restrict__ rproj, float* __restrict__ qk,
    float* __restrict__ kk_, float* __restrict__ vv, float* __restrict__ gbuf,
    float* __restrict__ betaT) {
  const int row = blockIdx.x;  // b*T + t
  const int b = row >> 11;
  const int t = row & (TT - 1);
  const int h = threadIdx.x >> 6;
  const int l = threadIdx.x & 63;
  const size_t base = (size_t)row * DD + h * 256;

  const float* hrow = hidden + (size_t)row * DD;
  float aa = 0.f, bb = 0.f;
#pragma unroll
  for (int i = 0; i < 16; ++i) {
    float hv = hrow[l + 64 * i];
    aa = fmaf(hv, Wa[(l + 64 * i) * HH + h], aa);
    bb = fmaf(hv, Wb[(l + 64 * i) * HH + h], bb);
  }
  aa = wave_sum(aa);
  bb = wave_sum(bb);
  float sp = (aa > 20.f) ? aa : log1pf(expf(aa));
  float a_ = -sp * expf(dt[h]);
  float beta = 1.f / (1.f + expf(-bb));
  const int bh = b * HH + h;
  if (l == 0) betaT[(size_t)bh * TT + t] = beta;

  float4 rt4 = *(const float4*)(rproj + base + l * 4);
  float rv[4] = {rt4.x, rt4.y, rt4.z, rt4.w};
  int used = 0;
  int widx[4];
  float wsig[4], wg[4], wkfac[4];
#pragma unroll
  for (int it = 0; it < 4; ++it) {
    float bv = -3.4e38f;
    int bi = 0x7fffffff;
#pragma unroll
    for (int c = 0; c < 4; ++c) {
      bool ok = !(used & (1 << c));
      float v = rv[c];
      if (ok && (v > bv)) {
        bv = v;
        bi = l * 4 + c;
      }
    }
#pragma unroll
    for (int off = 32; off >= 1; off >>= 1) {
      float ov = __shfl_xor(bv, off);
      int oi = __shfl_xor(bi, off);
      if (ov > bv || (ov == bv && oi < bi)) {
        bv = ov;
        bi = oi;
      }
    }
    widx[it] = bi;
    wsig[it] = 1.f / (1.f + expf(-bv));
    if ((bi >> 2) == l) used |= 1 << (bi & 3);
  }
  float wsum = wsig[0] + wsig[1] + wsig[2] + wsig[3] + 1e-6f;
#pragma unroll
  for (int it = 0; it < 4; ++it) {
    float g = a_ * (wsig[it] / wsum);
    wg[it] = g;
    wkfac[it] = 1.f - expf(g);
  }

  float4 kv4 = *(const float4*)(kk_ + base + l * 4);
  float kvv[4] = {kv4.x, kv4.y, kv4.z, kv4.w};
  float kmask[4], ddv[4];
#pragma unroll
  for (int c = 0; c < 4; ++c) {
    int slot = l * 4 + c;
    float f = 0.f, d = 0.f;
#pragma unroll
    for (int it = 0; it < 4; ++it) {
      bool hit = (slot == widx[it]);
      f = hit ? wkfac[it] : f;
      d = hit ? wg[it] : d;
    }
    kmask[c] = siluf(kvv[c]) * f;
    ddv[c] = d;  // log-decay (0 for unselected slots)
  }
  float ss = kmask[0] * kmask[0] + kmask[1] * kmask[1] + kmask[2] * kmask[2] +
             kmask[3] * kmask[3];
  ss = wave_sum(ss);
  float kn = rsqrtf(ss + 1e-6f);
  *(float4*)(kk_ + base + l * 4) =
      make_float4(kmask[0] * kn, kmask[1] * kn, kmask[2] * kn, kmask[3] * kn);
  *(float4*)(gbuf + ((size_t)bh * TT + t) * 256 + l * 4) =
      make_float4(ddv[0], ddv[1], ddv[2], ddv[3]);

  float4 qv4 = *(const float4*)(qk + base + l * 4);
  float qs[4] = {siluf(qv4.x), siluf(qv4.y), siluf(qv4.z), siluf(qv4.w)};
  float qss = qs[0] * qs[0] + qs[1] * qs[1] + qs[2] * qs[2] + qs[3] * qs[3];
  qss = wave_sum(qss);
  float qn = rsqrtf(qss + 1e-6f) * 0.0625f;
  *(float4*)(qk + base + l * 4) =
      make_float4(qs[0] * qn, qs[1] * qn, qs[2] * qn, qs[3] * qn);

  float4 vv4 = *(const float4*)(vv + base + l * 4);
  *(float4*)(vv + base + l * 4) =
      make_float4(siluf(vv4.x), siluf(vv4.y), siluf(vv4.z), siluf(vv4.w));
}

// ---------------- phase A: cumsum/expc, A=QwX^T, M=WX^T, Tinv; bf16 outputs ----
// Also emits Wg=k*e^c, Qg=q*e^c as bf16 [bh][t][k] and XTg=X^T bf16 [bh][k][T].
__global__ __launch_bounds__(256) void phaseA_kernel(
    const float* __restrict__ kproj, const float* __restrict__ qproj,
    float* __restrict__ expcG,  // in: g, out: exp(cumsum g)  [bh][T][K]
    const float* __restrict__ betaT, unsigned short* __restrict__ TinvB,
    unsigned short* __restrict__ AB, unsigned short* __restrict__ Wg,
    unsigned short* __restrict__ Qg, unsigned short* __restrict__ XTg) {
  __shared__ float Xs[64 * 256];   // X = k*exp(-c), swizzled k^(i&31) in 32-blocks
  __shared__ float Ws[64 * 256];   // Qw then W
  __shared__ float buf1[64 * 64];  // elem (i,s) at i*64+(s^(i&31))
  const int bid = blockIdx.x;
  const int bh = bid >> 5, c = bid & 31;
  const int b = bh >> 2, h = bh & 3;
  const int t0 = c * 64;
  const int tid = threadIdx.x;
  const int wv = tid >> 6, ln = tid & 63;

  // stage1: cumsum -> expc global; X and Qw into LDS; Wg/Qg global bf16
  {
    float cacc = 0.f;
    for (int i = 0; i < 64; ++i) {
      size_t ga = ((size_t)bh * TT + t0 + i) * 256 + tid;
      size_t pa = (((size_t)b * TT + t0 + i) * HH + h) * 256 + tid;
      cacc += expcG[ga];
      float e = expf(cacc);
      expcG[ga] = e;
      float kv = kproj[pa], qv = qproj[pa];
      int ks = (tid & ~31) | ((tid & 31) ^ (i & 31));
      Xs[i * 256 + ks] = kv * __builtin_amdgcn_rcpf(e);
      Ws[i * 256 + ks] = qv * e;  // Qw
      Wg[ga] = f2bf(kv * e);
      Qg[ga] = f2bf(qv * e);
    }
  }
  __syncthreads();

  float acc[64];
  // ---- A = Qw X^T ----
  if (wv < 2) {
#pragma unroll
    for (int s = 0; s < 64; ++s) acc[s] = 0.f;
    for (int kk = wv * 128; kk < wv * 128 + 128; ++kk) {
      int khi = kk & ~31, klo = kk & 31;
      float wq = Ws[ln * 256 + (khi | (klo ^ (ln & 31)))];
#pragma unroll
      for (int s = 0; s < 64; ++s)
        acc[s] = fmaf(wq, Xs[s * 256 + (khi | (klo ^ (s & 31)))], acc[s]);
    }
    if (wv == 1) {
#pragma unroll
      for (int s = 0; s < 64; ++s) buf1[ln * 64 + (s ^ (ln & 31))] = acc[s];
    }
  }
  __syncthreads();
  if (wv == 0) {
#pragma unroll
    for (int s = 0; s < 64; ++s) {
      float v = acc[s] + buf1[ln * 64 + (s ^ (ln & 31))];
      buf1[ln * 64 + (s ^ (ln & 31))] = v;
    }
  }
  __syncthreads();
  // write A bf16 (mask s<=i) + restage Ws = W = k*expc
  {
    int i = tid >> 2;
    size_t gb = (((size_t)bh * 32 + c) << 12) + (size_t)tid * 16;
#pragma unroll
    for (int mq = 0; mq < 4; ++mq) {
      int sb = (tid & 3) * 16 + mq * 4;
      float4 v;
      v.x = (sb + 0 <= i) ? buf1[i * 64 + ((sb + 0) ^ (i & 31))] : 0.f;
      v.y = (sb + 1 <= i) ? buf1[i * 64 + ((sb + 1) ^ (i & 31))] : 0.f;
      v.z = (sb + 2 <= i) ? buf1[i * 64 + ((sb + 2) ^ (i & 31))] : 0.f;
      v.w = (sb + 3 <= i) ? buf1[i * 64 + ((sb + 3) ^ (i & 31))] : 0.f;
      uint2 p;
      p.x = pack2(v.x, v.y);
      p.y = pack2(v.z, v.w);
      *(uint2*)(AB + gb + mq * 4) = p;
    }
    for (int ii = 0; ii < 64; ++ii) {
      size_t ga = ((size_t)bh * TT + t0 + ii) * 256 + tid;
      size_t pa = (((size_t)b * TT + t0 + ii) * HH + h) * 256 + tid;
      float e = expcG[ga];
      float kv = kproj[pa];
      Ws[ii * 256 + ((tid & ~31) | ((tid & 31) ^ (ii & 31)))] = kv * e;
    }
  }
  __syncthreads();
  // ---- M = W X^T ----
  if (wv < 2) {
#pragma unroll
    for (int s = 0; s < 64; ++s) acc[s] = 0.f;
    for (int kk = wv * 128; kk < wv * 128 + 128; ++kk) {
      int khi = kk & ~31, klo = kk & 31;
      float wq = Ws[ln * 256 + (khi | (klo ^ (ln & 31)))];
#pragma unroll
      for (int s = 0; s < 64; ++s)
        acc[s] = fmaf(wq, Xs[s * 256 + (khi | (klo ^ (s & 31)))], acc[s]);
    }
    if (wv == 1) {
#pragma unroll
      for (int s = 0; s < 64; ++s) buf1[ln * 64 + (s ^ (ln & 31))] = acc[s];
    }
  }
  __syncthreads();
  if (wv == 0) {
#pragma unroll
    for (int s = 0; s < 64; ++s) {
      float v = acc[s] + buf1[ln * 64 + (s ^ (ln & 31))];
      buf1[ln * 64 + (s ^ (ln & 31))] = v;
    }
  }
  __syncthreads();
  // ---- Tinv = (I + diag(beta) M)^{-1} (strict lower M) ----
  if (wv == 0) {
    float tcol[64];
#pragma unroll
    for (int i = 0; i < 64; ++i) {
      float bi = betaT[(size_t)bh * TT + t0 + i];
      float a_ = (ln == i) ? 1.f : 0.f;
#pragma unroll
      for (int s = 0; s < i; ++s) {
        float m = buf1[i * 64 + (s ^ (i & 31))];
        a_ = fmaf(-bi * m, tcol[s], a_);
      }
      tcol[i] = a_;
    }
#pragma unroll
    for (int s = 0; s < 64; ++s)
      buf1[s * 64 + (ln ^ (s & 31))] = tcol[s];
  }
  __syncthreads();
  // write Tinv bf16
  {
    int i = tid >> 2;
    size_t gb = (((size_t)bh * 32 + c) << 12) + (size_t)tid * 16;
#pragma unroll
    for (int mq = 0; mq < 4; ++mq) {
      int sb = (tid & 3) * 16 + mq * 4;
      float4 v;
      v.x = buf1[i * 64 + ((sb + 0) ^ (i & 31))];
      v.y = buf1[i * 64 + ((sb + 1) ^ (i & 31))];
      v.z = buf1[i * 64 + ((sb + 2) ^ (i & 31))];
      v.w = buf1[i * 64 + ((sb + 3) ^ (i & 31))];
      uint2 p;
      p.x = pack2(v.x, v.y);
      p.y = pack2(v.z, v.w);
      *(uint2*)(TinvB + gb + mq * 4) = p;
    }
  }
  // ---- XTg: transpose Xs -> [bh][k=tid][t0..t0+63] bf16 ----
  {
    unsigned short* dst = XTg + ((size_t)bh * 256 + tid) * TT + t0;
    const int khi = tid & ~31, klo = tid & 31;
#pragma unroll
    for (int jq = 0; jq < 8; ++jq) {
      uint4 o;
      unsigned short e0, e1, e2, e3, e4, e5, e6, e7;
      int i0 = jq * 8;
      e0 = f2bf(Xs[(i0 + 0) * 256 + (khi | (klo ^ ((i0 + 0) & 31)))]);
      e1 = f2bf(Xs[(i0 + 1) * 256 + (khi | (klo ^ ((i0 + 1) & 31)))]);
      e2 = f2bf(Xs[(i0 + 2) * 256 + (khi | (klo ^ ((i0 + 2) & 31)))]);
      e3 = f2bf(Xs[(i0 + 3) * 256 + (khi | (klo ^ ((i0 + 3) & 31)))]);
      e4 = f2bf(Xs[(i0 + 4) * 256 + (khi | (klo ^ ((i0 + 4) & 31)))]);
      e5 = f2bf(Xs[(i0 + 5) * 256 + (khi | (klo ^ ((i0 + 5) & 31)))]);
      e6 = f2bf(Xs[(i0 + 6) * 256 + (khi | (klo ^ ((i0 + 6) & 31)))]);
      e7 = f2bf(Xs[(i0 + 7) * 256 + (khi | (klo ^ ((i0 + 7) & 31)))]);
      o.x = ((unsigned)e0) | (((unsigned)e1) << 16);
      o.y = ((unsigned)e2) | (((unsigned)e3) << 16);
      o.z = ((unsigned)e4) | (((unsigned)e5) << 16);
      o.w = ((unsigned)e6) | (((unsigned)e7) << 16);
      *(uint4*)(dst + jq * 8) = o;
    }
  }
}

// ---------------- phase B: MFMA chunk scan; block=(bh, vslice16) ----
// 256 blocks x 256 threads (4 waves). Wave w owns t-rows w*16.. and k-rows
// w*64.. ; S[256][16] fp32 lives in registers (D-frag layout, 4 f32x4/lane).
// Per chunk: G1 RHS=W@S,Oq=Qw@S (S hi/lo bf16 from LDS); R2=beta(V-RHS);
// G2 U=Tinv@R2; G3 O=Oq+A@U -> global; G4 S=eL*(S+X^T@U) -> Sh/Sl LDS.
__global__ __launch_bounds__(256) void chunk_scan_kernel(
    const unsigned short* __restrict__ Wg, const unsigned short* __restrict__ Qg,
    const unsigned short* __restrict__ XTg, const unsigned short* __restrict__ Tb,
    const unsigned short* __restrict__ Ab, const float* __restrict__ vproj,
    const float* __restrict__ expcG, const float* __restrict__ betaT,
    float* __restrict__ obuf) {
  __shared__ unsigned short ShL[16 * 256];  // [n][k], 16B-slot swizzle ^n
  __shared__ unsigned short SlL[16 * 256];
  __shared__ unsigned short R2bL[16 * 64];  // [n][t], slot swizzle ^(n&7)
  __shared__ unsigned short UbL[16 * 64];
  const int bid = blockIdx.x;
  const int bh = bid & 15, slice = bid >> 4;  // all slices of bh -> same XCD
  const int b = bh >> 2, h = bh & 3;
  const int tid = threadIdx.x;
  const int w = tid >> 6;
  const int l = tid & 63;
  const int ln = l & 15, lg = l >> 4;

  const unsigned short* Wbh = Wg + (size_t)bh * TT * 256;
  const unsigned short* Qbh = Qg + (size_t)bh * TT * 256;
  const unsigned short* XTbh = XTg + (size_t)bh * 256 * TT;
  const unsigned short* Tbh = Tb + (size_t)bh * 32 * 4096;
  const unsigned short* Abh = Ab + (size_t)bh * 32 * 4096;
  const float* betabh = betaT + (size_t)bh * TT;
  const float* ebh = expcG + (size_t)bh * TT * 256;

  f32x4 S0 = {0.f, 0.f, 0.f, 0.f}, S1 = S0, S2 = S0, S3 = S0;

  for (int c = 0; c < 32; ++c) {
    const int t0 = c * 64;
    f32x4 rhs = {0.f, 0.f, 0.f, 0.f}, oq = {0.f, 0.f, 0.f, 0.f};
    if (c > 0) {
#pragma unroll
      for (int kt = 0; kt < 8; ++kt) {
        const size_t arow = (size_t)(t0 + w * 16 + ln) * 256 + kt * 32 + lg * 8;
        bf16x8 wf = *(const bf16x8*)(Wbh + arow);
        bf16x8 qf = *(const bf16x8*)(Qbh + arow);
        bf16x8 sh = *(const bf16x8*)(&ShL[ln * 256 + (((kt * 4 + lg) ^ ln) << 3)]);
        bf16x8 sl = *(const bf16x8*)(&SlL[ln * 256 + (((kt * 4 + lg) ^ ln) << 3)]);
        rhs = __builtin_amdgcn_mfma_f32_16x16x32_bf16(wf, sh, rhs, 0, 0, 0);
        rhs = __builtin_amdgcn_mfma_f32_16x16x32_bf16(wf, sl, rhs, 0, 0, 0);
        oq = __builtin_amdgcn_mfma_f32_16x16x32_bf16(qf, sh, oq, 0, 0, 0);
        oq = __builtin_amdgcn_mfma_f32_16x16x32_bf16(qf, sl, oq, 0, 0, 0);
      }
    }
    // R2 = beta*(V - RHS) -> R2bL
    {
      const size_t vrow =
          ((size_t)(b * TT + t0 + w * 16 + lg * 4) * HH + h) * 256 + slice * 16 + ln;
#pragma unroll
      for (int r = 0; r < 4; ++r) {
        int trow = w * 16 + lg * 4 + r;
        float vv = vproj[vrow + (size_t)r * (HH * 256)];
        float bet = betabh[t0 + trow];
        float r2 = bet * (vv - rhs[r]);
        R2bL[ln * 64 + (((trow >> 3) ^ (ln & 7)) << 3) + (trow & 7)] = f2bf(r2);
      }
    }
    __syncthreads();
    // G2: U = Tinv @ R2
    f32x4 u = {0.f, 0.f, 0.f, 0.f};
#pragma unroll
    for (int kt = 0; kt < 2; ++kt) {
      bf16x8 tf = *(const bf16x8*)(Tbh + (size_t)c * 4096 + (w * 16 + ln) * 64 +
                                   kt * 32 + lg * 8);
      bf16x8 rf = *(const bf16x8*)(&R2bL[ln * 64 + (((kt * 4 + lg) ^ (ln & 7)) << 3)]);
      u = __builtin_amdgcn_mfma_f32_16x16x32_bf16(tf, rf, u, 0, 0, 0);
    }
#pragma unroll
    for (int r = 0; r < 4; ++r) {
      int trow = w * 16 + lg * 4 + r;
      UbL[ln * 64 + (((trow >> 3) ^ (ln & 7)) << 3) + (trow & 7)] = f2bf(u[r]);
    }
    __syncthreads();
    // G3: O = Oq + A@U -> global
    {
      f32x4 o = oq;
#pragma unroll
      for (int kt = 0; kt < 2; ++kt) {
        bf16x8 af = *(const bf16x8*)(Abh + (size_t)c * 4096 + (w * 16 + ln) * 64 +
                                     kt * 32 + lg * 8);
        bf16x8 uf = *(const bf16x8*)(&UbL[ln * 64 + (((kt * 4 + lg) ^ (ln & 7)) << 3)]);
        o = __builtin_amdgcn_mfma_f32_16x16x32_bf16(af, uf, o, 0, 0, 0);
      }
      const size_t orow =
          ((size_t)(b * TT + t0 + w * 16 + lg * 4) * HH + h) * 256 + slice * 16 + ln;
#pragma unroll
      for (int r = 0; r < 4; ++r) obuf[orow + (size_t)r * (HH * 256)] = o[r];
    }
    // G4: S = eL * (S + X^T@U); scatter hi/lo to Sh/Sl
#pragma unroll
    for (int mt = 0; mt < 4; ++mt) {
      f32x4 s = (mt == 0) ? S0 : (mt == 1) ? S1 : (mt == 2) ? S2 : S3;
#pragma unroll
      for (int kt = 0; kt < 2; ++kt) {
        bf16x8 xf = *(const bf16x8*)(XTbh + (size_t)(w * 64 + mt * 16 + ln) * TT +
                                     t0 + kt * 32 + lg * 8);
        bf16x8 uf = *(const bf16x8*)(&UbL[ln * 64 + (((kt * 4 + lg) ^ (ln & 7)) << 3)]);
        s = __builtin_amdgcn_mfma_f32_16x16x32_bf16(xf, uf, s, 0, 0, 0);
      }
#pragma unroll
      for (int r = 0; r < 4; ++r) {
        int krow = w * 64 + mt * 16 + lg * 4 + r;
        float sv = s[r] * ebh[(size_t)(t0 + 63) * 256 + krow];
        s[r] = sv;
        unsigned short hi = f2bf(sv);
        int sidx = ln * 256 + (((krow >> 3) ^ ln) << 3) + (krow & 7);
        ShL[sidx] = hi;
        SlL[sidx] = f2bf(sv - bf2f(hi));
      }
      if (mt == 0) S0 = s; else if (mt == 1) S1 = s; else if (mt == 2) S2 = s; else S3 = s;
    }
    __syncthreads();
  }
}

// ---------------- per-head RMSNorm ----------------
__global__ __launch_bounds__(256) void rmsnorm_kernel(
    const float* __restrict__ o, const float* __restrict__ w,
    float* __restrict__ out) {
  const int row = blockIdx.x;
  const int l = threadIdx.x & 63;
  const size_t base = (size_t)row * DD + (threadIdx.x >> 6) * 256 + l * 4;
  float4 x = *(const float4*)(o + base);
  float ss = x.x * x.x + x.y * x.y + x.z * x.z + x.w * x.w;
  ss = wave_sum(ss);
  float sc = rsqrtf(ss * (1.f / 256.f) + 1e-5f);
  float4 wv = *(const float4*)(w + l * 4);
  *(float4*)(out + base) = make_float4(x.x * sc * wv.x, x.y * sc * wv.y,
                                       x.z * sc * wv.z, x.w * sc * wv.w);
}

extern "C" void kernel_launch(void* const* d_in, const int* in_sizes, int n_in,
                              void* d_out, int out_size, void* d_ws,
                              size_t ws_size, hipStream_t stream) {
  const float* hidden = (const float*)d_in[0];
  const float* Wq = (const float*)d_in[1];
  const float* Wk = (const float*)d_in[2];
  const float* Wv = (const float*)d_in[3];
  const float* Wa = (const float*)d_in[4];
  const float* Wr = (const float*)d_in[5];
  const float* Wb = (const float*)d_in[6];
  const float* dt = (const float*)d_in[7];
  const float* norm_w = (const float*)d_in[8];
  const float* Wo = (const float*)d_in[9];
  float* out = (float*)d_out;

  const size_t NP = (size_t)BB * TT * DD;  // 8388608
  float* ws = (float*)d_ws;
  float* qproj = ws;
  float* kproj = ws + NP;
  float* vproj = ws + 2 * NP;
  float* gbuf = ws + 3 * NP;  // g -> expc [bh][T][K]
  unsigned short* hbf = (unsigned short*)(ws + 4 * NP);          // NP bf16
  unsigned short* wT = (unsigned short*)(ws + 4 * NP + NP / 2);  // 6 x 1M bf16
  unsigned short* WT0 = wT;
  unsigned short* WT1 = wT + 1048576;
  unsigned short* WT2 = wT + 2 * 1048576;
  unsigned short* WT3 = wT + 3 * 1048576;
  unsigned short* WT4 = wT + 4 * 1048576;  // Wr^T hi (dead after bt3 -> Tb)
  unsigned short* WT5 = wT + 5 * 1048576;  // Wr^T lo
  float* betaT = ws + 4 * NP + NP / 2 + 3 * 1024 * 1024;  // 32K floats
  float* after_beta = betaT + 16 * TT;
  unsigned short* Qg = (unsigned short*)after_beta;        // NP bf16 (16MB)
  unsigned short* XTg = Qg + NP;                           // NP bf16 (16MB)
  unsigned short* Ab = XTg + NP;                           // 2M bf16 (4MB)
  unsigned short* Wgb = hbf;   // alias: hbf dead between projections and final cast
  unsigned short* Tbb = WT4;   // alias: WT4/WT5 dead after gemm_bt3 (2M bf16)
  unsigned short* hlo = (unsigned short*)qproj;  // alias: dead before q-GEMM
  float* rproj = out;
  float* normed = qproj;

  dim3 bt(256);
  cast2_bf16_kernel<<<8192, 256, 0, stream>>>(hidden, hbf, hlo);
  dim3 tg(32, 32), tb(32, 8);
  tcast2_kernel<<<tg, tb, 0, stream>>>(Wr, WT4, WT5, 1024, 1024);
  tcast_kernel<<<tg, tb, 0, stream>>>(Wq, WT0, 1024, 1024);
  tcast_kernel<<<tg, tb, 0, stream>>>(Wk, WT1, 1024, 1024);
  tcast_kernel<<<tg, tb, 0, stream>>>(Wv, WT2, 1024, 1024);
  tcast_kernel<<<tg, tb, 0, stream>>>(Wo, WT3, 1024, 1024);

  dim3 gmm(1024 / 128, 8192 / 128);
  gemm_bt3<<<gmm, bt, 0, stream>>>(hbf, hlo, WT4, WT5, rproj, 8192, 1024, 1024);
  gemm_bt<<<gmm, bt, 0, stream>>>(hbf, WT0, qproj, 8192, 1024, 1024);
  gemm_bt<<<gmm, bt, 0, stream>>>(hbf, WT1, kproj, 8192, 1024, 1024);
  gemm_bt<<<gmm, bt, 0, stream>>>(hbf, WT2, vproj, 8192, 1024, 1024);

  routing_kernel<<<8192, 256, 0, stream>>>(hidden, Wa, Wb, dt, rproj, qproj,
                                           kproj, vproj, gbuf, betaT);
  phaseA_kernel<<<512, 256, 0, stream>>>(kproj, qproj, gbuf, betaT, Tbb, Ab,
                                         Wgb, Qg, XTg);
  chunk_scan_kernel<<<256, 256, 0, stream>>>(Wgb, Qg, XTg, Tbb, Ab, vproj,
                                             gbuf, betaT, out);
  rmsnorm_kernel<<<8192, 256, 0, stream>>>(out, norm_w, normed);
  cast_bf16_kernel<<<8192, 256, 0, stream>>>(normed, hbf);
  gemm_bt<<<gmm, bt, 0, stream>>>(hbf, WT3, out, 8192, 1024, 1024);
}

// Round 6
// 902.995 us; speedup vs baseline: 4.0956x; 1.2706x over previous
//
#include <hip/hip_runtime.h>
#include <hip/hip_bf16.h>

#define TT 2048
#define BB 4
#define HH 4
#define DD 1024

using bf16x8 = __attribute__((ext_vector_type(8))) short;
using f32x4  = __attribute__((ext_vector_type(4))) float;

__device__ __forceinline__ float wave_sum(float x) {
#pragma unroll
  for (int off = 32; off >= 1; off >>= 1) x += __shfl_xor(x, off);
  return x;
}

__device__ __forceinline__ float siluf(float x) {
  return x / (1.f + expf(-x));
}

__device__ __forceinline__ unsigned short f2bf(float f) {
  unsigned u = __float_as_uint(f);
  u = (u + 0x7fffu + ((u >> 16) & 1u)) >> 16;
  return (unsigned short)u;
}
__device__ __forceinline__ float bf2f(unsigned short b) {
  return __uint_as_float(((unsigned)b) << 16);
}
__device__ __forceinline__ unsigned pack2(float a, float b) {
  return ((unsigned)f2bf(a)) | (((unsigned)f2bf(b)) << 16);
}

// ---------------- bf16 MFMA GEMM: C[M,N] = A[M,K] @ B[K,N], Bt is [N][K] ----
__global__ __launch_bounds__(256) void gemm_bt(const unsigned short* __restrict__ A,
                                               const unsigned short* __restrict__ Bt,
                                               float* __restrict__ C,
                                               int M, int N, int K) {
  __shared__ unsigned short As[128 * 64];
  __shared__ unsigned short Bs[128 * 64];
  const int tid = threadIdx.x;
  const int l = tid & 63;
  const int w = tid >> 6;
  const int wm = w >> 1, wn = w & 1;
  const int m0 = blockIdx.y * 128, n0 = blockIdx.x * 128;

  f32x4 acc[4][4];
#pragma unroll
  for (int i = 0; i < 4; ++i)
#pragma unroll
    for (int j = 0; j < 4; ++j) acc[i][j] = (f32x4){0.f, 0.f, 0.f, 0.f};

  int c_row[4], c_slot[4], c_dst[4];
#pragma unroll
  for (int it = 0; it < 4; ++it) {
    int chunk = it * 256 + tid;
    int row = chunk >> 3, s = chunk & 7;
    c_row[it] = row;
    c_slot[it] = s;
    c_dst[it] = row * 128 + ((s ^ (row & 7)) << 4);
  }
  int ra_off[2][4], rb_off[2][4];
#pragma unroll
  for (int kh = 0; kh < 2; ++kh)
#pragma unroll
    for (int f = 0; f < 4; ++f) {
      int rowA = wm * 64 + f * 16 + (l & 15);
      ra_off[kh][f] = rowA * 128 + (((kh * 4 + (l >> 4)) ^ (rowA & 7)) << 4);
      int rowB = wn * 64 + f * 16 + (l & 15);
      rb_off[kh][f] = rowB * 128 + (((kh * 4 + (l >> 4)) ^ (rowB & 7)) << 4);
    }

  for (int k0 = 0; k0 < K; k0 += 64) {
    uint4 ra[4], rb[4];
#pragma unroll
    for (int it = 0; it < 4; ++it) {
      ra[it] = *(const uint4*)(A + (size_t)(m0 + c_row[it]) * K + k0 + c_slot[it] * 8);
      rb[it] = *(const uint4*)(Bt + (size_t)(n0 + c_row[it]) * K + k0 + c_slot[it] * 8);
    }
    __syncthreads();
#pragma unroll
    for (int it = 0; it < 4; ++it) {
      *(uint4*)((char*)As + c_dst[it]) = ra[it];
      *(uint4*)((char*)Bs + c_dst[it]) = rb[it];
    }
    __syncthreads();
#pragma unroll
    for (int kh = 0; kh < 2; ++kh) {
      bf16x8 af[4], bfv[4];
#pragma unroll
      for (int f = 0; f < 4; ++f) {
        af[f] = *(const bf16x8*)((const char*)As + ra_off[kh][f]);
        bfv[f] = *(const bf16x8*)((const char*)Bs + rb_off[kh][f]);
      }
#pragma unroll
      for (int i = 0; i < 4; ++i)
#pragma unroll
        for (int j = 0; j < 4; ++j)
          acc[i][j] = __builtin_amdgcn_mfma_f32_16x16x32_bf16(af[i], bfv[j],
                                                              acc[i][j], 0, 0, 0);
    }
  }
  const int cn = n0 + wn * 64 + (l & 15);
  const int rbase = m0 + wm * 64 + ((l >> 4) << 2);
#pragma unroll
  for (int i = 0; i < 4; ++i)
#pragma unroll
    for (int j = 0; j < 4; ++j)
#pragma unroll
      for (int r = 0; r < 4; ++r)
        C[(size_t)(rbase + i * 16 + r) * N + cn + j * 16] = acc[i][j][r];
}

// ------------- split-bf16 3-term GEMM (fp32-accurate): C = Ah@Bh+Al@Bh+Ah@Bl
__global__ __launch_bounds__(256) void gemm_bt3(const unsigned short* __restrict__ Ah,
                                                const unsigned short* __restrict__ Al,
                                                const unsigned short* __restrict__ Bh,
                                                const unsigned short* __restrict__ Bl,
                                                float* __restrict__ C,
                                                int M, int N, int K) {
  __shared__ unsigned short Ash[128 * 64];
  __shared__ unsigned short Asl[128 * 64];
  __shared__ unsigned short Bsh[128 * 64];
  __shared__ unsigned short Bsl[128 * 64];
  const int tid = threadIdx.x;
  const int l = tid & 63;
  const int w = tid >> 6;
  const int wm = w >> 1, wn = w & 1;
  const int m0 = blockIdx.y * 128, n0 = blockIdx.x * 128;

  f32x4 acc[4][4];
#pragma unroll
  for (int i = 0; i < 4; ++i)
#pragma unroll
    for (int j = 0; j < 4; ++j) acc[i][j] = (f32x4){0.f, 0.f, 0.f, 0.f};

  int c_row[4], c_slot[4], c_dst[4];
#pragma unroll
  for (int it = 0; it < 4; ++it) {
    int chunk = it * 256 + tid;
    int row = chunk >> 3, s = chunk & 7;
    c_row[it] = row;
    c_slot[it] = s;
    c_dst[it] = row * 128 + ((s ^ (row & 7)) << 4);
  }
  int ra_off[2][4], rb_off[2][4];
#pragma unroll
  for (int kh = 0; kh < 2; ++kh)
#pragma unroll
    for (int f = 0; f < 4; ++f) {
      int rowA = wm * 64 + f * 16 + (l & 15);
      ra_off[kh][f] = rowA * 128 + (((kh * 4 + (l >> 4)) ^ (rowA & 7)) << 4);
      int rowB = wn * 64 + f * 16 + (l & 15);
      rb_off[kh][f] = rowB * 128 + (((kh * 4 + (l >> 4)) ^ (rowB & 7)) << 4);
    }

  for (int k0 = 0; k0 < K; k0 += 64) {
    uint4 rah[4], ral[4], rbh[4], rbl[4];
#pragma unroll
    for (int it = 0; it < 4; ++it) {
      size_t aoff = (size_t)(m0 + c_row[it]) * K + k0 + c_slot[it] * 8;
      size_t boff = (size_t)(n0 + c_row[it]) * K + k0 + c_slot[it] * 8;
      rah[it] = *(const uint4*)(Ah + aoff);
      ral[it] = *(const uint4*)(Al + aoff);
      rbh[it] = *(const uint4*)(Bh + boff);
      rbl[it] = *(const uint4*)(Bl + boff);
    }
    __syncthreads();
#pragma unroll
    for (int it = 0; it < 4; ++it) {
      *(uint4*)((char*)Ash + c_dst[it]) = rah[it];
      *(uint4*)((char*)Asl + c_dst[it]) = ral[it];
      *(uint4*)((char*)Bsh + c_dst[it]) = rbh[it];
      *(uint4*)((char*)Bsl + c_dst[it]) = rbl[it];
    }
    __syncthreads();
#pragma unroll
    for (int kh = 0; kh < 2; ++kh) {
      bf16x8 afh[4], bfh[4], tmp[4];
#pragma unroll
      for (int f = 0; f < 4; ++f) {
        afh[f] = *(const bf16x8*)((const char*)Ash + ra_off[kh][f]);
        bfh[f] = *(const bf16x8*)((const char*)Bsh + rb_off[kh][f]);
      }
#pragma unroll
      for (int i = 0; i < 4; ++i)
#pragma unroll
        for (int j = 0; j < 4; ++j)
          acc[i][j] = __builtin_amdgcn_mfma_f32_16x16x32_bf16(afh[i], bfh[j],
                                                              acc[i][j], 0, 0, 0);
#pragma unroll
      for (int f = 0; f < 4; ++f)
        tmp[f] = *(const bf16x8*)((const char*)Asl + ra_off[kh][f]);
#pragma unroll
      for (int i = 0; i < 4; ++i)
#pragma unroll
        for (int j = 0; j < 4; ++j)
          acc[i][j] = __builtin_amdgcn_mfma_f32_16x16x32_bf16(tmp[i], bfh[j],
                                                              acc[i][j], 0, 0, 0);
#pragma unroll
      for (int f = 0; f < 4; ++f)
        tmp[f] = *(const bf16x8*)((const char*)Bsl + rb_off[kh][f]);
#pragma unroll
      for (int i = 0; i < 4; ++i)
#pragma unroll
        for (int j = 0; j < 4; ++j)
          acc[i][j] = __builtin_amdgcn_mfma_f32_16x16x32_bf16(afh[i], tmp[j],
                                                              acc[i][j], 0, 0, 0);
    }
  }
  const int cn = n0 + wn * 64 + (l & 15);
  const int rbase = m0 + wm * 64 + ((l >> 4) << 2);
#pragma unroll
  for (int i = 0; i < 4; ++i)
#pragma unroll
    for (int j = 0; j < 4; ++j)
#pragma unroll
      for (int r = 0; r < 4; ++r)
        C[(size_t)(rbase + i * 16 + r) * N + cn + j * 16] = acc[i][j][r];
}

// ---------------- casts ----------------
__global__ __launch_bounds__(256) void cast_bf16_kernel(const float* __restrict__ in,
                                                        unsigned short* __restrict__ out) {
  const size_t i = ((size_t)blockIdx.x * 256 + threadIdx.x) * 4;
  float4 x = *(const float4*)(in + i);
  ushort4 o4;
  o4.x = f2bf(x.x);
  o4.y = f2bf(x.y);
  o4.z = f2bf(x.z);
  o4.w = f2bf(x.w);
  *(ushort4*)(out + i) = o4;
}

__global__ __launch_bounds__(256) void cast2_bf16_kernel(const float* __restrict__ in,
                                                         unsigned short* __restrict__ hi,
                                                         unsigned short* __restrict__ lo) {
  const size_t i = ((size_t)blockIdx.x * 256 + threadIdx.x) * 4;
  float4 x = *(const float4*)(in + i);
  ushort4 h4, l4;
  h4.x = f2bf(x.x); l4.x = f2bf(x.x - bf2f(h4.x));
  h4.y = f2bf(x.y); l4.y = f2bf(x.y - bf2f(h4.y));
  h4.z = f2bf(x.z); l4.z = f2bf(x.z - bf2f(h4.z));
  h4.w = f2bf(x.w); l4.w = f2bf(x.w - bf2f(h4.w));
  *(ushort4*)(hi + i) = h4;
  *(ushort4*)(lo + i) = l4;
}

// W [R][C] f32 row-major -> WT [C][R] bf16 (transpose + cast)
__global__ __launch_bounds__(256) void tcast_kernel(const float* __restrict__ W,
                                                    unsigned short* __restrict__ WT,
                                                    int R, int C) {
  __shared__ float tile[32][33];
  const int tx = threadIdx.x, ty = threadIdx.y;
  const int c0 = blockIdx.x * 32, r0 = blockIdx.y * 32;
#pragma unroll
  for (int i = 0; i < 4; ++i)
    tile[ty + 8 * i][tx] = W[(size_t)(r0 + ty + 8 * i) * C + c0 + tx];
  __syncthreads();
#pragma unroll
  for (int i = 0; i < 4; ++i)
    WT[(size_t)(c0 + ty + 8 * i) * R + r0 + tx] = f2bf(tile[tx][ty + 8 * i]);
}

__global__ __launch_bounds__(256) void tcast2_kernel(const float* __restrict__ W,
                                                     unsigned short* __restrict__ WTh,
                                                     unsigned short* __restrict__ WTl,
                                                     int R, int C) {
  __shared__ float tile[32][33];
  const int tx = threadIdx.x, ty = threadIdx.y;
  const int c0 = blockIdx.x * 32, r0 = blockIdx.y * 32;
#pragma unroll
  for (int i = 0; i < 4; ++i)
    tile[ty + 8 * i][tx] = W[(size_t)(r0 + ty + 8 * i) * C + c0 + tx];
  __syncthreads();
#pragma unroll
  for (int i = 0; i < 4; ++i) {
    float x = tile[tx][ty + 8 * i];
    unsigned short h = f2bf(x);
    WTh[(size_t)(c0 + ty + 8 * i) * R + r0 + tx] = h;
    WTl[(size_t)(c0 + ty + 8 * i) * R + r0 + tx] = f2bf(x - bf2f(h));
  }
}

// ---------------- routing: a/beta dots, top-4, silu+norms, dense LOG-decay ----
__global__ __launch_bounds__(256) void routing_kernel(
    const float* __restrict__ hidden, const float* __restrict__ Wa,
    const float* __restrict__ Wb, const float* __restrict__ dt,
    const float* __restrict__ rproj, float* __restrict__ qk,
    float* __restrict__ kk_, float* __restrict__ vv, float* __restrict__ gbuf,
    float* __restrict__ betaT) {
  const int row = blockIdx.x;  // b*T + t
  const int b = row >> 11;
  const int t = row & (TT - 1);
  const int h = threadIdx.x >> 6;
  const int l = threadIdx.x & 63;
  const size_t base = (size_t)row * DD + h * 256;

  const float* hrow = hidden + (size_t)row * DD;
  float aa = 0.f, bb = 0.f;
#pragma unroll
  for (int i = 0; i < 16; ++i) {
    float hv = hrow[l + 64 * i];
    aa = fmaf(hv, Wa[(l + 64 * i) * HH + h], aa);
    bb = fmaf(hv, Wb[(l + 64 * i) * HH + h], bb);
  }
  aa = wave_sum(aa);
  bb = wave_sum(bb);
  float sp = (aa > 20.f) ? aa : log1pf(expf(aa));
  float a_ = -sp * expf(dt[h]);
  float beta = 1.f / (1.f + expf(-bb));
  const int bh = b * HH + h;
  if (l == 0) betaT[(size_t)bh * TT + t] = beta;

  float4 rt4 = *(const float4*)(rproj + base + l * 4);
  float rv[4] = {rt4.x, rt4.y, rt4.z, rt4.w};
  int used = 0;
  int widx[4];
  float wsig[4], wg[4], wkfac[4];
#pragma unroll
  for (int it = 0; it < 4; ++it) {
    float bv = -3.4e38f;
    int bi = 0x7fffffff;
#pragma unroll
    for (int c = 0; c < 4; ++c) {
      bool ok = !(used & (1 << c));
      float v = rv[c];
      if (ok && (v > bv)) {
        bv = v;
        bi = l * 4 + c;
      }
    }
#pragma unroll
    for (int off = 32; off >= 1; off >>= 1) {
      float ov = __shfl_xor(bv, off);
      int oi = __shfl_xor(bi, off);
      if (ov > bv || (ov == bv && oi < bi)) {
        bv = ov;
        bi = oi;
      }
    }
    widx[it] = bi;
    wsig[it] = 1.f / (1.f + expf(-bv));
    if ((bi >> 2) == l) used |= 1 << (bi & 3);
  }
  float wsum = wsig[0] + wsig[1] + wsig[2] + wsig[3] + 1e-6f;
#pragma unroll
  for (int it = 0; it < 4; ++it) {
    float g = a_ * (wsig[it] / wsum);
    wg[it] = g;
    wkfac[it] = 1.f - expf(g);
  }

  float4 kv4 = *(const float4*)(kk_ + base + l * 4);
  float kvv[4] = {kv4.x, kv4.y, kv4.z, kv4.w};
  float kmask[4], ddv[4];
#pragma unroll
  for (int c = 0; c < 4; ++c) {
    int slot = l * 4 + c;
    float f = 0.f, d = 0.f;
#pragma unroll
    for (int it = 0; it < 4; ++it) {
      bool hit = (slot == widx[it]);
      f = hit ? wkfac[it] : f;
      d = hit ? wg[it] : d;
    }
    kmask[c] = siluf(kvv[c]) * f;
    ddv[c] = d;  // log-decay (0 for unselected slots)
  }
  float ss = kmask[0] * kmask[0] + kmask[1] * kmask[1] + kmask[2] * kmask[2] +
             kmask[3] * kmask[3];
  ss = wave_sum(ss);
  float kn = rsqrtf(ss + 1e-6f);
  *(float4*)(kk_ + base + l * 4) =
      make_float4(kmask[0] * kn, kmask[1] * kn, kmask[2] * kn, kmask[3] * kn);
  *(float4*)(gbuf + ((size_t)bh * TT + t) * 256 + l * 4) =
      make_float4(ddv[0], ddv[1], ddv[2], ddv[3]);

  float4 qv4 = *(const float4*)(qk + base + l * 4);
  float qs[4] = {siluf(qv4.x), siluf(qv4.y), siluf(qv4.z), siluf(qv4.w)};
  float qss = qs[0] * qs[0] + qs[1] * qs[1] + qs[2] * qs[2] + qs[3] * qs[3];
  qss = wave_sum(qss);
  float qn = rsqrtf(qss + 1e-6f) * 0.0625f;
  *(float4*)(qk + base + l * 4) =
      make_float4(qs[0] * qn, qs[1] * qn, qs[2] * qn, qs[3] * qn);

  float4 vv4 = *(const float4*)(vv + base + l * 4);
  *(float4*)(vv + base + l * 4) =
      make_float4(siluf(vv4.x), siluf(vv4.y), siluf(vv4.z), siluf(vv4.w));
}

// ---------------- phase A (MFMA): cumsum; P=[Qw;W]@X^T via mfma; Tinv; bf16 out
// block=(bh,chunk): 512 x 256. LDS: XB 32KB + QW 64KB + Mb 17KB = 114KB.
// Single staging pass; expcG written ONLY at chunk-final row (phase B reads it).
__global__ __launch_bounds__(256) void phaseA_kernel(
    const float* __restrict__ kproj, const float* __restrict__ qproj,
    float* __restrict__ expcG,  // in: g [bh][T][K]; out: row t0+63 = exp(csum)
    const float* __restrict__ betaT, unsigned short* __restrict__ TinvB,
    unsigned short* __restrict__ AB, unsigned short* __restrict__ Wg,
    unsigned short* __restrict__ Qg, unsigned short* __restrict__ XTg) {
  __shared__ unsigned short XB[64 * 256];   // X rows [t][k], 16B-slot ^ (t&7)
  __shared__ unsigned short QW[128 * 256];  // rows 0-63 Qw, 64-127 W, same swizzle
  __shared__ float Mb[64 * 68];             // M fp32 (then Tinv), padded
  const int bid = blockIdx.x;
  const int bh = bid >> 5, c = bid & 31;
  const int b = bh >> 2, h = bh & 3;
  const int t0 = c * 64;
  const int tid = threadIdx.x;
  const int w = tid >> 6, l = tid & 63;
  const int ln = l & 15, lg = l >> 4;

  // ---- stage 0: cumsum + bf16 staging (LDS + global Wg/Qg) ----
  {
    float cacc = 0.f;
    const int slot = tid >> 3, byt = tid & 7;
#pragma unroll 4
    for (int i = 0; i < 64; ++i) {
      size_t ga = ((size_t)bh * TT + t0 + i) * 256 + tid;
      size_t pa = (((size_t)b * TT + t0 + i) * HH + h) * 256 + tid;
      cacc += expcG[ga];
      float e = expf(cacc);
      float ei = __builtin_amdgcn_rcpf(e);
      float kv = kproj[pa], qv = qproj[pa];
      unsigned short wb = f2bf(kv * e);
      unsigned short qb = f2bf(qv * e);
      unsigned short xb = f2bf(kv * ei);
      Wg[ga] = wb;
      Qg[ga] = qb;
      int sw = ((slot ^ (i & 7)) << 3) + byt;
      XB[i * 256 + sw] = xb;
      QW[i * 256 + sw] = qb;
      QW[(i + 64) * 256 + sw] = wb;
      if (i == 63) expcG[ga] = e;  // only row phase B reads
    }
  }
  __syncthreads();

  // ---- MFMA: P[128][64] = QW @ XB^T; wave w owns rows w*32..w*32+31 ----
  f32x4 acc[2][4];
#pragma unroll
  for (int tr = 0; tr < 2; ++tr)
#pragma unroll
    for (int tc = 0; tc < 4; ++tc) acc[tr][tc] = (f32x4){0.f, 0.f, 0.f, 0.f};
  const int R0 = w * 32;
#pragma unroll
  for (int kt = 0; kt < 8; ++kt) {
    const int ks = kt * 4 + lg;  // 16B slot 0..31
    const int ra0 = R0 + ln, ra1 = R0 + 16 + ln;
    bf16x8 a0 = *(const bf16x8*)&QW[ra0 * 256 + ((ks ^ (ra0 & 7)) << 3)];
    bf16x8 a1 = *(const bf16x8*)&QW[ra1 * 256 + ((ks ^ (ra1 & 7)) << 3)];
#pragma unroll
    for (int tc = 0; tc < 4; ++tc) {
      const int br = tc * 16 + ln;
      bf16x8 bf_ = *(const bf16x8*)&XB[br * 256 + ((ks ^ (br & 7)) << 3)];
      acc[0][tc] = __builtin_amdgcn_mfma_f32_16x16x32_bf16(a0, bf_, acc[0][tc], 0, 0, 0);
      acc[1][tc] = __builtin_amdgcn_mfma_f32_16x16x32_bf16(a1, bf_, acc[1][tc], 0, 0, 0);
    }
  }
  // scatter: waves 0-1 -> A (masked, bf16, global); waves 2-3 -> M (fp32, LDS)
  const size_t gb = (((size_t)bh * 32 + c) << 12);
  if (w < 2) {
#pragma unroll
    for (int tr = 0; tr < 2; ++tr)
#pragma unroll
      for (int tc = 0; tc < 4; ++tc)
#pragma unroll
        for (int r = 0; r < 4; ++r) {
          int i = R0 + tr * 16 + lg * 4 + r;
          int s = tc * 16 + ln;
          AB[gb + i * 64 + s] = (s <= i) ? f2bf(acc[tr][tc][r]) : (unsigned short)0;
        }
  } else {
#pragma unroll
    for (int tr = 0; tr < 2; ++tr)
#pragma unroll
      for (int tc = 0; tc < 4; ++tc)
#pragma unroll
        for (int r = 0; r < 4; ++r) {
          int i = R0 - 64 + tr * 16 + lg * 4 + r;
          Mb[i * 68 + tc * 16 + ln] = acc[tr][tc][r];
        }
  }
  __syncthreads();

  // ---- wave 0: Tinv = (I + diag(beta) tril_strict(M))^{-1}; waves 1-3: XTg ----
  if (w == 0) {
    float tcol[64];
#pragma unroll
    for (int i = 0; i < 64; ++i) {
      float bi = betaT[(size_t)bh * TT + t0 + i];
      float a_ = (l == i) ? 1.f : 0.f;
#pragma unroll
      for (int s = 0; s < i; ++s)
        a_ = fmaf(-bi * Mb[i * 68 + s], tcol[s], a_);
      tcol[i] = a_;
    }
#pragma unroll
    for (int s = 0; s < 64; ++s) Mb[s * 68 + l] = tcol[s];
  } else {
    const int kk1 = tid - 64;  // 0..191
#pragma unroll 1
    for (int pass = 0; pass < 2; ++pass) {
      if (pass == 1 && kk1 >= 64) break;
      const int k = (pass == 0) ? kk1 : (192 + kk1);
      unsigned short* dst = XTg + ((size_t)bh * 256 + k) * TT + t0;
      const int kslot = k >> 3, kb = k & 7;
#pragma unroll 1
      for (int jq = 0; jq < 8; ++jq) {
        unsigned short e[8];
#pragma unroll
        for (int j = 0; j < 8; ++j) {
          int t = jq * 8 + j;
          e[j] = XB[t * 256 + (((kslot ^ (t & 7)) << 3) + kb)];
        }
        uint4 o;
        o.x = ((unsigned)e[0]) | (((unsigned)e[1]) << 16);
        o.y = ((unsigned)e[2]) | (((unsigned)e[3]) << 16);
        o.z = ((unsigned)e[4]) | (((unsigned)e[5]) << 16);
        o.w = ((unsigned)e[6]) | (((unsigned)e[7]) << 16);
        *(uint4*)(dst + jq * 8) = o;
      }
    }
  }
  __syncthreads();
  // ---- all: write Tinv bf16 [i][s] row-major ----
  {
    const int i = tid >> 2;
    const int sb = (tid & 3) * 16;
#pragma unroll
    for (int mq = 0; mq < 4; ++mq) {
      float v0 = Mb[i * 68 + sb + mq * 4 + 0];
      float v1 = Mb[i * 68 + sb + mq * 4 + 1];
      float v2 = Mb[i * 68 + sb + mq * 4 + 2];
      float v3 = Mb[i * 68 + sb + mq * 4 + 3];
      uint2 p;
      p.x = pack2(v0, v1);
      p.y = pack2(v2, v3);
      *(uint2*)(TinvB + gb + (size_t)i * 64 + sb + mq * 4) = p;
    }
  }
}

// ---------------- phase B: MFMA chunk scan; block=(bh, vslice16) ----
__global__ __launch_bounds__(256) void chunk_scan_kernel(
    const unsigned short* __restrict__ Wg, const unsigned short* __restrict__ Qg,
    const unsigned short* __restrict__ XTg, const unsigned short* __restrict__ Tb,
    const unsigned short* __restrict__ Ab, const float* __restrict__ vproj,
    const float* __restrict__ expcG, const float* __restrict__ betaT,
    float* __restrict__ obuf) {
  __shared__ unsigned short ShL[16 * 256];  // [n][k], 16B-slot swizzle ^n
  __shared__ unsigned short SlL[16 * 256];
  __shared__ unsigned short R2bL[16 * 64];  // [n][t], slot swizzle ^(n&7)
  __shared__ unsigned short UbL[16 * 64];
  const int bid = blockIdx.x;
  const int bh = bid & 15, slice = bid >> 4;  // all slices of bh -> same XCD
  const int b = bh >> 2, h = bh & 3;
  const int tid = threadIdx.x;
  const int w = tid >> 6;
  const int l = tid & 63;
  const int ln = l & 15, lg = l >> 4;

  const unsigned short* Wbh = Wg + (size_t)bh * TT * 256;
  const unsigned short* Qbh = Qg + (size_t)bh * TT * 256;
  const unsigned short* XTbh = XTg + (size_t)bh * 256 * TT;
  const unsigned short* Tbh = Tb + (size_t)bh * 32 * 4096;
  const unsigned short* Abh = Ab + (size_t)bh * 32 * 4096;
  const float* betabh = betaT + (size_t)bh * TT;
  const float* ebh = expcG + (size_t)bh * TT * 256;

  f32x4 S0 = {0.f, 0.f, 0.f, 0.f}, S1 = S0, S2 = S0, S3 = S0;

  for (int c = 0; c < 32; ++c) {
    const int t0 = c * 64;
    f32x4 rhs = {0.f, 0.f, 0.f, 0.f}, oq = {0.f, 0.f, 0.f, 0.f};
    if (c > 0) {
#pragma unroll
      for (int kt = 0; kt < 8; ++kt) {
        const size_t arow = (size_t)(t0 + w * 16 + ln) * 256 + kt * 32 + lg * 8;
        bf16x8 wf = *(const bf16x8*)(Wbh + arow);
        bf16x8 qf = *(const bf16x8*)(Qbh + arow);
        bf16x8 sh = *(const bf16x8*)(&ShL[ln * 256 + (((kt * 4 + lg) ^ ln) << 3)]);
        bf16x8 sl = *(const bf16x8*)(&SlL[ln * 256 + (((kt * 4 + lg) ^ ln) << 3)]);
        rhs = __builtin_amdgcn_mfma_f32_16x16x32_bf16(wf, sh, rhs, 0, 0, 0);
        rhs = __builtin_amdgcn_mfma_f32_16x16x32_bf16(wf, sl, rhs, 0, 0, 0);
        oq = __builtin_amdgcn_mfma_f32_16x16x32_bf16(qf, sh, oq, 0, 0, 0);
        oq = __builtin_amdgcn_mfma_f32_16x16x32_bf16(qf, sl, oq, 0, 0, 0);
      }
    }
    // R2 = beta*(V - RHS) -> R2bL
    {
      const size_t vrow =
          ((size_t)(b * TT + t0 + w * 16 + lg * 4) * HH + h) * 256 + slice * 16 + ln;
#pragma unroll
      for (int r = 0; r < 4; ++r) {
        int trow = w * 16 + lg * 4 + r;
        float vv = vproj[vrow + (size_t)r * (HH * 256)];
        float bet = betabh[t0 + trow];
        float r2 = bet * (vv - rhs[r]);
        R2bL[ln * 64 + (((trow >> 3) ^ (ln & 7)) << 3) + (trow & 7)] = f2bf(r2);
      }
    }
    __syncthreads();
    // G2: U = Tinv @ R2
    f32x4 u = {0.f, 0.f, 0.f, 0.f};
#pragma unroll
    for (int kt = 0; kt < 2; ++kt) {
      bf16x8 tf = *(const bf16x8*)(Tbh + (size_t)c * 4096 + (w * 16 + ln) * 64 +
                                   kt * 32 + lg * 8);
      bf16x8 rf = *(const bf16x8*)(&R2bL[ln * 64 + (((kt * 4 + lg) ^ (ln & 7)) << 3)]);
      u = __builtin_amdgcn_mfma_f32_16x16x32_bf16(tf, rf, u, 0, 0, 0);
    }
#pragma unroll
    for (int r = 0; r < 4; ++r) {
      int trow = w * 16 + lg * 4 + r;
      UbL[ln * 64 + (((trow >> 3) ^ (ln & 7)) << 3) + (trow & 7)] = f2bf(u[r]);
    }
    __syncthreads();
    // G3: O = Oq + A@U -> global
    {
      f32x4 o = oq;
#pragma unroll
      for (int kt = 0; kt < 2; ++kt) {
        bf16x8 af = *(const bf16x8*)(Abh + (size_t)c * 4096 + (w * 16 + ln) * 64 +
                                     kt * 32 + lg * 8);
        bf16x8 uf = *(const bf16x8*)(&UbL[ln * 64 + (((kt * 4 + lg) ^ (ln & 7)) << 3)]);
        o = __builtin_amdgcn_mfma_f32_16x16x32_bf16(af, uf, o, 0, 0, 0);
      }
      const size_t orow =
          ((size_t)(b * TT + t0 + w * 16 + lg * 4) * HH + h) * 256 + slice * 16 + ln;
#pragma unroll
      for (int r = 0; r < 4; ++r) obuf[orow + (size_t)r * (HH * 256)] = o[r];
    }
    // G4: S = eL * (S + X^T@U); scatter hi/lo to Sh/Sl
#pragma unroll
    for (int mt = 0; mt < 4; ++mt) {
      f32x4 s = (mt == 0) ? S0 : (mt == 1) ? S1 : (mt == 2) ? S2 : S3;
#pragma unroll
      for (int kt = 0; kt < 2; ++kt) {
        bf16x8 xf = *(const bf16x8*)(XTbh + (size_t)(w * 64 + mt * 16 + ln) * TT +
                                     t0 + kt * 32 + lg * 8);
        bf16x8 uf = *(const bf16x8*)(&UbL[ln * 64 + (((kt * 4 + lg) ^ (ln & 7)) << 3)]);
        s = __builtin_amdgcn_mfma_f32_16x16x32_bf16(xf, uf, s, 0, 0, 0);
      }
#pragma unroll
      for (int r = 0; r < 4; ++r) {
        int krow = w * 64 + mt * 16 + lg * 4 + r;
        float sv = s[r] * ebh[(size_t)(t0 + 63) * 256 + krow];
        s[r] = sv;
        unsigned short hi = f2bf(sv);
        int sidx = ln * 256 + (((krow >> 3) ^ ln) << 3) + (krow & 7);
        ShL[sidx] = hi;
        SlL[sidx] = f2bf(sv - bf2f(hi));
      }
      if (mt == 0) S0 = s; else if (mt == 1) S1 = s; else if (mt == 2) S2 = s; else S3 = s;
    }
    __syncthreads();
  }
}

// ---------------- per-head RMSNorm ----------------
__global__ __launch_bounds__(256) void rmsnorm_kernel(
    const float* __restrict__ o, const float* __restrict__ w,
    float* __restrict__ out) {
  const int row = blockIdx.x;
  const int l = threadIdx.x & 63;
  const size_t base = (size_t)row * DD + (threadIdx.x >> 6) * 256 + l * 4;
  float4 x = *(const float4*)(o + base);
  float ss = x.x * x.x + x.y * x.y + x.z * x.z + x.w * x.w;
  ss = wave_sum(ss);
  float sc = rsqrtf(ss * (1.f / 256.f) + 1e-5f);
  float4 wv = *(const float4*)(w + l * 4);
  *(float4*)(out + base) = make_float4(x.x * sc * wv.x, x.y * sc * wv.y,
                                       x.z * sc * wv.z, x.w * sc * wv.w);
}

extern "C" void kernel_launch(void* const* d_in, const int* in_sizes, int n_in,
                              void* d_out, int out_size, void* d_ws,
                              size_t ws_size, hipStream_t stream) {
  const float* hidden = (const float*)d_in[0];
  const float* Wq = (const float*)d_in[1];
  const float* Wk = (const float*)d_in[2];
  const float* Wv = (const float*)d_in[3];
  const float* Wa = (const float*)d_in[4];
  const float* Wr = (const float*)d_in[5];
  const float* Wb = (const float*)d_in[6];
  const float* dt = (const float*)d_in[7];
  const float* norm_w = (const float*)d_in[8];
  const float* Wo = (const float*)d_in[9];
  float* out = (float*)d_out;

  const size_t NP = (size_t)BB * TT * DD;  // 8388608
  float* ws = (float*)d_ws;
  float* qproj = ws;
  float* kproj = ws + NP;
  float* vproj = ws + 2 * NP;
  float* gbuf = ws + 3 * NP;  // g [bh][T][K]; row63-per-chunk overwritten with e
  unsigned short* hbf = (unsigned short*)(ws + 4 * NP);          // NP bf16
  unsigned short* wT = (unsigned short*)(ws + 4 * NP + NP / 2);  // 6 x 1M bf16
  unsigned short* WT0 = wT;
  unsigned short* WT1 = wT + 1048576;
  unsigned short* WT2 = wT + 2 * 1048576;
  unsigned short* WT3 = wT + 3 * 1048576;
  unsigned short* WT4 = wT + 4 * 1048576;  // Wr^T hi (dead after bt3 -> Tb)
  unsigned short* WT5 = wT + 5 * 1048576;  // Wr^T lo
  float* betaT = ws + 4 * NP + NP / 2 + 3 * 1024 * 1024;  // 32K floats
  float* after_beta = betaT + 16 * TT;
  unsigned short* Qg = (unsigned short*)after_beta;        // NP bf16 (16MB)
  unsigned short* XTg = Qg + NP;                           // NP bf16 (16MB)
  unsigned short* Ab = XTg + NP;                           // 2M bf16 (4MB)
  unsigned short* Wgb = hbf;   // alias: hbf dead between projections and final cast
  unsigned short* Tbb = WT4;   // alias: WT4/WT5 dead after gemm_bt3 (2M bf16)
  unsigned short* hlo = (unsigned short*)qproj;  // alias: dead before q-GEMM
  float* rproj = out;
  float* normed = qproj;

  dim3 bt(256);
  cast2_bf16_kernel<<<8192, 256, 0, stream>>>(hidden, hbf, hlo);
  dim3 tg(32, 32), tb(32, 8);
  tcast2_kernel<<<tg, tb, 0, stream>>>(Wr, WT4, WT5, 1024, 1024);
  tcast_kernel<<<tg, tb, 0, stream>>>(Wq, WT0, 1024, 1024);
  tcast_kernel<<<tg, tb, 0, stream>>>(Wk, WT1, 1024, 1024);
  tcast_kernel<<<tg, tb, 0, stream>>>(Wv, WT2, 1024, 1024);
  tcast_kernel<<<tg, tb, 0, stream>>>(Wo, WT3, 1024, 1024);

  dim3 gmm(1024 / 128, 8192 / 128);
  gemm_bt3<<<gmm, bt, 0, stream>>>(hbf, hlo, WT4, WT5, rproj, 8192, 1024, 1024);
  gemm_bt<<<gmm, bt, 0, stream>>>(hbf, WT0, qproj, 8192, 1024, 1024);
  gemm_bt<<<gmm, bt, 0, stream>>>(hbf, WT1, kproj, 8192, 1024, 1024);
  gemm_bt<<<gmm, bt, 0, stream>>>(hbf, WT2, vproj, 8192, 1024, 1024);

  routing_kernel<<<8192, 256, 0, stream>>>(hidden, Wa, Wb, dt, rproj, qproj,
                                           kproj, vproj, gbuf, betaT);
  phaseA_kernel<<<512, 256, 0, stream>>>(kproj, qproj, gbuf, betaT, Tbb, Ab,
                                         Wgb, Qg, XTg);
  chunk_scan_kernel<<<256, 256, 0, stream>>>(Wgb, Qg, XTg, Tbb, Ab, vproj,
                                             gbuf, betaT, out);
  rmsnorm_kernel<<<8192, 256, 0, stream>>>(out, norm_w, normed);
  cast_bf16_kernel<<<8192, 256, 0, stream>>>(normed, hbf);
  gemm_bt<<<gmm, bt, 0, stream>>>(hbf, WT3, out, 8192, 1024, 1024);
}

// Round 7
// 833.145 us; speedup vs baseline: 4.4389x; 1.0838x over previous
//
#include <hip/hip_runtime.h>
#include <hip/hip_bf16.h>

#define TT 2048
#define BB 4
#define HH 4
#define DD 1024

using bf16x8 = __attribute__((ext_vector_type(8))) short;
using f32x4  = __attribute__((ext_vector_type(4))) float;

__device__ __forceinline__ float wave_sum(float x) {
#pragma unroll
  for (int off = 32; off >= 1; off >>= 1) x += __shfl_xor(x, off);
  return x;
}

__device__ __forceinline__ float siluf(float x) {
  return x / (1.f + expf(-x));
}

__device__ __forceinline__ unsigned short f2bf(float f) {
  unsigned u = __float_as_uint(f);
  u = (u + 0x7fffu + ((u >> 16) & 1u)) >> 16;
  return (unsigned short)u;
}
__device__ __forceinline__ float bf2f(unsigned short b) {
  return __uint_as_float(((unsigned)b) << 16);
}
__device__ __forceinline__ unsigned pack2(float a, float b) {
  return ((unsigned)f2bf(a)) | (((unsigned)f2bf(b)) << 16);
}

// ---------------- bf16 MFMA GEMM: C[M,N] = A[M,K] @ B[K,N], Bt is [N][K] ----
__global__ __launch_bounds__(256) void gemm_bt(const unsigned short* __restrict__ A,
                                               const unsigned short* __restrict__ Bt,
                                               float* __restrict__ C,
                                               int M, int N, int K) {
  __shared__ unsigned short As[128 * 64];
  __shared__ unsigned short Bs[128 * 64];
  const int tid = threadIdx.x;
  const int l = tid & 63;
  const int w = tid >> 6;
  const int wm = w >> 1, wn = w & 1;
  const int m0 = blockIdx.y * 128, n0 = blockIdx.x * 128;

  f32x4 acc[4][4];
#pragma unroll
  for (int i = 0; i < 4; ++i)
#pragma unroll
    for (int j = 0; j < 4; ++j) acc[i][j] = (f32x4){0.f, 0.f, 0.f, 0.f};

  int c_row[4], c_slot[4], c_dst[4];
#pragma unroll
  for (int it = 0; it < 4; ++it) {
    int chunk = it * 256 + tid;
    int row = chunk >> 3, s = chunk & 7;
    c_row[it] = row;
    c_slot[it] = s;
    c_dst[it] = row * 128 + ((s ^ (row & 7)) << 4);
  }
  int ra_off[2][4], rb_off[2][4];
#pragma unroll
  for (int kh = 0; kh < 2; ++kh)
#pragma unroll
    for (int f = 0; f < 4; ++f) {
      int rowA = wm * 64 + f * 16 + (l & 15);
      ra_off[kh][f] = rowA * 128 + (((kh * 4 + (l >> 4)) ^ (rowA & 7)) << 4);
      int rowB = wn * 64 + f * 16 + (l & 15);
      rb_off[kh][f] = rowB * 128 + (((kh * 4 + (l >> 4)) ^ (rowB & 7)) << 4);
    }

  for (int k0 = 0; k0 < K; k0 += 64) {
    uint4 ra[4], rb[4];
#pragma unroll
    for (int it = 0; it < 4; ++it) {
      ra[it] = *(const uint4*)(A + (size_t)(m0 + c_row[it]) * K + k0 + c_slot[it] * 8);
      rb[it] = *(const uint4*)(Bt + (size_t)(n0 + c_row[it]) * K + k0 + c_slot[it] * 8);
    }
    __syncthreads();
#pragma unroll
    for (int it = 0; it < 4; ++it) {
      *(uint4*)((char*)As + c_dst[it]) = ra[it];
      *(uint4*)((char*)Bs + c_dst[it]) = rb[it];
    }
    __syncthreads();
#pragma unroll
    for (int kh = 0; kh < 2; ++kh) {
      bf16x8 af[4], bfv[4];
#pragma unroll
      for (int f = 0; f < 4; ++f) {
        af[f] = *(const bf16x8*)((const char*)As + ra_off[kh][f]);
        bfv[f] = *(const bf16x8*)((const char*)Bs + rb_off[kh][f]);
      }
#pragma unroll
      for (int i = 0; i < 4; ++i)
#pragma unroll
        for (int j = 0; j < 4; ++j)
          acc[i][j] = __builtin_amdgcn_mfma_f32_16x16x32_bf16(af[i], bfv[j],
                                                              acc[i][j], 0, 0, 0);
    }
  }
  const int cn = n0 + wn * 64 + (l & 15);
  const int rbase = m0 + wm * 64 + ((l >> 4) << 2);
#pragma unroll
  for (int i = 0; i < 4; ++i)
#pragma unroll
    for (int j = 0; j < 4; ++j)
#pragma unroll
      for (int r = 0; r < 4; ++r)
        C[(size_t)(rbase + i * 16 + r) * N + cn + j * 16] = acc[i][j][r];
}

// ------------- split-bf16 3-term GEMM (fp32-accurate): C = Ah@Bh+Al@Bh+Ah@Bl
__global__ __launch_bounds__(256) void gemm_bt3(const unsigned short* __restrict__ Ah,
                                                const unsigned short* __restrict__ Al,
                                                const unsigned short* __restrict__ Bh,
                                                const unsigned short* __restrict__ Bl,
                                                float* __restrict__ C,
                                                int M, int N, int K) {
  __shared__ unsigned short Ash[128 * 64];
  __shared__ unsigned short Asl[128 * 64];
  __shared__ unsigned short Bsh[128 * 64];
  __shared__ unsigned short Bsl[128 * 64];
  const int tid = threadIdx.x;
  const int l = tid & 63;
  const int w = tid >> 6;
  const int wm = w >> 1, wn = w & 1;
  const int m0 = blockIdx.y * 128, n0 = blockIdx.x * 128;

  f32x4 acc[4][4];
#pragma unroll
  for (int i = 0; i < 4; ++i)
#pragma unroll
    for (int j = 0; j < 4; ++j) acc[i][j] = (f32x4){0.f, 0.f, 0.f, 0.f};

  int c_row[4], c_slot[4], c_dst[4];
#pragma unroll
  for (int it = 0; it < 4; ++it) {
    int chunk = it * 256 + tid;
    int row = chunk >> 3, s = chunk & 7;
    c_row[it] = row;
    c_slot[it] = s;
    c_dst[it] = row * 128 + ((s ^ (row & 7)) << 4);
  }
  int ra_off[2][4], rb_off[2][4];
#pragma unroll
  for (int kh = 0; kh < 2; ++kh)
#pragma unroll
    for (int f = 0; f < 4; ++f) {
      int rowA = wm * 64 + f * 16 + (l & 15);
      ra_off[kh][f] = rowA * 128 + (((kh * 4 + (l >> 4)) ^ (rowA & 7)) << 4);
      int rowB = wn * 64 + f * 16 + (l & 15);
      rb_off[kh][f] = rowB * 128 + (((kh * 4 + (l >> 4)) ^ (rowB & 7)) << 4);
    }

  for (int k0 = 0; k0 < K; k0 += 64) {
    uint4 rah[4], ral[4], rbh[4], rbl[4];
#pragma unroll
    for (int it = 0; it < 4; ++it) {
      size_t aoff = (size_t)(m0 + c_row[it]) * K + k0 + c_slot[it] * 8;
      size_t boff = (size_t)(n0 + c_row[it]) * K + k0 + c_slot[it] * 8;
      rah[it] = *(const uint4*)(Ah + aoff);
      ral[it] = *(const uint4*)(Al + aoff);
      rbh[it] = *(const uint4*)(Bh + boff);
      rbl[it] = *(const uint4*)(Bl + boff);
    }
    __syncthreads();
#pragma unroll
    for (int it = 0; it < 4; ++it) {
      *(uint4*)((char*)Ash + c_dst[it]) = rah[it];
      *(uint4*)((char*)Asl + c_dst[it]) = ral[it];
      *(uint4*)((char*)Bsh + c_dst[it]) = rbh[it];
      *(uint4*)((char*)Bsl + c_dst[it]) = rbl[it];
    }
    __syncthreads();
#pragma unroll
    for (int kh = 0; kh < 2; ++kh) {
      bf16x8 afh[4], bfh[4], tmp[4];
#pragma unroll
      for (int f = 0; f < 4; ++f) {
        afh[f] = *(const bf16x8*)((const char*)Ash + ra_off[kh][f]);
        bfh[f] = *(const bf16x8*)((const char*)Bsh + rb_off[kh][f]);
      }
#pragma unroll
      for (int i = 0; i < 4; ++i)
#pragma unroll
        for (int j = 0; j < 4; ++j)
          acc[i][j] = __builtin_amdgcn_mfma_f32_16x16x32_bf16(afh[i], bfh[j],
                                                              acc[i][j], 0, 0, 0);
#pragma unroll
      for (int f = 0; f < 4; ++f)
        tmp[f] = *(const bf16x8*)((const char*)Asl + ra_off[kh][f]);
#pragma unroll
      for (int i = 0; i < 4; ++i)
#pragma unroll
        for (int j = 0; j < 4; ++j)
          acc[i][j] = __builtin_amdgcn_mfma_f32_16x16x32_bf16(tmp[i], bfh[j],
                                                              acc[i][j], 0, 0, 0);
#pragma unroll
      for (int f = 0; f < 4; ++f)
        tmp[f] = *(const bf16x8*)((const char*)Bsl + rb_off[kh][f]);
#pragma unroll
      for (int i = 0; i < 4; ++i)
#pragma unroll
        for (int j = 0; j < 4; ++j)
          acc[i][j] = __builtin_amdgcn_mfma_f32_16x16x32_bf16(afh[i], tmp[j],
                                                              acc[i][j], 0, 0, 0);
    }
  }
  const int cn = n0 + wn * 64 + (l & 15);
  const int rbase = m0 + wm * 64 + ((l >> 4) << 2);
#pragma unroll
  for (int i = 0; i < 4; ++i)
#pragma unroll
    for (int j = 0; j < 4; ++j)
#pragma unroll
      for (int r = 0; r < 4; ++r)
        C[(size_t)(rbase + i * 16 + r) * N + cn + j * 16] = acc[i][j][r];
}

// ---------------- casts ----------------
__global__ __launch_bounds__(256) void cast_bf16_kernel(const float* __restrict__ in,
                                                        unsigned short* __restrict__ out) {
  const size_t i = ((size_t)blockIdx.x * 256 + threadIdx.x) * 4;
  float4 x = *(const float4*)(in + i);
  ushort4 o4;
  o4.x = f2bf(x.x);
  o4.y = f2bf(x.y);
  o4.z = f2bf(x.z);
  o4.w = f2bf(x.w);
  *(ushort4*)(out + i) = o4;
}

__global__ __launch_bounds__(256) void cast2_bf16_kernel(const float* __restrict__ in,
                                                         unsigned short* __restrict__ hi,
                                                         unsigned short* __restrict__ lo) {
  const size_t i = ((size_t)blockIdx.x * 256 + threadIdx.x) * 4;
  float4 x = *(const float4*)(in + i);
  ushort4 h4, l4;
  h4.x = f2bf(x.x); l4.x = f2bf(x.x - bf2f(h4.x));
  h4.y = f2bf(x.y); l4.y = f2bf(x.y - bf2f(h4.y));
  h4.z = f2bf(x.z); l4.z = f2bf(x.z - bf2f(h4.z));
  h4.w = f2bf(x.w); l4.w = f2bf(x.w - bf2f(h4.w));
  *(ushort4*)(hi + i) = h4;
  *(ushort4*)(lo + i) = l4;
}

// W [R][C] f32 row-major -> WT [C][R] bf16 (transpose + cast)
__global__ __launch_bounds__(256) void tcast_kernel(const float* __restrict__ W,
                                                    unsigned short* __restrict__ WT,
                                                    int R, int C) {
  __shared__ float tile[32][33];
  const int tx = threadIdx.x, ty = threadIdx.y;
  const int c0 = blockIdx.x * 32, r0 = blockIdx.y * 32;
#pragma unroll
  for (int i = 0; i < 4; ++i)
    tile[ty + 8 * i][tx] = W[(size_t)(r0 + ty + 8 * i) * C + c0 + tx];
  __syncthreads();
#pragma unroll
  for (int i = 0; i < 4; ++i)
    WT[(size_t)(c0 + ty + 8 * i) * R + r0 + tx] = f2bf(tile[tx][ty + 8 * i]);
}

__global__ __launch_bounds__(256) void tcast2_kernel(const float* __restrict__ W,
                                                     unsigned short* __restrict__ WTh,
                                                     unsigned short* __restrict__ WTl,
                                                     int R, int C) {
  __shared__ float tile[32][33];
  const int tx = threadIdx.x, ty = threadIdx.y;
  const int c0 = blockIdx.x * 32, r0 = blockIdx.y * 32;
#pragma unroll
  for (int i = 0; i < 4; ++i)
    tile[ty + 8 * i][tx] = W[(size_t)(r0 + ty + 8 * i) * C + c0 + tx];
  __syncthreads();
#pragma unroll
  for (int i = 0; i < 4; ++i) {
    float x = tile[tx][ty + 8 * i];
    unsigned short h = f2bf(x);
    WTh[(size_t)(c0 + ty + 8 * i) * R + r0 + tx] = h;
    WTl[(size_t)(c0 + ty + 8 * i) * R + r0 + tx] = f2bf(x - bf2f(h));
  }
}

// ---------------- routing: a/beta dots, top-4, silu+norms, dense LOG-decay ----
__global__ __launch_bounds__(256) void routing_kernel(
    const float* __restrict__ hidden, const float* __restrict__ Wa,
    const float* __restrict__ Wb, const float* __restrict__ dt,
    const float* __restrict__ rproj, float* __restrict__ qk,
    float* __restrict__ kk_, float* __restrict__ vv, float* __restrict__ gbuf,
    float* __restrict__ betaT) {
  const int row = blockIdx.x;  // b*T + t
  const int b = row >> 11;
  const int t = row & (TT - 1);
  const int h = threadIdx.x >> 6;
  const int l = threadIdx.x & 63;
  const size_t base = (size_t)row * DD + h * 256;

  const float* hrow = hidden + (size_t)row * DD;
  float aa = 0.f, bb = 0.f;
#pragma unroll
  for (int i = 0; i < 16; ++i) {
    float hv = hrow[l + 64 * i];
    aa = fmaf(hv, Wa[(l + 64 * i) * HH + h], aa);
    bb = fmaf(hv, Wb[(l + 64 * i) * HH + h], bb);
  }
  aa = wave_sum(aa);
  bb = wave_sum(bb);
  float sp = (aa > 20.f) ? aa : log1pf(expf(aa));
  float a_ = -sp * expf(dt[h]);
  float beta = 1.f / (1.f + expf(-bb));
  const int bh = b * HH + h;
  if (l == 0) betaT[(size_t)bh * TT + t] = beta;

  float4 rt4 = *(const float4*)(rproj + base + l * 4);
  float rv[4] = {rt4.x, rt4.y, rt4.z, rt4.w};
  int used = 0;
  int widx[4];
  float wsig[4], wg[4], wkfac[4];
#pragma unroll
  for (int it = 0; it < 4; ++it) {
    float bv = -3.4e38f;
    int bi = 0x7fffffff;
#pragma unroll
    for (int c = 0; c < 4; ++c) {
      bool ok = !(used & (1 << c));
      float v = rv[c];
      if (ok && (v > bv)) {
        bv = v;
        bi = l * 4 + c;
      }
    }
#pragma unroll
    for (int off = 32; off >= 1; off >>= 1) {
      float ov = __shfl_xor(bv, off);
      int oi = __shfl_xor(bi, off);
      if (ov > bv || (ov == bv && oi < bi)) {
        bv = ov;
        bi = oi;
      }
    }
    widx[it] = bi;
    wsig[it] = 1.f / (1.f + expf(-bv));
    if ((bi >> 2) == l) used |= 1 << (bi & 3);
  }
  float wsum = wsig[0] + wsig[1] + wsig[2] + wsig[3] + 1e-6f;
#pragma unroll
  for (int it = 0; it < 4; ++it) {
    float g = a_ * (wsig[it] / wsum);
    wg[it] = g;
    wkfac[it] = 1.f - expf(g);
  }

  float4 kv4 = *(const float4*)(kk_ + base + l * 4);
  float kvv[4] = {kv4.x, kv4.y, kv4.z, kv4.w};
  float kmask[4], ddv[4];
#pragma unroll
  for (int c = 0; c < 4; ++c) {
    int slot = l * 4 + c;
    float f = 0.f, d = 0.f;
#pragma unroll
    for (int it = 0; it < 4; ++it) {
      bool hit = (slot == widx[it]);
      f = hit ? wkfac[it] : f;
      d = hit ? wg[it] : d;
    }
    kmask[c] = siluf(kvv[c]) * f;
    ddv[c] = d;  // log-decay (0 for unselected slots)
  }
  float ss = kmask[0] * kmask[0] + kmask[1] * kmask[1] + kmask[2] * kmask[2] +
             kmask[3] * kmask[3];
  ss = wave_sum(ss);
  float kn = rsqrtf(ss + 1e-6f);
  *(float4*)(kk_ + base + l * 4) =
      make_float4(kmask[0] * kn, kmask[1] * kn, kmask[2] * kn, kmask[3] * kn);
  *(float4*)(gbuf + ((size_t)bh * TT + t) * 256 + l * 4) =
      make_float4(ddv[0], ddv[1], ddv[2], ddv[3]);

  float4 qv4 = *(const float4*)(qk + base + l * 4);
  float qs[4] = {siluf(qv4.x), siluf(qv4.y), siluf(qv4.z), siluf(qv4.w)};
  float qss = qs[0] * qs[0] + qs[1] * qs[1] + qs[2] * qs[2] + qs[3] * qs[3];
  qss = wave_sum(qss);
  float qn = rsqrtf(qss + 1e-6f) * 0.0625f;
  *(float4*)(qk + base + l * 4) =
      make_float4(qs[0] * qn, qs[1] * qn, qs[2] * qn, qs[3] * qn);

  float4 vv4 = *(const float4*)(vv + base + l * 4);
  *(float4*)(vv + base + l * 4) =
      make_float4(siluf(vv4.x), siluf(vv4.y), siluf(vv4.z), siluf(vv4.w));
}

// ---------------- phase A (MFMA): cumsum; P=[Qw;W]@X^T via mfma; Tinv; bf16 out
__global__ __launch_bounds__(256) void phaseA_kernel(
    const float* __restrict__ kproj, const float* __restrict__ qproj,
    float* __restrict__ expcG,  // in: g [bh][T][K]; out: row t0+63 = exp(csum)
    const float* __restrict__ betaT, unsigned short* __restrict__ TinvB,
    unsigned short* __restrict__ AB, unsigned short* __restrict__ Wg,
    unsigned short* __restrict__ Qg, unsigned short* __restrict__ XTg) {
  __shared__ unsigned short XB[64 * 256];   // X rows [t][k], 16B-slot ^ (t&7)
  __shared__ unsigned short QW[128 * 256];  // rows 0-63 Qw, 64-127 W, same swizzle
  __shared__ float Mb[64 * 68];             // M fp32 (then Tinv), padded
  const int bid = blockIdx.x;
  const int bh = bid >> 5, c = bid & 31;
  const int b = bh >> 2, h = bh & 3;
  const int t0 = c * 64;
  const int tid = threadIdx.x;
  const int w = tid >> 6, l = tid & 63;
  const int ln = l & 15, lg = l >> 4;

  // ---- stage 0: cumsum + bf16 staging (LDS + global Wg/Qg) ----
  {
    float cacc = 0.f;
    const int slot = tid >> 3, byt = tid & 7;
#pragma unroll 4
    for (int i = 0; i < 64; ++i) {
      size_t ga = ((size_t)bh * TT + t0 + i) * 256 + tid;
      size_t pa = (((size_t)b * TT + t0 + i) * HH + h) * 256 + tid;
      cacc += expcG[ga];
      float e = expf(cacc);
      float ei = __builtin_amdgcn_rcpf(e);
      float kv = kproj[pa], qv = qproj[pa];
      unsigned short wb = f2bf(kv * e);
      unsigned short qb = f2bf(qv * e);
      unsigned short xb = f2bf(kv * ei);
      Wg[ga] = wb;
      Qg[ga] = qb;
      int sw = ((slot ^ (i & 7)) << 3) + byt;
      XB[i * 256 + sw] = xb;
      QW[i * 256 + sw] = qb;
      QW[(i + 64) * 256 + sw] = wb;
      if (i == 63) expcG[ga] = e;  // only row phase B reads
    }
  }
  __syncthreads();

  // ---- MFMA: P[128][64] = QW @ XB^T; wave w owns rows w*32..w*32+31 ----
  f32x4 acc[2][4];
#pragma unroll
  for (int tr = 0; tr < 2; ++tr)
#pragma unroll
    for (int tc = 0; tc < 4; ++tc) acc[tr][tc] = (f32x4){0.f, 0.f, 0.f, 0.f};
  const int R0 = w * 32;
#pragma unroll
  for (int kt = 0; kt < 8; ++kt) {
    const int ks = kt * 4 + lg;  // 16B slot 0..31
    const int ra0 = R0 + ln, ra1 = R0 + 16 + ln;
    bf16x8 a0 = *(const bf16x8*)&QW[ra0 * 256 + ((ks ^ (ra0 & 7)) << 3)];
    bf16x8 a1 = *(const bf16x8*)&QW[ra1 * 256 + ((ks ^ (ra1 & 7)) << 3)];
#pragma unroll
    for (int tc = 0; tc < 4; ++tc) {
      const int br = tc * 16 + ln;
      bf16x8 bf_ = *(const bf16x8*)&XB[br * 256 + ((ks ^ (br & 7)) << 3)];
      acc[0][tc] = __builtin_amdgcn_mfma_f32_16x16x32_bf16(a0, bf_, acc[0][tc], 0, 0, 0);
      acc[1][tc] = __builtin_amdgcn_mfma_f32_16x16x32_bf16(a1, bf_, acc[1][tc], 0, 0, 0);
    }
  }
  // scatter: waves 0-1 -> A (masked, bf16, global); waves 2-3 -> M (fp32, LDS)
  const size_t gb = (((size_t)bh * 32 + c) << 12);
  if (w < 2) {
#pragma unroll
    for (int tr = 0; tr < 2; ++tr)
#pragma unroll
      for (int tc = 0; tc < 4; ++tc)
#pragma unroll
        for (int r = 0; r < 4; ++r) {
          int i = R0 + tr * 16 + lg * 4 + r;
          int s = tc * 16 + ln;
          AB[gb + i * 64 + s] = (s <= i) ? f2bf(acc[tr][tc][r]) : (unsigned short)0;
        }
  } else {
#pragma unroll
    for (int tr = 0; tr < 2; ++tr)
#pragma unroll
      for (int tc = 0; tc < 4; ++tc)
#pragma unroll
        for (int r = 0; r < 4; ++r) {
          int i = R0 - 64 + tr * 16 + lg * 4 + r;
          Mb[i * 68 + tc * 16 + ln] = acc[tr][tc][r];
        }
  }
  __syncthreads();

  // ---- wave 0: Tinv = (I + diag(beta) tril_strict(M))^{-1}; waves 1-3: XTg ----
  if (w == 0) {
    float tcol[64];
#pragma unroll
    for (int i = 0; i < 64; ++i) {
      float bi = betaT[(size_t)bh * TT + t0 + i];
      float a_ = (l == i) ? 1.f : 0.f;
#pragma unroll
      for (int s = 0; s < i; ++s)
        a_ = fmaf(-bi * Mb[i * 68 + s], tcol[s], a_);
      tcol[i] = a_;
    }
#pragma unroll
    for (int s = 0; s < 64; ++s) Mb[s * 68 + l] = tcol[s];
  } else {
    const int kk1 = tid - 64;  // 0..191
#pragma unroll 1
    for (int pass = 0; pass < 2; ++pass) {
      if (pass == 1 && kk1 >= 64) break;
      const int k = (pass == 0) ? kk1 : (192 + kk1);
      unsigned short* dst = XTg + ((size_t)bh * 256 + k) * TT + t0;
      const int kslot = k >> 3, kb = k & 7;
#pragma unroll 1
      for (int jq = 0; jq < 8; ++jq) {
        unsigned short e[8];
#pragma unroll
        for (int j = 0; j < 8; ++j) {
          int t = jq * 8 + j;
          e[j] = XB[t * 256 + (((kslot ^ (t & 7)) << 3) + kb)];
        }
        uint4 o;
        o.x = ((unsigned)e[0]) | (((unsigned)e[1]) << 16);
        o.y = ((unsigned)e[2]) | (((unsigned)e[3]) << 16);
        o.z = ((unsigned)e[4]) | (((unsigned)e[5]) << 16);
        o.w = ((unsigned)e[6]) | (((unsigned)e[7]) << 16);
        *(uint4*)(dst + jq * 8) = o;
      }
    }
  }
  __syncthreads();
  // ---- all: write Tinv bf16 [i][s] row-major ----
  {
    const int i = tid >> 2;
    const int sb = (tid & 3) * 16;
#pragma unroll
    for (int mq = 0; mq < 4; ++mq) {
      float v0 = Mb[i * 68 + sb + mq * 4 + 0];
      float v1 = Mb[i * 68 + sb + mq * 4 + 1];
      float v2 = Mb[i * 68 + sb + mq * 4 + 2];
      float v3 = Mb[i * 68 + sb + mq * 4 + 3];
      uint2 p;
      p.x = pack2(v0, v1);
      p.y = pack2(v2, v3);
      *(uint2*)(TinvB + gb + (size_t)i * 64 + sb + mq * 4) = p;
    }
  }
}

// ---------------- phase B: software-pipelined MFMA chunk scan ----------------
// block=(bh, vslice16): 256 x 256 (4 waves). All global inputs are
// chunk-independent -> double-buffer W/Q/V/beta in regs (prefetch c+1 during c);
// Tinv/A issued at chunk top; XT/eL issued right after barrier 1. LDS stores
// packed as ushort4.
__global__ __launch_bounds__(256) void chunk_scan_kernel(
    const unsigned short* __restrict__ Wg, const unsigned short* __restrict__ Qg,
    const unsigned short* __restrict__ XTg, const unsigned short* __restrict__ Tb,
    const unsigned short* __restrict__ Ab, const float* __restrict__ vproj,
    const float* __restrict__ expcG, const float* __restrict__ betaT,
    float* __restrict__ obuf) {
  __shared__ unsigned short ShL[16 * 256];  // [n][k], 16B-slot swizzle ^n
  __shared__ unsigned short SlL[16 * 256];
  __shared__ unsigned short R2bL[16 * 64];  // [n][t], slot swizzle ^(n&7)
  __shared__ unsigned short UbL[16 * 64];
  const int bid = blockIdx.x;
  const int bh = bid & 15, slice = bid >> 4;  // all slices of bh -> same XCD
  const int b = bh >> 2, h = bh & 3;
  const int tid = threadIdx.x;
  const int w = tid >> 6;
  const int l = tid & 63;
  const int ln = l & 15, lg = l >> 4;

  const unsigned short* Wbh = Wg + (size_t)bh * TT * 256;
  const unsigned short* Qbh = Qg + (size_t)bh * TT * 256;
  const unsigned short* XTbh = XTg + (size_t)bh * 256 * TT;
  const unsigned short* Tbh = Tb + (size_t)bh * 32 * 4096;
  const unsigned short* Abh = Ab + (size_t)bh * 32 * 4096;
  const float* betabh = betaT + (size_t)bh * TT;
  const float* ebh = expcG + (size_t)bh * TT * 256;

  f32x4 S0 = {0.f, 0.f, 0.f, 0.f}, S1 = S0, S2 = S0, S3 = S0;

  // R2/U pack-write offset (4 consecutive t share a 16B slot)
  const int ru_off =
      ln * 64 + ((((w * 2) + (lg >> 1)) ^ (ln & 7)) << 3) + (lg & 1) * 4;

  bf16x8 wA[8], qA[8], wB[8], qB[8];
  float4 vA, bA, vB, bB;

#define LOADWQV(W_, Q_, V_, B_, c_)                                            \
  {                                                                            \
    const int t0_ = (c_) * 64;                                                 \
    _Pragma("unroll") for (int kt = 0; kt < 8; ++kt) {                         \
      const size_t arow =                                                      \
          (size_t)(t0_ + w * 16 + ln) * 256 + kt * 32 + lg * 8;                \
      W_[kt] = *(const bf16x8*)(Wbh + arow);                                   \
      Q_[kt] = *(const bf16x8*)(Qbh + arow);                                   \
    }                                                                          \
    const size_t vrow =                                                        \
        ((size_t)(b * TT + t0_ + w * 16 + lg * 4) * HH + h) * 256 +            \
        slice * 16 + ln;                                                       \
    V_.x = vproj[vrow];                                                        \
    V_.y = vproj[vrow + HH * 256];                                             \
    V_.z = vproj[vrow + 2 * HH * 256];                                         \
    V_.w = vproj[vrow + 3 * HH * 256];                                         \
    B_ = *(const float4*)(betabh + t0_ + w * 16 + lg * 4);                     \
  }

#define SSTORE(S_, E_, mt_)                                                    \
  {                                                                            \
    S_[0] *= E_.x;                                                             \
    S_[1] *= E_.y;                                                             \
    S_[2] *= E_.z;                                                             \
    S_[3] *= E_.w;                                                             \
    ushort4 hp, lp;                                                            \
    hp.x = f2bf(S_[0]); lp.x = f2bf(S_[0] - bf2f(hp.x));                       \
    hp.y = f2bf(S_[1]); lp.y = f2bf(S_[1] - bf2f(hp.y));                       \
    hp.z = f2bf(S_[2]); lp.z = f2bf(S_[2] - bf2f(hp.z));                       \
    hp.w = f2bf(S_[3]); lp.w = f2bf(S_[3] - bf2f(hp.w));                       \
    const int so_ = ln * 256 +                                                 \
                    ((((w * 8) + (mt_)*2 + (lg >> 1)) ^ ln) << 3) +            \
                    (lg & 1) * 4;                                              \
    *(ushort4*)(&ShL[so_]) = hp;                                               \
    *(ushort4*)(&SlL[so_]) = lp;                                               \
  }

#define CHUNK(Wc, Qc, Vc, Bc, Wn, Qn, Vn, Bn, c_)                              \
  {                                                                            \
    const int c = (c_);                                                        \
    const size_t tb_base = (size_t)c * 4096 + (w * 16 + ln) * 64 + lg * 8;     \
    bf16x8 tf0 = *(const bf16x8*)(Tbh + tb_base);                              \
    bf16x8 tf1 = *(const bf16x8*)(Tbh + tb_base + 32);                         \
    bf16x8 af0 = *(const bf16x8*)(Abh + tb_base);                              \
    bf16x8 af1 = *(const bf16x8*)(Abh + tb_base + 32);                         \
    f32x4 rhs = {0.f, 0.f, 0.f, 0.f}, oq = {0.f, 0.f, 0.f, 0.f};               \
    if (c > 0) {                                                               \
      _Pragma("unroll") for (int kt = 0; kt < 8; ++kt) {                       \
        const int sro = ln * 256 + (((kt * 4 + lg) ^ ln) << 3);                \
        bf16x8 sh = *(const bf16x8*)(&ShL[sro]);                               \
        bf16x8 sl = *(const bf16x8*)(&SlL[sro]);                               \
        rhs = __builtin_amdgcn_mfma_f32_16x16x32_bf16(Wc[kt], sh, rhs, 0, 0, 0); \
        rhs = __builtin_amdgcn_mfma_f32_16x16x32_bf16(Wc[kt], sl, rhs, 0, 0, 0); \
        oq = __builtin_amdgcn_mfma_f32_16x16x32_bf16(Qc[kt], sh, oq, 0, 0, 0); \
        oq = __builtin_amdgcn_mfma_f32_16x16x32_bf16(Qc[kt], sl, oq, 0, 0, 0); \
      }                                                                        \
    }                                                                          \
    if (c + 1 < 32) LOADWQV(Wn, Qn, Vn, Bn, c + 1);                            \
    {                                                                          \
      ushort4 r2p;                                                             \
      r2p.x = f2bf(Bc.x * (Vc.x - rhs[0]));                                    \
      r2p.y = f2bf(Bc.y * (Vc.y - rhs[1]));                                    \
      r2p.z = f2bf(Bc.z * (Vc.z - rhs[2]));                                    \
      r2p.w = f2bf(Bc.w * (Vc.w - rhs[3]));                                    \
      *(ushort4*)(&R2bL[ru_off]) = r2p;                                        \
    }                                                                          \
    __syncthreads();                                                           \
    bf16x8 xf0a, xf0b, xf1a, xf1b, xf2a, xf2b, xf3a, xf3b;                     \
    {                                                                          \
      const size_t xb = (size_t)(w * 64 + ln) * TT + c * 64 + lg * 8;          \
      xf0a = *(const bf16x8*)(XTbh + xb);                                      \
      xf0b = *(const bf16x8*)(XTbh + xb + 32);                                 \
      xf1a = *(const bf16x8*)(XTbh + xb + 16 * TT);                            \
      xf1b = *(const bf16x8*)(XTbh + xb + 16 * TT + 32);                       \
      xf2a = *(const bf16x8*)(XTbh + xb + 32 * TT);                            \
      xf2b = *(const bf16x8*)(XTbh + xb + 32 * TT + 32);                       \
      xf3a = *(const bf16x8*)(XTbh + xb + 48 * TT);                            \
      xf3b = *(const bf16x8*)(XTbh + xb + 48 * TT + 32);                       \
    }                                                                          \
    const float* ebase = ebh + (size_t)(c * 64 + 63) * 256 + w * 64 + lg * 4;  \
    float4 eL0 = *(const float4*)(ebase);                                      \
    float4 eL1 = *(const float4*)(ebase + 16);                                 \
    float4 eL2 = *(const float4*)(ebase + 32);                                 \
    float4 eL3 = *(const float4*)(ebase + 48);                                 \
    {                                                                          \
      bf16x8 rf0 = *(const bf16x8*)(&R2bL[ln * 64 + (((0 + lg) ^ (ln & 7)) << 3)]); \
      bf16x8 rf1 = *(const bf16x8*)(&R2bL[ln * 64 + (((4 + lg) ^ (ln & 7)) << 3)]); \
      f32x4 u = {0.f, 0.f, 0.f, 0.f};                                          \
      u = __builtin_amdgcn_mfma_f32_16x16x32_bf16(tf0, rf0, u, 0, 0, 0);       \
      u = __builtin_amdgcn_mfma_f32_16x16x32_bf16(tf1, rf1, u, 0, 0, 0);       \
      ushort4 up;                                                              \
      up.x = f2bf(u[0]);                                                       \
      up.y = f2bf(u[1]);                                                       \
      up.z = f2bf(u[2]);                                                       \
      up.w = f2bf(u[3]);                                                       \
      *(ushort4*)(&UbL[ru_off]) = up;                                          \
    }                                                                          \
    __syncthreads();                                                           \
    bf16x8 uf0 = *(const bf16x8*)(&UbL[ln * 64 + (((0 + lg) ^ (ln & 7)) << 3)]); \
    bf16x8 uf1 = *(const bf16x8*)(&UbL[ln * 64 + (((4 + lg) ^ (ln & 7)) << 3)]); \
    {                                                                          \
      f32x4 o = oq;                                                            \
      o = __builtin_amdgcn_mfma_f32_16x16x32_bf16(af0, uf0, o, 0, 0, 0);       \
      o = __builtin_amdgcn_mfma_f32_16x16x32_bf16(af1, uf1, o, 0, 0, 0);       \
      const size_t orow =                                                      \
          ((size_t)(b * TT + c * 64 + w * 16 + lg * 4) * HH + h) * 256 +       \
          slice * 16 + ln;                                                     \
      obuf[orow] = o[0];                                                       \
      obuf[orow + HH * 256] = o[1];                                            \
      obuf[orow + 2 * HH * 256] = o[2];                                        \
      obuf[orow + 3 * HH * 256] = o[3];                                        \
    }                                                                          \
    S0 = __builtin_amdgcn_mfma_f32_16x16x32_bf16(xf0a, uf0, S0, 0, 0, 0);      \
    S0 = __builtin_amdgcn_mfma_f32_16x16x32_bf16(xf0b, uf1, S0, 0, 0, 0);      \
    S1 = __builtin_amdgcn_mfma_f32_16x16x32_bf16(xf1a, uf0, S1, 0, 0, 0);      \
    S1 = __builtin_amdgcn_mfma_f32_16x16x32_bf16(xf1b, uf1, S1, 0, 0, 0);      \
    S2 = __builtin_amdgcn_mfma_f32_16x16x32_bf16(xf2a, uf0, S2, 0, 0, 0);      \
    S2 = __builtin_amdgcn_mfma_f32_16x16x32_bf16(xf2b, uf1, S2, 0, 0, 0);      \
    S3 = __builtin_amdgcn_mfma_f32_16x16x32_bf16(xf3a, uf0, S3, 0, 0, 0);      \
    S3 = __builtin_amdgcn_mfma_f32_16x16x32_bf16(xf3b, uf1, S3, 0, 0, 0);      \
    SSTORE(S0, eL0, 0);                                                        \
    SSTORE(S1, eL1, 1);                                                        \
    SSTORE(S2, eL2, 2);                                                        \
    SSTORE(S3, eL3, 3);                                                        \
    __syncthreads();                                                           \
  }

  LOADWQV(wA, qA, vA, bA, 0);
  for (int cc = 0; cc < 32; cc += 2) {
    CHUNK(wA, qA, vA, bA, wB, qB, vB, bB, cc);
    CHUNK(wB, qB, vB, bB, wA, qA, vA, bA, cc + 1);
  }
#undef CHUNK
#undef SSTORE
#undef LOADWQV
}

// ---------------- per-head RMSNorm ----------------
__global__ __launch_bounds__(256) void rmsnorm_kernel(
    const float* __restrict__ o, const float* __restrict__ w,
    float* __restrict__ out) {
  const int row = blockIdx.x;
  const int l = threadIdx.x & 63;
  const size_t base = (size_t)row * DD + (threadIdx.x >> 6) * 256 + l * 4;
  float4 x = *(const float4*)(o + base);
  float ss = x.x * x.x + x.y * x.y + x.z * x.z + x.w * x.w;
  ss = wave_sum(ss);
  float sc = rsqrtf(ss * (1.f / 256.f) + 1e-5f);
  float4 wv = *(const float4*)(w + l * 4);
  *(float4*)(out + base) = make_float4(x.x * sc * wv.x, x.y * sc * wv.y,
                                       x.z * sc * wv.z, x.w * sc * wv.w);
}

extern "C" void kernel_launch(void* const* d_in, const int* in_sizes, int n_in,
                              void* d_out, int out_size, void* d_ws,
                              size_t ws_size, hipStream_t stream) {
  const float* hidden = (const float*)d_in[0];
  const float* Wq = (const float*)d_in[1];
  const float* Wk = (const float*)d_in[2];
  const float* Wv = (const float*)d_in[3];
  const float* Wa = (const float*)d_in[4];
  const float* Wr = (const float*)d_in[5];
  const float* Wb = (const float*)d_in[6];
  const float* dt = (const float*)d_in[7];
  const float* norm_w = (const float*)d_in[8];
  const float* Wo = (const float*)d_in[9];
  float* out = (float*)d_out;

  const size_t NP = (size_t)BB * TT * DD;  // 8388608
  float* ws = (float*)d_ws;
  float* qproj = ws;
  float* kproj = ws + NP;
  float* vproj = ws + 2 * NP;
  float* gbuf = ws + 3 * NP;  // g [bh][T][K]; row63-per-chunk overwritten with e
  unsigned short* hbf = (unsigned short*)(ws + 4 * NP);          // NP bf16
  unsigned short* wT = (unsigned short*)(ws + 4 * NP + NP / 2);  // 6 x 1M bf16
  unsigned short* WT0 = wT;
  unsigned short* WT1 = wT + 1048576;
  unsigned short* WT2 = wT + 2 * 1048576;
  unsigned short* WT3 = wT + 3 * 1048576;
  unsigned short* WT4 = wT + 4 * 1048576;  // Wr^T hi (dead after bt3 -> Tb)
  unsigned short* WT5 = wT + 5 * 1048576;  // Wr^T lo
  float* betaT = ws + 4 * NP + NP / 2 + 3 * 1024 * 1024;  // 32K floats
  float* after_beta = betaT + 16 * TT;
  unsigned short* Qg = (unsigned short*)after_beta;        // NP bf16 (16MB)
  unsigned short* XTg = Qg + NP;                           // NP bf16 (16MB)
  unsigned short* Ab = XTg + NP;                           // 2M bf16 (4MB)
  unsigned short* Wgb = hbf;   // alias: hbf dead between projections and final cast
  unsigned short* Tbb = WT4;   // alias: WT4/WT5 dead after gemm_bt3 (2M bf16)
  unsigned short* hlo = (unsigned short*)qproj;  // alias: dead before q-GEMM
  float* rproj = out;
  float* normed = qproj;

  dim3 bt(256);
  cast2_bf16_kernel<<<8192, 256, 0, stream>>>(hidden, hbf, hlo);
  dim3 tg(32, 32), tb(32, 8);
  tcast2_kernel<<<tg, tb, 0, stream>>>(Wr, WT4, WT5, 1024, 1024);
  tcast_kernel<<<tg, tb, 0, stream>>>(Wq, WT0, 1024, 1024);
  tcast_kernel<<<tg, tb, 0, stream>>>(Wk, WT1, 1024, 1024);
  tcast_kernel<<<tg, tb, 0, stream>>>(Wv, WT2, 1024, 1024);
  tcast_kernel<<<tg, tb, 0, stream>>>(Wo, WT3, 1024, 1024);

  dim3 gmm(1024 / 128, 8192 / 128);
  gemm_bt3<<<gmm, bt, 0, stream>>>(hbf, hlo, WT4, WT5, rproj, 8192, 1024, 1024);
  gemm_bt<<<gmm, bt, 0, stream>>>(hbf, WT0, qproj, 8192, 1024, 1024);
  gemm_bt<<<gmm, bt, 0, stream>>>(hbf, WT1, kproj, 8192, 1024, 1024);
  gemm_bt<<<gmm, bt, 0, stream>>>(hbf, WT2, vproj, 8192, 1024, 1024);

  routing_kernel<<<8192, 256, 0, stream>>>(hidden, Wa, Wb, dt, rproj, qproj,
                                           kproj, vproj, gbuf, betaT);
  phaseA_kernel<<<512, 256, 0, stream>>>(kproj, qproj, gbuf, betaT, Tbb, Ab,
                                         Wgb, Qg, XTg);
  chunk_scan_kernel<<<256, 256, 0, stream>>>(Wgb, Qg, XTg, Tbb, Ab, vproj,
                                             gbuf, betaT, out);
  rmsnorm_kernel<<<8192, 256, 0, stream>>>(out, norm_w, normed);
  cast_bf16_kernel<<<8192, 256, 0, stream>>>(normed, hbf);
  gemm_bt<<<gmm, bt, 0, stream>>>(hbf, WT3, out, 8192, 1024, 1024);
}

// Round 8
// 465.225 us; speedup vs baseline: 7.9495x; 1.7908x over previous
//
#include <hip/hip_runtime.h>
#include <hip/hip_bf16.h>

#define TT 2048
#define BB 4
#define HH 4
#define DD 1024

using bf16x8 = __attribute__((ext_vector_type(8))) short;
using f32x4  = __attribute__((ext_vector_type(4))) float;

__device__ __forceinline__ float wave_sum(float x) {
#pragma unroll
  for (int off = 32; off >= 1; off >>= 1) x += __shfl_xor(x, off);
  return x;
}

__device__ __forceinline__ float siluf(float x) {
  return x / (1.f + expf(-x));
}

__device__ __forceinline__ unsigned short f2bf(float f) {
  unsigned u = __float_as_uint(f);
  u = (u + 0x7fffu + ((u >> 16) & 1u)) >> 16;
  return (unsigned short)u;
}
__device__ __forceinline__ float bf2f(unsigned short b) {
  return __uint_as_float(((unsigned)b) << 16);
}
__device__ __forceinline__ unsigned pack2(float a, float b) {
  return ((unsigned)f2bf(a)) | (((unsigned)f2bf(b)) << 16);
}

// async global->LDS, 16B per lane; dest = lds base + lane*16 (linear)
__device__ __forceinline__ void gload_lds16(const void* g, void* l) {
  __builtin_amdgcn_global_load_lds(
      (const __attribute__((address_space(1))) unsigned int*)g,
      (__attribute__((address_space(3))) unsigned int*)l, 16, 0, 0);
}

// ---------------- bf16 MFMA GEMM: C[M,N] = A[M,K] @ B[K,N], Bt is [N][K] ----
// global_load_lds staging (pre-swizzled source, linear LDS dest) + XCD swizzle.
__global__ __launch_bounds__(256) void gemm_bt(const unsigned short* __restrict__ A,
                                               const unsigned short* __restrict__ Bt,
                                               float* __restrict__ C,
                                               int M, int N, int K) {
  __shared__ unsigned short As[128 * 64];
  __shared__ unsigned short Bs[128 * 64];
  const int tid = threadIdx.x;
  const int l = tid & 63;
  const int w = tid >> 6;
  const int wm = w >> 1, wn = w & 1;
  // XCD-bijective swizzle: same A-panel (all n-tiles) -> same XCD
  const int bid = blockIdx.x;
  const int nt = N >> 7;
  const int swz = (bid & 7) * ((int)gridDim.x >> 3) + (bid >> 3);
  const int m0 = (swz / nt) * 128, n0 = (swz % nt) * 128;

  f32x4 acc[4][4];
#pragma unroll
  for (int i = 0; i < 4; ++i)
#pragma unroll
    for (int j = 0; j < 4; ++j) acc[i][j] = (f32x4){0.f, 0.f, 0.f, 0.f};

  // staging: per wave 4 calls/tensor; call it covers chunks (it*4+w)*64 + lane
  size_t asrc[4], bsrc[4];
  int ldst[4];
#pragma unroll
  for (int it = 0; it < 4; ++it) {
    int chunk = (it * 4 + w) * 64 + l;
    int row = chunk >> 3, s = chunk & 7;
    size_t soff = (size_t)row * K + ((s ^ (row & 7)) << 3);
    asrc[it] = (size_t)m0 * K + soff;
    bsrc[it] = (size_t)n0 * K + soff;
    ldst[it] = chunk * 8;  // ushort index (16B per chunk)
  }
  int ra_off[2][4], rb_off[2][4];
#pragma unroll
  for (int kh = 0; kh < 2; ++kh)
#pragma unroll
    for (int f = 0; f < 4; ++f) {
      int rowA = wm * 64 + f * 16 + (l & 15);
      ra_off[kh][f] = rowA * 128 + (((kh * 4 + (l >> 4)) ^ (rowA & 7)) << 4);
      int rowB = wn * 64 + f * 16 + (l & 15);
      rb_off[kh][f] = rowB * 128 + (((kh * 4 + (l >> 4)) ^ (rowB & 7)) << 4);
    }

  for (int k0 = 0; k0 < K; k0 += 64) {
    __syncthreads();
#pragma unroll
    for (int it = 0; it < 4; ++it) {
      gload_lds16(A + asrc[it] + k0, As + ldst[it] - l * 8);
      gload_lds16(Bt + bsrc[it] + k0, Bs + ldst[it] - l * 8);
    }
    __syncthreads();
#pragma unroll
    for (int kh = 0; kh < 2; ++kh) {
      bf16x8 af[4], bfv[4];
#pragma unroll
      for (int f = 0; f < 4; ++f) {
        af[f] = *(const bf16x8*)((const char*)As + ra_off[kh][f]);
        bfv[f] = *(const bf16x8*)((const char*)Bs + rb_off[kh][f]);
      }
#pragma unroll
      for (int i = 0; i < 4; ++i)
#pragma unroll
        for (int j = 0; j < 4; ++j)
          acc[i][j] = __builtin_amdgcn_mfma_f32_16x16x32_bf16(af[i], bfv[j],
                                                              acc[i][j], 0, 0, 0);
    }
  }
  const int cn = n0 + wn * 64 + (l & 15);
  const int rbase = m0 + wm * 64 + ((l >> 4) << 2);
#pragma unroll
  for (int i = 0; i < 4; ++i)
#pragma unroll
    for (int j = 0; j < 4; ++j)
#pragma unroll
      for (int r = 0; r < 4; ++r)
        C[(size_t)(rbase + i * 16 + r) * N + cn + j * 16] = acc[i][j][r];
}

// ------------- split-bf16 3-term GEMM (fp32-accurate): C = Ah@Bh+Al@Bh+Ah@Bl
__global__ __launch_bounds__(256) void gemm_bt3(const unsigned short* __restrict__ Ah,
                                                const unsigned short* __restrict__ Al,
                                                const unsigned short* __restrict__ Bh,
                                                const unsigned short* __restrict__ Bl,
                                                float* __restrict__ C,
                                                int M, int N, int K) {
  __shared__ unsigned short Ash[128 * 64];
  __shared__ unsigned short Asl[128 * 64];
  __shared__ unsigned short Bsh[128 * 64];
  __shared__ unsigned short Bsl[128 * 64];
  const int tid = threadIdx.x;
  const int l = tid & 63;
  const int w = tid >> 6;
  const int wm = w >> 1, wn = w & 1;
  const int bid = blockIdx.x;
  const int nt = N >> 7;
  const int swz = (bid & 7) * ((int)gridDim.x >> 3) + (bid >> 3);
  const int m0 = (swz / nt) * 128, n0 = (swz % nt) * 128;

  f32x4 acc[4][4];
#pragma unroll
  for (int i = 0; i < 4; ++i)
#pragma unroll
    for (int j = 0; j < 4; ++j) acc[i][j] = (f32x4){0.f, 0.f, 0.f, 0.f};

  size_t asrc[4], bsrc[4];
  int ldst[4];
#pragma unroll
  for (int it = 0; it < 4; ++it) {
    int chunk = (it * 4 + w) * 64 + l;
    int row = chunk >> 3, s = chunk & 7;
    size_t soff = (size_t)row * K + ((s ^ (row & 7)) << 3);
    asrc[it] = (size_t)m0 * K + soff;
    bsrc[it] = (size_t)n0 * K + soff;
    ldst[it] = chunk * 8;
  }
  int ra_off[2][4], rb_off[2][4];
#pragma unroll
  for (int kh = 0; kh < 2; ++kh)
#pragma unroll
    for (int f = 0; f < 4; ++f) {
      int rowA = wm * 64 + f * 16 + (l & 15);
      ra_off[kh][f] = rowA * 128 + (((kh * 4 + (l >> 4)) ^ (rowA & 7)) << 4);
      int rowB = wn * 64 + f * 16 + (l & 15);
      rb_off[kh][f] = rowB * 128 + (((kh * 4 + (l >> 4)) ^ (rowB & 7)) << 4);
    }

  for (int k0 = 0; k0 < K; k0 += 64) {
    __syncthreads();
#pragma unroll
    for (int it = 0; it < 4; ++it) {
      unsigned short* d = (unsigned short*)0;
      (void)d;
      gload_lds16(Ah + asrc[it] + k0, Ash + ldst[it] - l * 8);
      gload_lds16(Al + asrc[it] + k0, Asl + ldst[it] - l * 8);
      gload_lds16(Bh + bsrc[it] + k0, Bsh + ldst[it] - l * 8);
      gload_lds16(Bl + bsrc[it] + k0, Bsl + ldst[it] - l * 8);
    }
    __syncthreads();
#pragma unroll
    for (int kh = 0; kh < 2; ++kh) {
      bf16x8 afh[4], bfh[4], tmp[4];
#pragma unroll
      for (int f = 0; f < 4; ++f) {
        afh[f] = *(const bf16x8*)((const char*)Ash + ra_off[kh][f]);
        bfh[f] = *(const bf16x8*)((const char*)Bsh + rb_off[kh][f]);
      }
#pragma unroll
      for (int i = 0; i < 4; ++i)
#pragma unroll
        for (int j = 0; j < 4; ++j)
          acc[i][j] = __builtin_amdgcn_mfma_f32_16x16x32_bf16(afh[i], bfh[j],
                                                              acc[i][j], 0, 0, 0);
#pragma unroll
      for (int f = 0; f < 4; ++f)
        tmp[f] = *(const bf16x8*)((const char*)Asl + ra_off[kh][f]);
#pragma unroll
      for (int i = 0; i < 4; ++i)
#pragma unroll
        for (int j = 0; j < 4; ++j)
          acc[i][j] = __builtin_amdgcn_mfma_f32_16x16x32_bf16(tmp[i], bfh[j],
                                                              acc[i][j], 0, 0, 0);
#pragma unroll
      for (int f = 0; f < 4; ++f)
        tmp[f] = *(const bf16x8*)((const char*)Bsl + rb_off[kh][f]);
#pragma unroll
      for (int i = 0; i < 4; ++i)
#pragma unroll
        for (int j = 0; j < 4; ++j)
          acc[i][j] = __builtin_amdgcn_mfma_f32_16x16x32_bf16(afh[i], tmp[j],
                                                              acc[i][j], 0, 0, 0);
    }
  }
  const int cn = n0 + wn * 64 + (l & 15);
  const int rbase = m0 + wm * 64 + ((l >> 4) << 2);
#pragma unroll
  for (int i = 0; i < 4; ++i)
#pragma unroll
    for (int j = 0; j < 4; ++j)
#pragma unroll
      for (int r = 0; r < 4; ++r)
        C[(size_t)(rbase + i * 16 + r) * N + cn + j * 16] = acc[i][j][r];
}

// ---------------- casts ----------------
__global__ __launch_bounds__(256) void cast_bf16_kernel(const float* __restrict__ in,
                                                        unsigned short* __restrict__ out) {
  const size_t i = ((size_t)blockIdx.x * 256 + threadIdx.x) * 4;
  float4 x = *(const float4*)(in + i);
  ushort4 o4;
  o4.x = f2bf(x.x);
  o4.y = f2bf(x.y);
  o4.z = f2bf(x.z);
  o4.w = f2bf(x.w);
  *(ushort4*)(out + i) = o4;
}

__global__ __launch_bounds__(256) void cast2_bf16_kernel(const float* __restrict__ in,
                                                         unsigned short* __restrict__ hi,
                                                         unsigned short* __restrict__ lo) {
  const size_t i = ((size_t)blockIdx.x * 256 + threadIdx.x) * 4;
  float4 x = *(const float4*)(in + i);
  ushort4 h4, l4;
  h4.x = f2bf(x.x); l4.x = f2bf(x.x - bf2f(h4.x));
  h4.y = f2bf(x.y); l4.y = f2bf(x.y - bf2f(h4.y));
  h4.z = f2bf(x.z); l4.z = f2bf(x.z - bf2f(h4.z));
  h4.w = f2bf(x.w); l4.w = f2bf(x.w - bf2f(h4.w));
  *(ushort4*)(hi + i) = h4;
  *(ushort4*)(lo + i) = l4;
}

// W [R][C] f32 row-major -> WT [C][R] bf16 (transpose + cast)
__global__ __launch_bounds__(256) void tcast_kernel(const float* __restrict__ W,
                                                    unsigned short* __restrict__ WT,
                                                    int R, int C) {
  __shared__ float tile[32][33];
  const int tx = threadIdx.x, ty = threadIdx.y;
  const int c0 = blockIdx.x * 32, r0 = blockIdx.y * 32;
#pragma unroll
  for (int i = 0; i < 4; ++i)
    tile[ty + 8 * i][tx] = W[(size_t)(r0 + ty + 8 * i) * C + c0 + tx];
  __syncthreads();
#pragma unroll
  for (int i = 0; i < 4; ++i)
    WT[(size_t)(c0 + ty + 8 * i) * R + r0 + tx] = f2bf(tile[tx][ty + 8 * i]);
}

__global__ __launch_bounds__(256) void tcast2_kernel(const float* __restrict__ W,
                                                     unsigned short* __restrict__ WTh,
                                                     unsigned short* __restrict__ WTl,
                                                     int R, int C) {
  __shared__ float tile[32][33];
  const int tx = threadIdx.x, ty = threadIdx.y;
  const int c0 = blockIdx.x * 32, r0 = blockIdx.y * 32;
#pragma unroll
  for (int i = 0; i < 4; ++i)
    tile[ty + 8 * i][tx] = W[(size_t)(r0 + ty + 8 * i) * C + c0 + tx];
  __syncthreads();
#pragma unroll
  for (int i = 0; i < 4; ++i) {
    float x = tile[tx][ty + 8 * i];
    unsigned short h = f2bf(x);
    WTh[(size_t)(c0 + ty + 8 * i) * R + r0 + tx] = h;
    WTl[(size_t)(c0 + ty + 8 * i) * R + r0 + tx] = f2bf(x - bf2f(h));
  }
}

// ---------------- routing: a/beta dots, top-4, silu+norms, dense LOG-decay ----
__global__ __launch_bounds__(256) void routing_kernel(
    const float* __restrict__ hidden, const float* __restrict__ Wa,
    const float* __restrict__ Wb, const float* __restrict__ dt,
    const float* __restrict__ rproj, float* __restrict__ qk,
    float* __restrict__ kk_, float* __restrict__ vv, float* __restrict__ gbuf,
    float* __restrict__ betaT) {
  const int row = blockIdx.x;  // b*T + t
  const int b = row >> 11;
  const int t = row & (TT - 1);
  const int h = threadIdx.x >> 6;
  const int l = threadIdx.x & 63;
  const size_t base = (size_t)row * DD + h * 256;

  const float* hrow = hidden + (size_t)row * DD;
  float aa = 0.f, bb = 0.f;
#pragma unroll
  for (int i = 0; i < 16; ++i) {
    float hv = hrow[l + 64 * i];
    aa = fmaf(hv, Wa[(l + 64 * i) * HH + h], aa);
    bb = fmaf(hv, Wb[(l + 64 * i) * HH + h], bb);
  }
  aa = wave_sum(aa);
  bb = wave_sum(bb);
  float sp = (aa > 20.f) ? aa : log1pf(expf(aa));
  float a_ = -sp * expf(dt[h]);
  float beta = 1.f / (1.f + expf(-bb));
  const int bh = b * HH + h;
  if (l == 0) betaT[(size_t)bh * TT + t] = beta;

  float4 rt4 = *(const float4*)(rproj + base + l * 4);
  float rv[4] = {rt4.x, rt4.y, rt4.z, rt4.w};
  int used = 0;
  int widx[4];
  float wsig[4], wg[4], wkfac[4];
#pragma unroll
  for (int it = 0; it < 4; ++it) {
    float bv = -3.4e38f;
    int bi = 0x7fffffff;
#pragma unroll
    for (int c = 0; c < 4; ++c) {
      bool ok = !(used & (1 << c));
      float v = rv[c];
      if (ok && (v > bv)) {
        bv = v;
        bi = l * 4 + c;
      }
    }
#pragma unroll
    for (int off = 32; off >= 1; off >>= 1) {
      float ov = __shfl_xor(bv, off);
      int oi = __shfl_xor(bi, off);
      if (ov > bv || (ov == bv && oi < bi)) {
        bv = ov;
        bi = oi;
      }
    }
    widx[it] = bi;
    wsig[it] = 1.f / (1.f + expf(-bv));
    if ((bi >> 2) == l) used |= 1 << (bi & 3);
  }
  float wsum = wsig[0] + wsig[1] + wsig[2] + wsig[3] + 1e-6f;
#pragma unroll
  for (int it = 0; it < 4; ++it) {
    float g = a_ * (wsig[it] / wsum);
    wg[it] = g;
    wkfac[it] = 1.f - expf(g);
  }

  float4 kv4 = *(const float4*)(kk_ + base + l * 4);
  float kvv[4] = {kv4.x, kv4.y, kv4.z, kv4.w};
  float kmask[4], ddv[4];
#pragma unroll
  for (int c = 0; c < 4; ++c) {
    int slot = l * 4 + c;
    float f = 0.f, d = 0.f;
#pragma unroll
    for (int it = 0; it < 4; ++it) {
      bool hit = (slot == widx[it]);
      f = hit ? wkfac[it] : f;
      d = hit ? wg[it] : d;
    }
    kmask[c] = siluf(kvv[c]) * f;
    ddv[c] = d;  // log-decay (0 for unselected slots)
  }
  float ss = kmask[0] * kmask[0] + kmask[1] * kmask[1] + kmask[2] * kmask[2] +
             kmask[3] * kmask[3];
  ss = wave_sum(ss);
  float kn = rsqrtf(ss + 1e-6f);
  *(float4*)(kk_ + base + l * 4) =
      make_float4(kmask[0] * kn, kmask[1] * kn, kmask[2] * kn, kmask[3] * kn);
  *(float4*)(gbuf + ((size_t)bh * TT + t) * 256 + l * 4) =
      make_float4(ddv[0], ddv[1], ddv[2], ddv[3]);

  float4 qv4 = *(const float4*)(qk + base + l * 4);
  float qs[4] = {siluf(qv4.x), siluf(qv4.y), siluf(qv4.z), siluf(qv4.w)};
  float qss = qs[0] * qs[0] + qs[1] * qs[1] + qs[2] * qs[2] + qs[3] * qs[3];
  qss = wave_sum(qss);
  float qn = rsqrtf(qss + 1e-6f) * 0.0625f;
  *(float4*)(qk + base + l * 4) =
      make_float4(qs[0] * qn, qs[1] * qn, qs[2] * qn, qs[3] * qn);

  float4 vv4 = *(const float4*)(vv + base + l * 4);
  *(float4*)(vv + base + l * 4) =
      make_float4(siluf(vv4.x), siluf(vv4.y), siluf(vv4.z), siluf(vv4.w));
}

// ---------------- phase A (MFMA): cumsum; P=[Qw;W]@X^T via mfma; Tinv; bf16 out
__global__ __launch_bounds__(256) void phaseA_kernel(
    const float* __restrict__ kproj, const float* __restrict__ qproj,
    float* __restrict__ expcG,  // in: g [bh][T][K]; out: row t0+63 = exp(csum)
    const float* __restrict__ betaT, unsigned short* __restrict__ TinvB,
    unsigned short* __restrict__ AB, unsigned short* __restrict__ Wg,
    unsigned short* __restrict__ Qg, unsigned short* __restrict__ XTg) {
  __shared__ unsigned short XB[64 * 256];   // X rows [t][k], 16B-slot ^ (t&7)
  __shared__ unsigned short QW[128 * 256];  // rows 0-63 Qw, 64-127 W, same swizzle
  __shared__ float Mb[64 * 68];             // M fp32 (then Tinv), padded
  const int bid = blockIdx.x;
  const int bh = bid >> 5, c = bid & 31;
  const int b = bh >> 2, h = bh & 3;
  const int t0 = c * 64;
  const int tid = threadIdx.x;
  const int w = tid >> 6, l = tid & 63;
  const int ln = l & 15, lg = l >> 4;

  // ---- stage 0: cumsum + bf16 staging (LDS + global Wg/Qg) ----
  {
    float cacc = 0.f;
    const int slot = tid >> 3, byt = tid & 7;
#pragma unroll 4
    for (int i = 0; i < 64; ++i) {
      size_t ga = ((size_t)bh * TT + t0 + i) * 256 + tid;
      size_t pa = (((size_t)b * TT + t0 + i) * HH + h) * 256 + tid;
      cacc += expcG[ga];
      float e = expf(cacc);
      float ei = __builtin_amdgcn_rcpf(e);
      float kv = kproj[pa], qv = qproj[pa];
      unsigned short wb = f2bf(kv * e);
      unsigned short qb = f2bf(qv * e);
      unsigned short xb = f2bf(kv * ei);
      Wg[ga] = wb;
      Qg[ga] = qb;
      int sw = ((slot ^ (i & 7)) << 3) + byt;
      XB[i * 256 + sw] = xb;
      QW[i * 256 + sw] = qb;
      QW[(i + 64) * 256 + sw] = wb;
      if (i == 63) expcG[ga] = e;  // only row phase B reads
    }
  }
  __syncthreads();

  // ---- MFMA: P[128][64] = QW @ XB^T; wave w owns rows w*32..w*32+31 ----
  f32x4 acc[2][4];
#pragma unroll
  for (int tr = 0; tr < 2; ++tr)
#pragma unroll
    for (int tc = 0; tc < 4; ++tc) acc[tr][tc] = (f32x4){0.f, 0.f, 0.f, 0.f};
  const int R0 = w * 32;
#pragma unroll
  for (int kt = 0; kt < 8; ++kt) {
    const int ks = kt * 4 + lg;  // 16B slot 0..31
    const int ra0 = R0 + ln, ra1 = R0 + 16 + ln;
    bf16x8 a0 = *(const bf16x8*)&QW[ra0 * 256 + ((ks ^ (ra0 & 7)) << 3)];
    bf16x8 a1 = *(const bf16x8*)&QW[ra1 * 256 + ((ks ^ (ra1 & 7)) << 3)];
#pragma unroll
    for (int tc = 0; tc < 4; ++tc) {
      const int br = tc * 16 + ln;
      bf16x8 bf_ = *(const bf16x8*)&XB[br * 256 + ((ks ^ (br & 7)) << 3)];
      acc[0][tc] = __builtin_amdgcn_mfma_f32_16x16x32_bf16(a0, bf_, acc[0][tc], 0, 0, 0);
      acc[1][tc] = __builtin_amdgcn_mfma_f32_16x16x32_bf16(a1, bf_, acc[1][tc], 0, 0, 0);
    }
  }
  // scatter: waves 0-1 -> A (masked, bf16, global); waves 2-3 -> M (fp32, LDS)
  const size_t gb = (((size_t)bh * 32 + c) << 12);
  if (w < 2) {
#pragma unroll
    for (int tr = 0; tr < 2; ++tr)
#pragma unroll
      for (int tc = 0; tc < 4; ++tc)
#pragma unroll
        for (int r = 0; r < 4; ++r) {
          int i = R0 + tr * 16 + lg * 4 + r;
          int s = tc * 16 + ln;
          AB[gb + i * 64 + s] = (s <= i) ? f2bf(acc[tr][tc][r]) : (unsigned short)0;
        }
  } else {
#pragma unroll
    for (int tr = 0; tr < 2; ++tr)
#pragma unroll
      for (int tc = 0; tc < 4; ++tc)
#pragma unroll
        for (int r = 0; r < 4; ++r) {
          int i = R0 - 64 + tr * 16 + lg * 4 + r;
          Mb[i * 68 + tc * 16 + ln] = acc[tr][tc][r];
        }
  }
  __syncthreads();

  // ---- wave 0: Tinv = (I + diag(beta) tril_strict(M))^{-1}; waves 1-3: XTg ----
  if (w == 0) {
    float tcol[64];
#pragma unroll
    for (int i = 0; i < 64; ++i) {
      float bi = betaT[(size_t)bh * TT + t0 + i];
      float a_ = (l == i) ? 1.f : 0.f;
#pragma unroll
      for (int s = 0; s < i; ++s)
        a_ = fmaf(-bi * Mb[i * 68 + s], tcol[s], a_);
      tcol[i] = a_;
    }
#pragma unroll
    for (int s = 0; s < 64; ++s) Mb[s * 68 + l] = tcol[s];
  } else {
    const int kk1 = tid - 64;  // 0..191
#pragma unroll 1
    for (int pass = 0; pass < 2; ++pass) {
      if (pass == 1 && kk1 >= 64) break;
      const int k = (pass == 0) ? kk1 : (192 + kk1);
      unsigned short* dst = XTg + ((size_t)bh * 256 + k) * TT + t0;
      const int kslot = k >> 3, kb = k & 7;
#pragma unroll 1
      for (int jq = 0; jq < 8; ++jq) {
        unsigned short e[8];
#pragma unroll
        for (int j = 0; j < 8; ++j) {
          int t = jq * 8 + j;
          e[j] = XB[t * 256 + (((kslot ^ (t & 7)) << 3) + kb)];
        }
        uint4 o;
        o.x = ((unsigned)e[0]) | (((unsigned)e[1]) << 16);
        o.y = ((unsigned)e[2]) | (((unsigned)e[3]) << 16);
        o.z = ((unsigned)e[4]) | (((unsigned)e[5]) << 16);
        o.w = ((unsigned)e[6]) | (((unsigned)e[7]) << 16);
        *(uint4*)(dst + jq * 8) = o;
      }
    }
  }
  __syncthreads();
  // ---- all: write Tinv bf16 [i][s] row-major ----
  {
    const int i = tid >> 2;
    const int sb = (tid & 3) * 16;
#pragma unroll
    for (int mq = 0; mq < 4; ++mq) {
      float v0 = Mb[i * 68 + sb + mq * 4 + 0];
      float v1 = Mb[i * 68 + sb + mq * 4 + 1];
      float v2 = Mb[i * 68 + sb + mq * 4 + 2];
      float v3 = Mb[i * 68 + sb + mq * 4 + 3];
      uint2 p;
      p.x = pack2(v0, v1);
      p.y = pack2(v2, v3);
      *(uint2*)(TinvB + gb + (size_t)i * 64 + sb + mq * 4) = p;
    }
  }
}

// ---------------- phase B: software-pipelined MFMA chunk scan ----------------
__global__ __launch_bounds__(256) void chunk_scan_kernel(
    const unsigned short* __restrict__ Wg, const unsigned short* __restrict__ Qg,
    const unsigned short* __restrict__ XTg, const unsigned short* __restrict__ Tb,
    const unsigned short* __restrict__ Ab, const float* __restrict__ vproj,
    const float* __restrict__ expcG, const float* __restrict__ betaT,
    float* __restrict__ obuf) {
  __shared__ unsigned short ShL[16 * 256];  // [n][k], 16B-slot swizzle ^n
  __shared__ unsigned short SlL[16 * 256];
  __shared__ unsigned short R2bL[16 * 64];  // [n][t], slot swizzle ^(n&7)
  __shared__ unsigned short UbL[16 * 64];
  const int bid = blockIdx.x;
  const int bh = bid & 15, slice = bid >> 4;  // all slices of bh -> same XCD
  const int b = bh >> 2, h = bh & 3;
  const int tid = threadIdx.x;
  const int w = tid >> 6;
  const int l = tid & 63;
  const int ln = l & 15, lg = l >> 4;

  const unsigned short* Wbh = Wg + (size_t)bh * TT * 256;
  const unsigned short* Qbh = Qg + (size_t)bh * TT * 256;
  const unsigned short* XTbh = XTg + (size_t)bh * 256 * TT;
  const unsigned short* Tbh = Tb + (size_t)bh * 32 * 4096;
  const unsigned short* Abh = Ab + (size_t)bh * 32 * 4096;
  const float* betabh = betaT + (size_t)bh * TT;
  const float* ebh = expcG + (size_t)bh * TT * 256;

  f32x4 S0 = {0.f, 0.f, 0.f, 0.f}, S1 = S0, S2 = S0, S3 = S0;

  // R2/U pack-write offset (4 consecutive t share a 16B slot)
  const int ru_off =
      ln * 64 + ((((w * 2) + (lg >> 1)) ^ (ln & 7)) << 3) + (lg & 1) * 4;

  bf16x8 wA[8], qA[8], wB[8], qB[8];
  float4 vA, bA, vB, bB;

#define LOADWQV(W_, Q_, V_, B_, c_)                                            \
  {                                                                            \
    const int t0_ = (c_) * 64;                                                 \
    _Pragma("unroll") for (int kt = 0; kt < 8; ++kt) {                         \
      const size_t arow =                                                      \
          (size_t)(t0_ + w * 16 + ln) * 256 + kt * 32 + lg * 8;                \
      W_[kt] = *(const bf16x8*)(Wbh + arow);                                   \
      Q_[kt] = *(const bf16x8*)(Qbh + arow);                                   \
    }                                                                          \
    const size_t vrow =                                                        \
        ((size_t)(b * TT + t0_ + w * 16 + lg * 4) * HH + h) * 256 +            \
        slice * 16 + ln;                                                       \
    V_.x = vproj[vrow];                                                        \
    V_.y = vproj[vrow + HH * 256];                                             \
    V_.z = vproj[vrow + 2 * HH * 256];                                         \
    V_.w = vproj[vrow + 3 * HH * 256];                                         \
    B_ = *(const float4*)(betabh + t0_ + w * 16 + lg * 4);                     \
  }

#define SSTORE(S_, E_, mt_)                                                    \
  {                                                                            \
    S_[0] *= E_.x;                                                             \
    S_[1] *= E_.y;                                                             \
    S_[2] *= E_.z;                                                             \
    S_[3] *= E_.w;                                                             \
    ushort4 hp, lp;                                                            \
    hp.x = f2bf(S_[0]); lp.x = f2bf(S_[0] - bf2f(hp.x));                       \
    hp.y = f2bf(S_[1]); lp.y = f2bf(S_[1] - bf2f(hp.y));                       \
    hp.z = f2bf(S_[2]); lp.z = f2bf(S_[2] - bf2f(hp.z));                       \
    hp.w = f2bf(S_[3]); lp.w = f2bf(S_[3] - bf2f(hp.w));                       \
    const int so_ = ln * 256 +                                                 \
                    ((((w * 8) + (mt_)*2 + (lg >> 1)) ^ ln) << 3) +            \
                    (lg & 1) * 4;                                              \
    *(ushort4*)(&ShL[so_]) = hp;                                               \
    *(ushort4*)(&SlL[so_]) = lp;                                               \
  }

#define CHUNK(Wc, Qc, Vc, Bc, Wn, Qn, Vn, Bn, c_)                              \
  {                                                                            \
    const int c = (c_);                                                        \
    const size_t tb_base = (size_t)c * 4096 + (w * 16 + ln) * 64 + lg * 8;     \
    bf16x8 tf0 = *(const bf16x8*)(Tbh + tb_base);                              \
    bf16x8 tf1 = *(const bf16x8*)(Tbh + tb_base + 32);                         \
    bf16x8 af0 = *(const bf16x8*)(Abh + tb_base);                              \
    bf16x8 af1 = *(const bf16x8*)(Abh + tb_base + 32);                         \
    f32x4 rhs = {0.f, 0.f, 0.f, 0.f}, oq = {0.f, 0.f, 0.f, 0.f};               \
    if (c > 0) {                                                               \
      _Pragma("unroll") for (int kt = 0; kt < 8; ++kt) {                       \
        const int sro = ln * 256 + (((kt * 4 + lg) ^ ln) << 3);                \
        bf16x8 sh = *(const bf16x8*)(&ShL[sro]);                               \
        bf16x8 sl = *(const bf16x8*)(&SlL[sro]);                               \
        rhs = __builtin_amdgcn_mfma_f32_16x16x32_bf16(Wc[kt], sh, rhs, 0, 0, 0); \
        rhs = __builtin_amdgcn_mfma_f32_16x16x32_bf16(Wc[kt], sl, rhs, 0, 0, 0); \
        oq = __builtin_amdgcn_mfma_f32_16x16x32_bf16(Qc[kt], sh, oq, 0, 0, 0); \
        oq = __builtin_amdgcn_mfma_f32_16x16x32_bf16(Qc[kt], sl, oq, 0, 0, 0); \
      }                                                                        \
    }                                                                          \
    if (c + 1 < 32) LOADWQV(Wn, Qn, Vn, Bn, c + 1);                            \
    {                                                                          \
      ushort4 r2p;                                                             \
      r2p.x = f2bf(Bc.x * (Vc.x - rhs[0]));                                    \
      r2p.y = f2bf(Bc.y * (Vc.y - rhs[1]));                                    \
      r2p.z = f2bf(Bc.z * (Vc.z - rhs[2]));                                    \
      r2p.w = f2bf(Bc.w * (Vc.w - rhs[3]));                                    \
      *(ushort4*)(&R2bL[ru_off]) = r2p;                                        \
    }                                                                          \
    __syncthreads();                                                           \
    bf16x8 xf0a, xf0b, xf1a, xf1b, xf2a, xf2b, xf3a, xf3b;                     \
    {                                                                          \
      const size_t xb = (size_t)(w * 64 + ln) * TT + c * 64 + lg * 8;          \
      xf0a = *(const bf16x8*)(XTbh + xb);                                      \
      xf0b = *(const bf16x8*)(XTbh + xb + 32);                                 \
      xf1a = *(const bf16x8*)(XTbh + xb + 16 * TT);                            \
      xf1b = *(const bf16x8*)(XTbh + xb + 16 * TT + 32);                       \
      xf2a = *(const bf16x8*)(XTbh + xb + 32 * TT);                            \
      xf2b = *(const bf16x8*)(XTbh + xb + 32 * TT + 32);                       \
      xf3a = *(const bf16x8*)(XTbh + xb + 48 * TT);                            \
      xf3b = *(const bf16x8*)(XTbh + xb + 48 * TT + 32);                       \
    }                                                                          \
    const float* ebase = ebh + (size_t)(c * 64 + 63) * 256 + w * 64 + lg * 4;  \
    float4 eL0 = *(const float4*)(ebase);                                      \
    float4 eL1 = *(const float4*)(ebase + 16);                                 \
    float4 eL2 = *(const float4*)(ebase + 32);                                 \
    float4 eL3 = *(const float4*)(ebase + 48);                                 \
    {                                                                          \
      bf16x8 rf0 = *(const bf16x8*)(&R2bL[ln * 64 + (((0 + lg) ^ (ln & 7)) << 3)]); \
      bf16x8 rf1 = *(const bf16x8*)(&R2bL[ln * 64 + (((4 + lg) ^ (ln & 7)) << 3)]); \
      f32x4 u = {0.f, 0.f, 0.f, 0.f};                                          \
      u = __builtin_amdgcn_mfma_f32_16x16x32_bf16(tf0, rf0, u, 0, 0, 0);       \
      u = __builtin_amdgcn_mfma_f32_16x16x32_bf16(tf1, rf1, u, 0, 0, 0);       \
      ushort4 up;                                                              \
      up.x = f2bf(u[0]);                                                       \
      up.y = f2bf(u[1]);                                                       \
      up.z = f2bf(u[2]);                                                       \
      up.w = f2bf(u[3]);                                                       \
      *(ushort4*)(&UbL[ru_off]) = up;                                          \
    }                                                                          \
    __syncthreads();                                                           \
    bf16x8 uf0 = *(const bf16x8*)(&UbL[ln * 64 + (((0 + lg) ^ (ln & 7)) << 3)]); \
    bf16x8 uf1 = *(const bf16x8*)(&UbL[ln * 64 + (((4 + lg) ^ (ln & 7)) << 3)]); \
    {                                                                          \
      f32x4 o = oq;                                                            \
      o = __builtin_amdgcn_mfma_f32_16x16x32_bf16(af0, uf0, o, 0, 0, 0);       \
      o = __builtin_amdgcn_mfma_f32_16x16x32_bf16(af1, uf1, o, 0, 0, 0);       \
      const size_t orow =                                                      \
          ((size_t)(b * TT + c * 64 + w * 16 + lg * 4) * HH + h) * 256 +       \
          slice * 16 + ln;                                                     \
      obuf[orow] = o[0];                                                       \
      obuf[orow + HH * 256] = o[1];                                            \
      obuf[orow + 2 * HH * 256] = o[2];                                        \
      obuf[orow + 3 * HH * 256] = o[3];                                        \
    }                                                                          \
    S0 = __builtin_amdgcn_mfma_f32_16x16x32_bf16(xf0a, uf0, S0, 0, 0, 0);      \
    S0 = __builtin_amdgcn_mfma_f32_16x16x32_bf16(xf0b, uf1, S0, 0, 0, 0);      \
    S1 = __builtin_amdgcn_mfma_f32_16x16x32_bf16(xf1a, uf0, S1, 0, 0, 0);      \
    S1 = __builtin_amdgcn_mfma_f32_16x16x32_bf16(xf1b, uf1, S1, 0, 0, 0);      \
    S2 = __builtin_amdgcn_mfma_f32_16x16x32_bf16(xf2a, uf0, S2, 0, 0, 0);      \
    S2 = __builtin_amdgcn_mfma_f32_16x16x32_bf16(xf2b, uf1, S2, 0, 0, 0);      \
    S3 = __builtin_amdgcn_mfma_f32_16x16x32_bf16(xf3a, uf0, S3, 0, 0, 0);      \
    S3 = __builtin_amdgcn_mfma_f32_16x16x32_bf16(xf3b, uf1, S3, 0, 0, 0);      \
    SSTORE(S0, eL0, 0);                                                        \
    SSTORE(S1, eL1, 1);                                                        \
    SSTORE(S2, eL2, 2);                                                        \
    SSTORE(S3, eL3, 3);                                                        \
    __syncthreads();                                                           \
  }

  LOADWQV(wA, qA, vA, bA, 0);
  for (int cc = 0; cc < 32; cc += 2) {
    CHUNK(wA, qA, vA, bA, wB, qB, vB, bB, cc);
    CHUNK(wB, qB, vB, bB, wA, qA, vA, bA, cc + 1);
  }
#undef CHUNK
#undef SSTORE
#undef LOADWQV
}

// ---------------- per-head RMSNorm ----------------
__global__ __launch_bounds__(256) void rmsnorm_kernel(
    const float* __restrict__ o, const float* __restrict__ w,
    float* __restrict__ out) {
  const int row = blockIdx.x;
  const int l = threadIdx.x & 63;
  const size_t base = (size_t)row * DD + (threadIdx.x >> 6) * 256 + l * 4;
  float4 x = *(const float4*)(o + base);
  float ss = x.x * x.x + x.y * x.y + x.z * x.z + x.w * x.w;
  ss = wave_sum(ss);
  float sc = rsqrtf(ss * (1.f / 256.f) + 1e-5f);
  float4 wv = *(const float4*)(w + l * 4);
  *(float4*)(out + base) = make_float4(x.x * sc * wv.x, x.y * sc * wv.y,
                                       x.z * sc * wv.z, x.w * sc * wv.w);
}

extern "C" void kernel_launch(void* const* d_in, const int* in_sizes, int n_in,
                              void* d_out, int out_size, void* d_ws,
                              size_t ws_size, hipStream_t stream) {
  const float* hidden = (const float*)d_in[0];
  const float* Wq = (const float*)d_in[1];
  const float* Wk = (const float*)d_in[2];
  const float* Wv = (const float*)d_in[3];
  const float* Wa = (const float*)d_in[4];
  const float* Wr = (const float*)d_in[5];
  const float* Wb = (const float*)d_in[6];
  const float* dt = (const float*)d_in[7];
  const float* norm_w = (const float*)d_in[8];
  const float* Wo = (const float*)d_in[9];
  float* out = (float*)d_out;

  const size_t NP = (size_t)BB * TT * DD;  // 8388608
  float* ws = (float*)d_ws;
  float* qproj = ws;
  float* kproj = ws + NP;
  float* vproj = ws + 2 * NP;
  float* gbuf = ws + 3 * NP;  // g [bh][T][K]; row63-per-chunk overwritten with e
  unsigned short* hbf = (unsigned short*)(ws + 4 * NP);          // NP bf16
  unsigned short* wT = (unsigned short*)(ws + 4 * NP + NP / 2);  // 6 x 1M bf16
  unsigned short* WT0 = wT;
  unsigned short* WT1 = wT + 1048576;
  unsigned short* WT2 = wT + 2 * 1048576;
  unsigned short* WT3 = wT + 3 * 1048576;
  unsigned short* WT4 = wT + 4 * 1048576;  // Wr^T hi (dead after bt3 -> Tb)
  unsigned short* WT5 = wT + 5 * 1048576;  // Wr^T lo
  float* betaT = ws + 4 * NP + NP / 2 + 3 * 1024 * 1024;  // 32K floats
  float* after_beta = betaT + 16 * TT;
  unsigned short* Qg = (unsigned short*)after_beta;        // NP bf16 (16MB)
  unsigned short* XTg = Qg + NP;                           // NP bf16 (16MB)
  unsigned short* Ab = XTg + NP;                           // 2M bf16 (4MB)
  unsigned short* Wgb = hbf;   // alias: hbf dead between projections and final cast
  unsigned short* Tbb = WT4;   // alias: WT4/WT5 dead after gemm_bt3 (2M bf16)
  unsigned short* hlo = (unsigned short*)qproj;  // alias: dead before q-GEMM
  float* rproj = out;
  float* normed = qproj;

  dim3 bt(256);
  cast2_bf16_kernel<<<8192, 256, 0, stream>>>(hidden, hbf, hlo);
  dim3 tg(32, 32), tb(32, 8);
  tcast2_kernel<<<tg, tb, 0, stream>>>(Wr, WT4, WT5, 1024, 1024);
  tcast_kernel<<<tg, tb, 0, stream>>>(Wq, WT0, 1024, 1024);
  tcast_kernel<<<tg, tb, 0, stream>>>(Wk, WT1, 1024, 1024);
  tcast_kernel<<<tg, tb, 0, stream>>>(Wv, WT2, 1024, 1024);
  tcast_kernel<<<tg, tb, 0, stream>>>(Wo, WT3, 1024, 1024);

  const int GEMM_BLKS = 512;  // (8192/128)*(1024/128); %8==0 -> bijective swizzle
  gemm_bt3<<<GEMM_BLKS, bt, 0, stream>>>(hbf, hlo, WT4, WT5, rproj, 8192, 1024, 1024);
  gemm_bt<<<GEMM_BLKS, bt, 0, stream>>>(hbf, WT0, qproj, 8192, 1024, 1024);
  gemm_bt<<<GEMM_BLKS, bt, 0, stream>>>(hbf, WT1, kproj, 8192, 1024, 1024);
  gemm_bt<<<GEMM_BLKS, bt, 0, stream>>>(hbf, WT2, vproj, 8192, 1024, 1024);

  routing_kernel<<<8192, 256, 0, stream>>>(hidden, Wa, Wb, dt, rproj, qproj,
                                           kproj, vproj, gbuf, betaT);
  phaseA_kernel<<<512, 256, 0, stream>>>(kproj, qproj, gbuf, betaT, Tbb, Ab,
                                         Wgb, Qg, XTg);
  chunk_scan_kernel<<<256, 256, 0, stream>>>(Wgb, Qg, XTg, Tbb, Ab, vproj,
                                             gbuf, betaT, out);
  rmsnorm_kernel<<<8192, 256, 0, stream>>>(out, norm_w, normed);
  cast_bf16_kernel<<<8192, 256, 0, stream>>>(normed, hbf);
  gemm_bt<<<GEMM_BLKS, bt, 0, stream>>>(hbf, WT3, out, 8192, 1024, 1024);
}